// Round 1
// baseline (1329.700 us; speedup 1.0000x reference)
//
#include <hip/hip_runtime.h>
#include <stdint.h>

// R1: full fp32 implementation + bf16 MFMA for the two memory-module GEMMs.
// Structure: conv kernels write RAW outputs + per-channel sum/sumsq (atomics),
// k_coef turns stats into affine (a,c); next kernel applies relu(a*x+c) on load.

typedef unsigned short ushort_t;
typedef __bf16 bf16x8 __attribute__((ext_vector_type(8)));
typedef float f32x4 __attribute__((ext_vector_type(4)));

#define DEV static __device__ __forceinline__

DEV ushort_t f2bf(float f){
  union { float f; uint32_t u; } v; v.f = f;
  return (ushort_t)((v.u + 0x7FFFu + ((v.u >> 16) & 1u)) >> 16);
}

// ---------------- header (stats/coeff) offsets in floats ----------------
#define H_XS   0      // [2] sampled-x sum, sumsq
#define H_A1   16     // [16] folded conv1+bn1 scale (applied to sampled x)
#define H_C1   32     // [16]
#define H_S2   64
#define H_Q2   96
#define H_A2   128
#define H_C2   160
#define H_S3   192
#define H_Q3   256
#define H_A3   320
#define H_C3   384
#define H_S4   448
#define H_Q4   512
#define H_A4   576
#define H_C4   640
#define H_DS0  704
#define H_DQ0  768
#define H_DA0  832
#define H_DC0  896
#define H_DS1  960
#define H_DQ1  992
#define H_DA1  1024
#define H_DC1  1056
#define H_DS2  1088
#define H_DQ2  1104
#define H_DA2  1120
#define H_DC2  1136
#define H_ZN   1152   // [512]
#define H_MN   1664   // [2000]
#define HDR_FLOATS 4096

// ---------------- stats of strided-sampled input (for bn1 fold) ----------------
__global__ __launch_bounds__(256) void k_xstats(const float* __restrict__ x, float* __restrict__ hdr){
  __shared__ float red[8];
  float s = 0.f, q = 0.f;
  const int total = 512*49*49;
  for (int idx = blockIdx.x*256 + threadIdx.x; idx < total; idx += gridDim.x*256){
    int b = idx / 2401;
    int r = idx - b*2401;
    int i = r / 49, j = r - i*49;
    float v = 0.f;
    if (i > 0 && j > 0) v = x[(size_t)b*9216 + (2*i-1)*96 + (2*j-1)];
    s += v; q += v*v;
  }
  for (int o=32;o;o>>=1){ s += __shfl_down(s,o,64); q += __shfl_down(q,o,64); }
  int w = threadIdx.x>>6;
  if ((threadIdx.x&63)==0){ red[w*2]=s; red[w*2+1]=q; }
  __syncthreads();
  if (threadIdx.x==0){
    atomicAdd(&hdr[H_XS+0], red[0]+red[2]+red[4]+red[6]);
    atomicAdd(&hdr[H_XS+1], red[1]+red[3]+red[5]+red[7]);
  }
}

__global__ void k_coef1(float* __restrict__ hdr, const float* __restrict__ c1w,
                        const float* __restrict__ c1b, const float* __restrict__ g,
                        const float* __restrict__ be){
  int c = threadIdx.x;
  if (c < 16){
    const float N = 512.f*49.f*49.f;
    float mx = hdr[H_XS+0]/N;
    float vx = hdr[H_XS+1]/N - mx*mx;
    float mean = c1w[c]*mx + c1b[c];
    float var  = c1w[c]*c1w[c]*vx;
    float a = g[c]*rsqrtf(var + 1e-5f);
    hdr[H_A1+c] = a*c1w[c];
    hdr[H_C1+c] = a*(c1b[c]-mean) + be[c];
  }
}

__global__ void k_coef(const float* __restrict__ S, const float* __restrict__ Q,
                       const float* __restrict__ g, const float* __restrict__ be,
                       float* __restrict__ A, float* __restrict__ C, int nch, float invN){
  int c = threadIdx.x;
  if (c < nch){
    float m = S[c]*invN;
    float v = Q[c]*invN - m*m;
    float a = g[c]*rsqrtf(v + 1e-5f);
    A[c] = a;
    C[c] = be[c] - m*a;
  }
}

// reorder conv4 / deconv0 weights to [tap][ci][co] for coalesced float4 reads
__global__ __launch_bounds__(256) void k_wprep(const float* __restrict__ c4w, const float* __restrict__ d0w,
                                               float* __restrict__ w4r, float* __restrict__ d0r){
  int i = blockIdx.x*256 + threadIdx.x;
  if (i < 36864){
    int co = i&63, ci = (i>>6)&63, tap = i>>12;
    w4r[i] = c4w[(co*64+ci)*9 + tap];        // c4_w [co][ci][3][3]
  } else if (i < 73728){
    int o = i - 36864;
    int co = o&63, ci = (o>>6)&63, tap = o>>12;
    d0r[o] = d0w[(ci*64+co)*9 + tap];        // d0_w [ci][co][3][3]
  }
}

// memory rows -> bf16 + row norms
__global__ __launch_bounds__(256) void k_memrows(const float* __restrict__ mem, float* __restrict__ hdr,
                                                 ushort_t* __restrict__ mbf){
  __shared__ float red[4];
  const int m = blockIdx.x, tid = threadIdx.x;
  float part = 0.f;
  for (int i=tid;i<2304;i+=256){
    float v = mem[(size_t)m*2304+i];
    mbf[(size_t)m*2304+i] = f2bf(v);
    part += v*v;
  }
  for (int o=32;o;o>>=1) part += __shfl_down(part,o,64);
  if ((tid&63)==0) red[tid>>6] = part;
  __syncthreads();
  if (tid==0) hdr[H_MN+m] = sqrtf(red[0]+red[1]+red[2]+red[3]);
}

// memory transpose -> bf16 [2304][2016] (zero-padded K for GEMM2)
__global__ __launch_bounds__(256) void k_memT(const float* __restrict__ mem, ushort_t* __restrict__ mt){
  __shared__ ushort_t tile[32][33];
  const int ft = blockIdx.x % 72, mtile = blockIdx.x / 72;
  const int tx = threadIdx.x & 31, ty = threadIdx.x >> 5;
  #pragma unroll
  for (int r0=0;r0<4;r0++){
    int m = mtile*32 + r0*8 + ty;
    int f = ft*32 + tx;
    float v = (m < 2000) ? mem[(size_t)m*2304 + f] : 0.f;
    tile[r0*8+ty][tx] = f2bf(v);
  }
  __syncthreads();
  #pragma unroll
  for (int r0=0;r0<4;r0++){
    int f = ft*32 + r0*8 + ty;
    mt[(size_t)f*2016 + mtile*32 + tx] = tile[tx][r0*8+ty];
  }
}

// ---------------- conv2: reads x, computes h1=relu(A1*xv+C1) on the fly ----------------
__global__ __launch_bounds__(256) void k_conv2(
    const float* __restrict__ x, const float* __restrict__ w2g, const float* __restrict__ b2g,
    float* __restrict__ hdr, float* __restrict__ out){
  __shared__ float xv[2401];     // strided-sampled x, 49x49
  __shared__ float wl[4608];     // [tap][ci][co]
  const int b = blockIdx.x, tid = threadIdx.x;
  for (int i=tid;i<2401;i+=256){
    int r = i/49, c = i - r*49;
    xv[i] = (r>0 && c>0) ? x[(size_t)b*9216 + (2*r-1)*96 + (2*c-1)] : 0.f;
  }
  for (int i=tid;i<4608;i+=256){
    int co = i & 31, t = i >> 5, ci = t & 15, tap = t >> 4;
    wl[i] = w2g[(co*16+ci)*9 + tap];
  }
  float A1r[16], C1r[16];
  #pragma unroll
  for (int ci=0;ci<16;ci++){ A1r[ci] = hdr[H_A1+ci]; C1r[ci] = hdr[H_C1+ci]; }
  const int co4 = tid>>5, lane = tid&31;
  float bias[4];
  #pragma unroll
  for (int v=0;v<4;v++) bias[v] = b2g[co4*4+v];
  float sacc[4]={0,0,0,0}, qacc[4]={0,0,0,0};
  __syncthreads();
  for (int p0=0;p0<625;p0+=128){
    int p[4], oi[4], oj[4];
    float acc[4][4];
    #pragma unroll
    for (int u=0;u<4;u++){
      p[u] = p0 + u*32 + lane;
      int pc = p[u] < 625 ? p[u] : 624;
      oi[u] = pc/25; oj[u] = pc - oi[u]*25;
      #pragma unroll
      for (int v=0;v<4;v++) acc[u][v] = bias[v];
    }
    #pragma unroll 1
    for (int tap=0; tap<9; tap++){
      int ki = tap/3, kj = tap - ki*3;
      const float* wt = &wl[tap*512 + co4*4];
      float xvv[4], msk[4];
      #pragma unroll
      for (int u=0;u<4;u++){
        int ii = 2*oi[u]-1+ki, jj = 2*oj[u]-1+kj;
        bool ok = (p[u]<625) & ((unsigned)ii<49u) & ((unsigned)jj<49u);
        xvv[u] = xv[ok ? (ii*49+jj) : 0];
        msk[u] = ok ? 1.f : 0.f;
      }
      #pragma unroll
      for (int ci=0;ci<16;ci++){
        const float4 wv = *(const float4*)&wt[ci*32];
        #pragma unroll
        for (int u=0;u<4;u++){
          float h = fmaxf(fmaf(A1r[ci], xvv[u], C1r[ci]), 0.f) * msk[u];
          acc[u][0] = fmaf(h, wv.x, acc[u][0]);
          acc[u][1] = fmaf(h, wv.y, acc[u][1]);
          acc[u][2] = fmaf(h, wv.z, acc[u][2]);
          acc[u][3] = fmaf(h, wv.w, acc[u][3]);
        }
      }
    }
    #pragma unroll
    for (int u=0;u<4;u++) if (p[u] < 625){
      #pragma unroll
      for (int v=0;v<4;v++){
        float y = acc[u][v];
        out[((size_t)b*32 + co4*4+v)*625 + p[u]] = y;
        sacc[v] += y; qacc[v] += y*y;
      }
    }
  }
  #pragma unroll
  for (int v=0;v<4;v++){
    float s = sacc[v], q = qacc[v];
    for (int o=16;o;o>>=1){ s += __shfl_down(s,o,32); q += __shfl_down(q,o,32); }
    if (lane==0){ atomicAdd(&hdr[H_S2+co4*4+v], s); atomicAdd(&hdr[H_Q2+co4*4+v], q); }
  }
}

// ---------------- conv3: 32->64, 3x3 s2 p1, 25->13; 4 ci-quarter phases ----------------
__global__ __launch_bounds__(256) void k_conv3(
    const float* __restrict__ h2, const float* __restrict__ w3g, const float* __restrict__ b3g,
    float* __restrict__ hdr, float* __restrict__ out){
  __shared__ float inp[8*626];   // 8 ci, stride 626 (slot 625 == 0 for OOB taps)
  __shared__ float wl[9*8*64];   // [tap][ci8][co]
  const int b = blockIdx.x, tid = threadIdx.x;
  const int co4 = tid>>4, lane = tid&15;
  float bias[4];
  #pragma unroll
  for (int v=0;v<4;v++) bias[v] = b3g[co4*4+v];
  int oi_[3][4], oj_[3][4];
  float acc[3][4][4];
  #pragma unroll
  for (int it=0;it<3;it++)
  #pragma unroll
  for (int u=0;u<4;u++){
    int p = it*64 + u*16 + lane; if (p > 168) p = 168;
    oi_[it][u] = p/13; oj_[it][u] = p - oi_[it][u]*13;
    #pragma unroll
    for (int v=0;v<4;v++) acc[it][u][v] = bias[v];
  }
  for (int ph=0; ph<4; ph++){
    if (ph) __syncthreads();
    for (int i=tid;i<5008;i+=256){
      int ci8 = i/626, pp = i - ci8*626;
      int ci = ph*8 + ci8;
      float val = 0.f;
      if (pp < 625){
        float raw = h2[((size_t)b*32 + ci)*625 + pp];
        val = fmaxf(fmaf(hdr[H_A2+ci], raw, hdr[H_C2+ci]), 0.f);
      }
      inp[i] = val;
    }
    for (int i=tid;i<4608;i+=256){
      int co = i&63, t = i>>6, ci8 = t&7, tap = t>>3;
      wl[i] = w3g[(co*32 + ph*8 + ci8)*9 + tap];
    }
    __syncthreads();
    #pragma unroll 1
    for (int tap=0; tap<9; tap++){
      int ki = tap/3, kj = tap - ki*3;
      const float* wt = &wl[tap*512 + co4*4];
      #pragma unroll
      for (int it=0;it<3;it++){
        int idxu[4];
        #pragma unroll
        for (int u=0;u<4;u++){
          int p = it*64 + u*16 + lane;
          int ii = 2*oi_[it][u]-1+ki, jj = 2*oj_[it][u]-1+kj;
          bool ok = (p<169) & ((unsigned)ii<25u) & ((unsigned)jj<25u);
          idxu[u] = ok ? (ii*25+jj) : 625;
        }
        #pragma unroll 2
        for (int ci8=0;ci8<8;ci8++){
          const float4 wv = *(const float4*)&wt[ci8*64];
          #pragma unroll
          for (int u=0;u<4;u++){
            float xvv = inp[ci8*626 + idxu[u]];
            acc[it][u][0] = fmaf(xvv, wv.x, acc[it][u][0]);
            acc[it][u][1] = fmaf(xvv, wv.y, acc[it][u][1]);
            acc[it][u][2] = fmaf(xvv, wv.z, acc[it][u][2]);
            acc[it][u][3] = fmaf(xvv, wv.w, acc[it][u][3]);
          }
        }
      }
    }
  }
  float sacc[4]={0,0,0,0}, qacc[4]={0,0,0,0};
  #pragma unroll
  for (int it=0;it<3;it++)
  #pragma unroll
  for (int u=0;u<4;u++){
    int p = it*64 + u*16 + lane;
    if (p < 169){
      #pragma unroll
      for (int v=0;v<4;v++){
        float y = acc[it][u][v];
        out[((size_t)b*64 + co4*4+v)*169 + p] = y;
        sacc[v] += y; qacc[v] += y*y;
      }
    }
  }
  #pragma unroll
  for (int v=0;v<4;v++){
    float s = sacc[v], q = qacc[v];
    for (int o=8;o;o>>=1){ s += __shfl_down(s,o,16); q += __shfl_down(q,o,16); }
    if (lane==0){ atomicAdd(&hdr[H_S3+co4*4+v], s); atomicAdd(&hdr[H_Q3+co4*4+v], q); }
  }
}

// ---------------- conv4: 64->64, 3x3 s2 p0, 13->6 (no padding) ----------------
__global__ __launch_bounds__(256) void k_conv4(
    const float* __restrict__ h3, const float* __restrict__ w4r, const float* __restrict__ b4g,
    float* __restrict__ hdr, float* __restrict__ out){
  __shared__ float inp[10816];   // 64 x 13 x 13, post bn3+relu
  const int b = blockIdx.x, tid = threadIdx.x;
  for (int i=tid;i<10816;i+=256){
    int ci = i/169;
    float raw = h3[(size_t)b*10816 + i];
    inp[i] = fmaxf(fmaf(hdr[H_A3+ci], raw, hdr[H_C3+ci]), 0.f);
  }
  __syncthreads();
  const int co4 = tid>>4, lane = tid&15;
  const bool act = lane < 12;
  float bias[4];
  #pragma unroll
  for (int v=0;v<4;v++) bias[v] = b4g[co4*4+v];
  int base_[3];
  float acc[3][4];
  #pragma unroll
  for (int u=0;u<3;u++){
    int p = u*12 + lane; if (p > 35) p = 35;
    int oi = p/6, oj = p - oi*6;
    base_[u] = (2*oi)*13 + 2*oj;
    #pragma unroll
    for (int v=0;v<4;v++) acc[u][v] = bias[v];
  }
  #pragma unroll 1
  for (int tap=0; tap<9; tap++){
    int ki = tap/3, kj = tap - ki*3;
    const int toff = ki*13 + kj;
    #pragma unroll 2
    for (int ci=0;ci<64;ci++){
      const float4 wv = *(const float4*)&w4r[((size_t)(tap*64+ci))*64 + co4*4];
      #pragma unroll
      for (int u=0;u<3;u++){
        float xvv = inp[ci*169 + base_[u] + toff];
        acc[u][0] = fmaf(xvv, wv.x, acc[u][0]);
        acc[u][1] = fmaf(xvv, wv.y, acc[u][1]);
        acc[u][2] = fmaf(xvv, wv.z, acc[u][2]);
        acc[u][3] = fmaf(xvv, wv.w, acc[u][3]);
      }
    }
  }
  float sacc[4]={0,0,0,0}, qacc[4]={0,0,0,0};
  if (act){
    #pragma unroll
    for (int u=0;u<3;u++){
      int p = u*12 + lane;
      #pragma unroll
      for (int v=0;v<4;v++){
        float y = acc[u][v];
        out[((size_t)b*64 + co4*4+v)*36 + p] = y;
        sacc[v] += y; qacc[v] += y*y;
      }
    }
  }
  #pragma unroll
  for (int v=0;v<4;v++){
    float s = sacc[v], q = qacc[v];
    for (int o=8;o;o>>=1){ s += __shfl_down(s,o,16); q += __shfl_down(q,o,16); }
    if (lane==0){ atomicAdd(&hdr[H_S4+co4*4+v], s); atomicAdd(&hdr[H_Q4+co4*4+v], q); }
  }
}

// z = relu(bn4(conv4 raw)) -> bf16, plus per-row norm
__global__ __launch_bounds__(256) void k_z(const float* __restrict__ zraw, float* __restrict__ hdr,
                                           ushort_t* __restrict__ zbf){
  __shared__ float red[4];
  const int b = blockIdx.x, tid = threadIdx.x;
  float part = 0.f;
  for (int i=tid;i<2304;i+=256){
    int c = i/36;
    float h = fmaxf(fmaf(hdr[H_A4+c], zraw[(size_t)b*2304+i], hdr[H_C4+c]), 0.f);
    zbf[(size_t)b*2304+i] = f2bf(h);
    part += h*h;
  }
  for (int o=32;o;o>>=1) part += __shfl_down(part,o,64);
  if ((tid&63)==0) red[tid>>6] = part;
  __syncthreads();
  if (tid==0) hdr[H_ZN+b] = sqrtf(red[0]+red[1]+red[2]+red[3]);
}

// D[i][j] = sum_k A[i][k]*B[j][k], bf16 in / fp32 out, one 16x16 tile per wave
__global__ __launch_bounds__(256) void k_gemm_bt(const ushort_t* __restrict__ A, const ushort_t* __restrict__ Bm,
                                                 float* __restrict__ D, int Ntiles, int Kp, int kch, int N){
  const int gw = blockIdx.x*4 + (threadIdx.x>>6);
  const int lane = threadIdx.x & 63;
  const int ti = gw / Ntiles, tj = gw - ti*Ntiles;
  const int r = lane & 15, q = lane >> 4;
  const ushort_t* pa = A + (size_t)(ti*16+r)*Kp + q*8;
  const ushort_t* pb = Bm + (size_t)(tj*16+r)*Kp + q*8;
  f32x4 acc = {0.f,0.f,0.f,0.f};
  #pragma unroll 2
  for (int k=0;k<kch;k++){
    bf16x8 av = *(const bf16x8*)(pa + k*32);
    bf16x8 bv = *(const bf16x8*)(pb + k*32);
    acc = __builtin_amdgcn_mfma_f32_16x16x32_bf16(av, bv, acc, 0, 0, 0);
  }
  float* pd = D + (size_t)(ti*16 + q*4)*N + (size_t)tj*16 + r;
  #pragma unroll
  for (int reg=0; reg<4; reg++) pd[(size_t)reg*N] = acc[reg];
}

// softmax over M=2000 + hard-shrink + L1 renorm -> bf16 weights (K padded to 2016)
__global__ __launch_bounds__(256) void k_softmax(const float* __restrict__ sim, float* __restrict__ hdr,
                                                 ushort_t* __restrict__ wbf){
  __shared__ float e[2000];
  __shared__ float red[8];
  const int b = blockIdx.x, tid = threadIdx.x;
  const float znb = hdr[H_ZN+b];
  float part = 0.f;
  for (int m=tid;m<2000;m+=256){
    float s = sim[(size_t)b*2000+m] / fmaxf(znb * hdr[H_MN+m], 1e-8f);
    float ev = __expf(s);
    e[m] = ev; part += ev;
  }
  for (int o=32;o;o>>=1) part += __shfl_down(part,o,64);
  if ((tid&63)==0) red[tid>>6] = part;
  __syncthreads();
  const float denom = red[0]+red[1]+red[2]+red[3];
  const float t = 1.0f/2000.0f;
  float part2 = 0.f;
  for (int m=tid;m<2000;m+=256){
    float w = e[m]/denom;
    float d = w - t;
    float sh = fmaxf(d,0.f)*w/(fabsf(d)+0.01f);
    e[m] = sh; part2 += sh;
  }
  for (int o=32;o;o>>=1) part2 += __shfl_down(part2,o,64);
  if ((tid&63)==0) red[4+(tid>>6)] = part2;
  __syncthreads();
  const float inv = 1.0f/(red[4]+red[5]+red[6]+red[7]);
  for (int m=tid;m<2016;m+=256){
    ushort_t o = 0;
    if (m < 2000) o = f2bf(e[m]*inv);
    wbf[(size_t)b*2016+m] = o;
  }
}

// ---------------- deconv0: 64->64, k3 s2 p0, 6->13; parity classes, padded LDS grid ----------------
__global__ __launch_bounds__(256) void k_deconv0(
    const float* __restrict__ zh, const float* __restrict__ d0r, const float* __restrict__ b0g,
    float* __restrict__ hdr, float* __restrict__ out){
  __shared__ float inp[4096];   // [ci][8][8] zero-padded (rows/cols 0 and 7)
  const int b = blockIdx.x, tid = threadIdx.x;
  for (int i=tid;i<4096;i+=256){
    int ci = i>>6, rr = (i>>3)&7, cc = i&7;
    float v = 0.f;
    if (rr>=1 && rr<=6 && cc>=1 && cc<=6)
      v = zh[(size_t)b*2304 + ci*36 + (rr-1)*6 + (cc-1)];
    inp[i] = v;
  }
  __syncthreads();
  const int co4 = tid>>4, lane = tid&15;
  float bias[4];
  #pragma unroll
  for (int v=0;v<4;v++) bias[v] = b0g[co4*4+v];
  float sacc[4]={0,0,0,0}, qacc[4]={0,0,0,0};
  const int pis[4]={0,0,1,1}, pjs[4]={0,1,0,1};
  const int ncs[4]={7,6,7,6};
  const int nposs[4]={49,42,42,36};
  #pragma unroll
  for (int cl=0; cl<4; cl++){
    const int pi=pis[cl], pj=pjs[cl], nc=ncs[cl], npos=nposs[cl];
    int a_[4], c_[4]; bool val_[4];
    float acc[4][4];
    #pragma unroll
    for (int u=0;u<4;u++){
      int p = u*16 + lane;
      val_[u] = p < npos;
      int pc = val_[u] ? p : (npos-1);
      a_[u] = pc / nc; c_[u] = pc - a_[u]*nc;
      #pragma unroll
      for (int v=0;v<4;v++) acc[u][v] = bias[v];
    }
    const int nki = (pi==0)?2:1, nkj = (pj==0)?2:1;
    #pragma unroll
    for (int tki=0;tki<2;tki++){ if (tki<nki){
    #pragma unroll
    for (int tkj=0;tkj<2;tkj++){ if (tkj<nkj){
      const int ki = (pi==0)?(tki*2):1;
      const int kj = (pj==0)?(tkj*2):1;
      const int tap = ki*3+kj;
      // padded-grid row index: ii+1; pi=0: ii=a-(ki>>1); pi=1: ii=a
      int idx_[4];
      #pragma unroll
      for (int u=0;u<4;u++){
        int row = a_[u] + 1 - ((pi==0)?(ki>>1):0);
        int col = c_[u] + 1 - ((pj==0)?(kj>>1):0);
        idx_[u] = row*8 + col;
      }
      #pragma unroll 2
      for (int ci=0;ci<64;ci++){
        const float4 wv = *(const float4*)&d0r[((size_t)(tap*64+ci))*64 + co4*4];
        #pragma unroll
        for (int u=0;u<4;u++){
          float xvv = inp[(ci<<6) + idx_[u]];
          acc[u][0] = fmaf(xvv, wv.x, acc[u][0]);
          acc[u][1] = fmaf(xvv, wv.y, acc[u][1]);
          acc[u][2] = fmaf(xvv, wv.z, acc[u][2]);
          acc[u][3] = fmaf(xvv, wv.w, acc[u][3]);
        }
      }
    }}}}
    #pragma unroll
    for (int u=0;u<4;u++) if (val_[u]){
      int oi = 2*a_[u] + pi, oj = 2*c_[u] + pj;
      #pragma unroll
      for (int v=0;v<4;v++){
        float y = acc[u][v];
        out[((size_t)b*64 + co4*4+v)*169 + oi*13 + oj] = y;
        sacc[v] += y; qacc[v] += y*y;
      }
    }
  }
  #pragma unroll
  for (int v=0;v<4;v++){
    float s = sacc[v], q = qacc[v];
    for (int o=8;o;o>>=1){ s += __shfl_down(s,o,16); q += __shfl_down(q,o,16); }
    if (lane==0){ atomicAdd(&hdr[H_DS0+co4*4+v], s); atomicAdd(&hdr[H_DQ0+co4*4+v], q); }
  }
}

// ---------------- deconv1: 64->32, k3 s2 p1, 13->25; two launches over ci-halves ----------------
__global__ __launch_bounds__(256) void k_deconv1(
    const float* __restrict__ g0, const float* __restrict__ d1wg, const float* __restrict__ b1g,
    float* __restrict__ hdr, float* __restrict__ out, int ph){
  __shared__ float inp[5408];   // [cih 32][13x13] post bn0+relu
  __shared__ float wl[9216];    // [tap][cih][co]
  const int b = blockIdx.x, tid = threadIdx.x;
  for (int i=tid;i<5408;i+=256){
    int ci = i/169, pp = i - ci*169;
    int cig = ph*32 + ci;
    float raw = g0[((size_t)b*64 + cig)*169 + pp];
    inp[i] = fmaxf(fmaf(hdr[H_DA0+cig], raw, hdr[H_DC0+cig]), 0.f);
  }
  for (int i=tid;i<9216;i+=256){
    int co = i&31, t = i>>5, cih = t&31, tap = t>>5;
    wl[i] = d1wg[((ph*32+cih)*32 + co)*9 + tap];
  }
  __syncthreads();
  const int co4 = tid>>5, lane = tid&31;
  float bias[4];
  #pragma unroll
  for (int v=0;v<4;v++) bias[v] = b1g[co4*4+v];
  float sacc[4]={0,0,0,0}, qacc[4]={0,0,0,0};
  const int pis[4]={0,0,1,1}, pjs[4]={0,1,0,1};
  const int ncs[4]={13,12,13,12};
  const int nposs[4]={169,156,156,144};
  #pragma unroll
  for (int cl=0; cl<4; cl++){
    const int pi=pis[cl], pj=pjs[cl], nc=ncs[cl], npos=nposs[cl];
    for (int itc=0; itc<2; itc++){
      int a_[4], c_[4]; bool val_[4];
      float acc[4][4];
      #pragma unroll
      for (int u=0;u<4;u++){
        int p = itc*128 + u*32 + lane;
        val_[u] = p < npos;
        int pc = val_[u] ? p : 0;
        a_[u] = pc/nc; c_[u] = pc - a_[u]*nc;
      }
      #pragma unroll
      for (int u=0;u<4;u++){
        int oi = 2*a_[u]+pi, oj = 2*c_[u]+pj;
        #pragma unroll
        for (int v=0;v<4;v++){
          if (ph == 0) acc[u][v] = bias[v];
          else acc[u][v] = val_[u] ? out[((size_t)b*32 + co4*4+v)*625 + oi*25+oj] : 0.f;
        }
      }
      const int nki = (pi==0)?1:2, nkj = (pj==0)?1:2;
      #pragma unroll
      for (int tki=0;tki<2;tki++){ if (tki<nki){
      #pragma unroll
      for (int tkj=0;tkj<2;tkj++){ if (tkj<nkj){
        // pi=0: ki=1, ii=a ; pi=1: ki=2*tki, ii=a+1-tki... (tki=0->a+1, tki=1->a)
        const int ki = (pi==0)?1:(tki*2);
        const int kj = (pj==0)?1:(tkj*2);
        const int tap = ki*3+kj;
        const int ioff = (pi==0)?0:(1-tki);
        const int joff = (pj==0)?0:(1-tkj);
        int idx_[4];
        #pragma unroll
        for (int u=0;u<4;u++) idx_[u] = (a_[u]+ioff)*13 + (c_[u]+joff);
        const float* wt = &wl[tap*1024 + co4*4];
        #pragma unroll 2
        for (int cih=0;cih<32;cih++){
          const float4 wv = *(const float4*)&wt[cih*32];
          #pragma unroll
          for (int u=0;u<4;u++){
            float xvv = inp[cih*169 + idx_[u]];
            acc[u][0] = fmaf(xvv, wv.x, acc[u][0]);
            acc[u][1] = fmaf(xvv, wv.y, acc[u][1]);
            acc[u][2] = fmaf(xvv, wv.z, acc[u][2]);
            acc[u][3] = fmaf(xvv, wv.w, acc[u][3]);
          }
        }
      }}}}
      #pragma unroll
      for (int u=0;u<4;u++) if (val_[u]){
        int oi = 2*a_[u]+pi, oj = 2*c_[u]+pj;
        #pragma unroll
        for (int v=0;v<4;v++){
          float y = acc[u][v];
          out[((size_t)b*32 + co4*4+v)*625 + oi*25+oj] = y;
          if (ph==1){ sacc[v]+=y; qacc[v]+=y*y; }
        }
      }
    }
  }
  if (ph==1){
    #pragma unroll
    for (int v=0;v<4;v++){
      float s = sacc[v], q = qacc[v];
      for (int o=16;o;o>>=1){ s += __shfl_down(s,o,32); q += __shfl_down(q,o,32); }
      if (lane==0){ atomicAdd(&hdr[H_DS1+co4*4+v], s); atomicAdd(&hdr[H_DQ1+co4*4+v], q); }
    }
  }
}

// ---------------- deconv2: 32->16, k2 s2 p1 op1, 25->49; 4 sub-pixel 1x1 convs ----------------
__global__ __launch_bounds__(256) void k_deconv2(
    const float* __restrict__ g1, const float* __restrict__ d2wg, const float* __restrict__ bg,
    float* __restrict__ hdr, float* __restrict__ out){
  __shared__ float inp[10400];   // [ci 32][<=13 rows x 25]
  __shared__ float wl[2048];     // [ci][n=class*16+co]
  const int bh = blockIdx.x, b = bh>>1, hf = bh&1, tid = threadIdx.x;
  const int row0 = hf*13, nrows = hf ? 12 : 13, npos = nrows*25;
  for (int i=tid; i<32*npos; i+=256){
    int ci = i/npos, pp = i - ci*npos;
    float raw = g1[((size_t)b*32+ci)*625 + row0*25 + pp];
    inp[ci*325 + pp] = fmaxf(fmaf(hdr[H_DA1+ci], raw, hdr[H_DC1+ci]), 0.f);
  }
  for (int i=tid;i<2048;i+=256){
    int n = i&63, ci = i>>6;
    int pi = n>>5, pj = (n>>4)&1, co = n&15;
    wl[i] = d2wg[((ci*16+co)*2 + (1-pi))*2 + (1-pj)];
  }
  __syncthreads();
  const int n4 = tid>>4, lane = tid&15;
  float bias[4];
  #pragma unroll
  for (int v=0;v<4;v++) bias[v] = bg[(n4*4+v)&15];
  float sacc[4]={0,0,0,0}, qacc[4]={0,0,0,0};
  const int iters = (npos + 63)>>6;
  for (int itc=0; itc<iters; itc++){
    int p_[4]; bool val_[4];
    float acc[4][4];
    #pragma unroll
    for (int u=0;u<4;u++){
      int p = itc*64 + u*16 + lane;
      val_[u] = p < npos;
      p_[u] = val_[u] ? p : 0;
      #pragma unroll
      for (int v=0;v<4;v++) acc[u][v] = bias[v];
    }
    #pragma unroll 2
    for (int ci=0;ci<32;ci++){
      const float4 wv = *(const float4*)&wl[(ci<<6) + n4*4];
      #pragma unroll
      for (int u=0;u<4;u++){
        float xvv = inp[ci*325 + p_[u]];
        acc[u][0] = fmaf(xvv, wv.x, acc[u][0]);
        acc[u][1] = fmaf(xvv, wv.y, acc[u][1]);
        acc[u][2] = fmaf(xvv, wv.z, acc[u][2]);
        acc[u][3] = fmaf(xvv, wv.w, acc[u][3]);
      }
    }
    #pragma unroll
    for (int u=0;u<4;u++) if (val_[u]){
      int il = p_[u]/25, jj = p_[u] - il*25;
      int ii = row0 + il;
      #pragma unroll
      for (int v=0;v<4;v++){
        int n = n4*4+v, pi = n>>5, pj = (n>>4)&1, co = n&15;
        int oi = 2*ii - pi, oj = 2*jj - pj;
        if (oi>=0 && oj>=0){
          float y = acc[u][v];
          out[((size_t)b*16+co)*2401 + oi*49 + oj] = y;
          sacc[v]+=y; qacc[v]+=y*y;
        }
      }
    }
  }
  #pragma unroll
  for (int v=0;v<4;v++){
    float s = sacc[v], q = qacc[v];
    for (int o=8;o;o>>=1){ s += __shfl_down(s,o,16); q += __shfl_down(q,o,16); }
    if (lane==0){
      atomicAdd(&hdr[H_DS2+((n4*4+v)&15)], s);
      atomicAdd(&hdr[H_DQ2+((n4*4+v)&15)], q);
    }
  }
}

// ---------------- deconv3: 16->1, k2 s2 p0, 49->98, + sigmoid ----------------
__global__ __launch_bounds__(256) void k_deconv3(const float* __restrict__ g2, const float* __restrict__ w,
                                                 const float* __restrict__ bias, const float* __restrict__ hdr,
                                                 float* __restrict__ out){
  int idx = blockIdx.x*256 + threadIdx.x;
  if (idx >= 512*9604) return;
  int b = idx / 9604; int r = idx - b*9604;
  int oi = r / 98, oj = r - oi*98;
  int ki = oi & 1, kj = oj & 1, ii = oi >> 1, jj = oj >> 1;
  float acc = bias[0];
  const float* gp = g2 + (size_t)b*16*2401 + ii*49 + jj;
  #pragma unroll
  for (int ci=0; ci<16; ci++){
    float raw = gp[(size_t)ci*2401];
    float h = fmaxf(fmaf(hdr[H_DA2+ci], raw, hdr[H_DC2+ci]), 0.f);
    acc = fmaf(h, w[ci*4 + ki*2 + kj], acc);
  }
  out[idx] = 1.f/(1.f + __expf(-acc));
}

// ======================================================================
extern "C" void kernel_launch(void* const* d_in, const int* in_sizes, int n_in,
                              void* d_out, int out_size, void* d_ws, size_t ws_size,
                              hipStream_t stream){
  (void)in_sizes; (void)n_in; (void)out_size; (void)ws_size;
  const float* x     = (const float*)d_in[0];
  const float* c1w   = (const float*)d_in[1];
  const float* c1b   = (const float*)d_in[2];
  const float* bn1g  = (const float*)d_in[3];
  const float* bn1b  = (const float*)d_in[4];
  const float* c2w   = (const float*)d_in[5];
  const float* c2b   = (const float*)d_in[6];
  const float* bn2g  = (const float*)d_in[7];
  const float* bn2b  = (const float*)d_in[8];
  const float* c3w   = (const float*)d_in[9];
  const float* c3b   = (const float*)d_in[10];
  const float* bn3g  = (const float*)d_in[11];
  const float* bn3b  = (const float*)d_in[12];
  const float* c4w   = (const float*)d_in[13];
  const float* c4b   = (const float*)d_in[14];
  const float* bn4g  = (const float*)d_in[15];
  const float* bn4b  = (const float*)d_in[16];
  const float* mem   = (const float*)d_in[17];
  const float* d0w   = (const float*)d_in[18];
  const float* d0b   = (const float*)d_in[19];
  const float* dbn0g = (const float*)d_in[20];
  const float* dbn0b = (const float*)d_in[21];
  const float* d1w   = (const float*)d_in[22];
  const float* d1b   = (const float*)d_in[23];
  const float* dbn1g = (const float*)d_in[24];
  const float* dbn1b = (const float*)d_in[25];
  const float* d2w   = (const float*)d_in[26];
  const float* d2b   = (const float*)d_in[27];
  const float* dbn2g = (const float*)d_in[28];
  const float* dbn2b = (const float*)d_in[29];
  const float* d3w   = (const float*)d_in[30];
  const float* d3b   = (const float*)d_in[31];

  float* hdr  = (float*)d_ws;
  float* H2   = hdr + HDR_FLOATS;        // 512*32*625   = 10,240,000  (reused as G1)
  float* H3   = H2 + 10240000;           // 512*64*169   = 5,537,792   (reused as G0)
  float* ZRAW = H3 + 5537792;            // 512*2304
  float* ZH   = ZRAW + 1179648;          // 512*2304
  float* SIM  = ZH + 1179648;            // 512*2000
  float* W4R  = SIM + 1024000;           // 36,864
  float* D0R  = W4R + 36864;             // 36,864
  float* G2   = D0R + 36864;             // 512*16*2401  = 19,668,992
  ushort_t* MEMBF = (ushort_t*)(G2 + 19668992); // 2000*2304
  ushort_t* MEMT  = MEMBF + 4608000;            // 2304*2016
  ushort_t* ZBF   = MEMT + 4644864;             // 512*2304
  ushort_t* WBF   = ZBF + 1179648;              // 512*2016
  float* G0 = H3;
  float* G1 = H2;
  float* OUT = (float*)d_out;

  hipMemsetAsync(hdr, 0, HDR_FLOATS*sizeof(float), stream);
  k_xstats  <<<1024, 256, 0, stream>>>(x, hdr);
  k_coef1   <<<1, 64, 0, stream>>>(hdr, c1w, c1b, bn1g, bn1b);
  k_wprep   <<<288, 256, 0, stream>>>(c4w, d0w, W4R, D0R);
  k_memrows <<<2000, 256, 0, stream>>>(mem, hdr, MEMBF);
  k_memT    <<<72*63, 256, 0, stream>>>(mem, MEMT);
  k_conv2   <<<512, 256, 0, stream>>>(x, c2w, c2b, hdr, H2);
  k_coef    <<<1, 64, 0, stream>>>(hdr+H_S2, hdr+H_Q2, bn2g, bn2b, hdr+H_A2, hdr+H_C2, 32, 1.f/(512.f*625.f));
  k_conv3   <<<512, 256, 0, stream>>>(H2, c3w, c3b, hdr, H3);
  k_coef    <<<1, 64, 0, stream>>>(hdr+H_S3, hdr+H_Q3, bn3g, bn3b, hdr+H_A3, hdr+H_C3, 64, 1.f/(512.f*169.f));
  k_conv4   <<<512, 256, 0, stream>>>(H3, W4R, c4b, hdr, ZRAW);
  k_coef    <<<1, 64, 0, stream>>>(hdr+H_S4, hdr+H_Q4, bn4g, bn4b, hdr+H_A4, hdr+H_C4, 64, 1.f/(512.f*36.f));
  k_z       <<<512, 256, 0, stream>>>(ZRAW, hdr, ZBF);
  k_gemm_bt <<<1000, 256, 0, stream>>>(ZBF, MEMBF, SIM, 125, 2304, 72, 2000);
  k_softmax <<<512, 256, 0, stream>>>(SIM, hdr, WBF);
  k_gemm_bt <<<1152, 256, 0, stream>>>(WBF, MEMT, ZH, 144, 2016, 63, 2304);
  k_deconv0 <<<512, 256, 0, stream>>>(ZH, D0R, d0b, hdr, G0);
  k_coef    <<<1, 64, 0, stream>>>(hdr+H_DS0, hdr+H_DQ0, dbn0g, dbn0b, hdr+H_DA0, hdr+H_DC0, 64, 1.f/(512.f*169.f));
  k_deconv1 <<<512, 256, 0, stream>>>(G0, d1w, d1b, hdr, G1, 0);
  k_deconv1 <<<512, 256, 0, stream>>>(G0, d1w, d1b, hdr, G1, 1);
  k_coef    <<<1, 64, 0, stream>>>(hdr+H_DS1, hdr+H_DQ1, dbn1g, dbn1b, hdr+H_DA1, hdr+H_DC1, 32, 1.f/(512.f*625.f));
  k_deconv2 <<<1024, 256, 0, stream>>>(G1, d2w, d2b, hdr, G2);
  k_coef    <<<1, 64, 0, stream>>>(hdr+H_DS2, hdr+H_DQ2, dbn2g, dbn2b, hdr+H_DA2, hdr+H_DC2, 16, 1.f/(512.f*2401.f));
  k_deconv3 <<<19208, 256, 0, stream>>>(G2, d3w, d3b, hdr, OUT);
}

// Round 2
// 849.029 us; speedup vs baseline: 1.5661x; 1.5661x over previous
//
#include <hip/hip_runtime.h>
#include <stdint.h>

// R2: same structure as R1; stats accumulation de-contended.
// All per-channel sum/sumsq atomics now go to one of 16 bucket banks
// (bank = blockIdx & 15, banks on distinct cache lines); k_coef sums banks.
// k_deconv2 additionally pre-reduces its 4x-duplicated channels in LDS.

typedef unsigned short ushort_t;
typedef __bf16 bf16x8 __attribute__((ext_vector_type(8)));
typedef float f32x4 __attribute__((ext_vector_type(4)));

#define DEV static __device__ __forceinline__

DEV ushort_t f2bf(float f){
  union { float f; uint32_t u; } v; v.f = f;
  return (ushort_t)((v.u + 0x7FFFu + ((v.u >> 16) & 1u)) >> 16);
}

// ---------------- header (stats/coeff) offsets in floats ----------------
#define H_XS   0      // [2] sampled-x sum, sumsq
#define H_A1   16     // [16] folded conv1+bn1 scale (applied to sampled x)
#define H_C1   32     // [16]
#define H_S2   64
#define H_Q2   96
#define H_A2   128
#define H_C2   160
#define H_S3   192
#define H_Q3   256
#define H_A3   320
#define H_C3   384
#define H_S4   448
#define H_Q4   512
#define H_A4   576
#define H_C4   640
#define H_DS0  704
#define H_DQ0  768
#define H_DA0  832
#define H_DC0  896
#define H_DS1  960
#define H_DQ1  992
#define H_DA1  1024
#define H_DC1  1056
#define H_DS2  1088
#define H_DQ2  1104
#define H_DA2  1120
#define H_DC2  1136
#define H_ZN   1152   // [512]
#define H_MN   1664   // [2000]
#define H_BUK  4096   // 16 bucket banks of 1280 floats each
#define NBUK   16
#define BSTRIDE 1280
#define HDR_FLOATS (H_BUK + NBUK*BSTRIDE)   // 24576 floats = 96 KB

DEV float* bkt(float* hdr, int blk){ return hdr + H_BUK + (size_t)(blk & (NBUK-1))*BSTRIDE; }

// ---------------- stats of strided-sampled input (for bn1 fold) ----------------
__global__ __launch_bounds__(256) void k_xstats(const float* __restrict__ x, float* __restrict__ hdr){
  __shared__ float red[8];
  float s = 0.f, q = 0.f;
  const int total = 512*49*49;
  for (int idx = blockIdx.x*256 + threadIdx.x; idx < total; idx += gridDim.x*256){
    int b = idx / 2401;
    int r = idx - b*2401;
    int i = r / 49, j = r - i*49;
    float v = 0.f;
    if (i > 0 && j > 0) v = x[(size_t)b*9216 + (2*i-1)*96 + (2*j-1)];
    s += v; q += v*v;
  }
  for (int o=32;o;o>>=1){ s += __shfl_down(s,o,64); q += __shfl_down(q,o,64); }
  int w = threadIdx.x>>6;
  if ((threadIdx.x&63)==0){ red[w*2]=s; red[w*2+1]=q; }
  __syncthreads();
  if (threadIdx.x==0){
    float* bk = bkt(hdr, blockIdx.x);
    atomicAdd(&bk[H_XS+0], red[0]+red[2]+red[4]+red[6]);
    atomicAdd(&bk[H_XS+1], red[1]+red[3]+red[5]+red[7]);
  }
}

__global__ void k_coef1(float* __restrict__ hdr, const float* __restrict__ c1w,
                        const float* __restrict__ c1b, const float* __restrict__ g,
                        const float* __restrict__ be){
  int c = threadIdx.x;
  if (c < 16){
    const float N = 512.f*49.f*49.f;
    float sx = 0.f, qx = 0.f;
    for (int k=0;k<NBUK;k++){
      sx += hdr[H_BUK + k*BSTRIDE + H_XS+0];
      qx += hdr[H_BUK + k*BSTRIDE + H_XS+1];
    }
    float mx = sx/N;
    float vx = qx/N - mx*mx;
    float mean = c1w[c]*mx + c1b[c];
    float var  = c1w[c]*c1w[c]*vx;
    float a = g[c]*rsqrtf(var + 1e-5f);
    hdr[H_A1+c] = a*c1w[c];
    hdr[H_C1+c] = a*(c1b[c]-mean) + be[c];
  }
}

__global__ void k_coef(const float* __restrict__ buk, int offS, int offQ,
                       const float* __restrict__ g, const float* __restrict__ be,
                       float* __restrict__ A, float* __restrict__ C, int nch, float invN){
  int c = threadIdx.x;
  if (c < nch){
    float s = 0.f, q = 0.f;
    for (int k=0;k<NBUK;k++){
      s += buk[k*BSTRIDE + offS + c];
      q += buk[k*BSTRIDE + offQ + c];
    }
    float m = s*invN;
    float v = q*invN - m*m;
    float a = g[c]*rsqrtf(v + 1e-5f);
    A[c] = a;
    C[c] = be[c] - m*a;
  }
}

// reorder conv4 / deconv0 weights to [tap][ci][co] for coalesced float4 reads
__global__ __launch_bounds__(256) void k_wprep(const float* __restrict__ c4w, const float* __restrict__ d0w,
                                               float* __restrict__ w4r, float* __restrict__ d0r){
  int i = blockIdx.x*256 + threadIdx.x;
  if (i < 36864){
    int co = i&63, ci = (i>>6)&63, tap = i>>12;
    w4r[i] = c4w[(co*64+ci)*9 + tap];        // c4_w [co][ci][3][3]
  } else if (i < 73728){
    int o = i - 36864;
    int co = o&63, ci = (o>>6)&63, tap = o>>12;
    d0r[o] = d0w[(ci*64+co)*9 + tap];        // d0_w [ci][co][3][3]
  }
}

// memory rows -> bf16 + row norms
__global__ __launch_bounds__(256) void k_memrows(const float* __restrict__ mem, float* __restrict__ hdr,
                                                 ushort_t* __restrict__ mbf){
  __shared__ float red[4];
  const int m = blockIdx.x, tid = threadIdx.x;
  float part = 0.f;
  for (int i=tid;i<2304;i+=256){
    float v = mem[(size_t)m*2304+i];
    mbf[(size_t)m*2304+i] = f2bf(v);
    part += v*v;
  }
  for (int o=32;o;o>>=1) part += __shfl_down(part,o,64);
  if ((tid&63)==0) red[tid>>6] = part;
  __syncthreads();
  if (tid==0) hdr[H_MN+m] = sqrtf(red[0]+red[1]+red[2]+red[3]);
}

// memory transpose -> bf16 [2304][2016] (zero-padded K for GEMM2)
__global__ __launch_bounds__(256) void k_memT(const float* __restrict__ mem, ushort_t* __restrict__ mt){
  __shared__ ushort_t tile[32][33];
  const int ft = blockIdx.x % 72, mtile = blockIdx.x / 72;
  const int tx = threadIdx.x & 31, ty = threadIdx.x >> 5;
  #pragma unroll
  for (int r0=0;r0<4;r0++){
    int m = mtile*32 + r0*8 + ty;
    int f = ft*32 + tx;
    float v = (m < 2000) ? mem[(size_t)m*2304 + f] : 0.f;
    tile[r0*8+ty][tx] = f2bf(v);
  }
  __syncthreads();
  #pragma unroll
  for (int r0=0;r0<4;r0++){
    int f = ft*32 + r0*8 + ty;
    mt[(size_t)f*2016 + mtile*32 + tx] = tile[tx][r0*8+ty];
  }
}

// ---------------- conv2: reads x, computes h1=relu(A1*xv+C1) on the fly ----------------
__global__ __launch_bounds__(256) void k_conv2(
    const float* __restrict__ x, const float* __restrict__ w2g, const float* __restrict__ b2g,
    float* __restrict__ hdr, float* __restrict__ out){
  __shared__ float xv[2401];     // strided-sampled x, 49x49
  __shared__ float wl[4608];     // [tap][ci][co]
  const int b = blockIdx.x, tid = threadIdx.x;
  for (int i=tid;i<2401;i+=256){
    int r = i/49, c = i - r*49;
    xv[i] = (r>0 && c>0) ? x[(size_t)b*9216 + (2*r-1)*96 + (2*c-1)] : 0.f;
  }
  for (int i=tid;i<4608;i+=256){
    int co = i & 31, t = i >> 5, ci = t & 15, tap = t >> 4;
    wl[i] = w2g[(co*16+ci)*9 + tap];
  }
  float A1r[16], C1r[16];
  #pragma unroll
  for (int ci=0;ci<16;ci++){ A1r[ci] = hdr[H_A1+ci]; C1r[ci] = hdr[H_C1+ci]; }
  const int co4 = tid>>5, lane = tid&31;
  float bias[4];
  #pragma unroll
  for (int v=0;v<4;v++) bias[v] = b2g[co4*4+v];
  float sacc[4]={0,0,0,0}, qacc[4]={0,0,0,0};
  __syncthreads();
  for (int p0=0;p0<625;p0+=128){
    int p[4], oi[4], oj[4];
    float acc[4][4];
    #pragma unroll
    for (int u=0;u<4;u++){
      p[u] = p0 + u*32 + lane;
      int pc = p[u] < 625 ? p[u] : 624;
      oi[u] = pc/25; oj[u] = pc - oi[u]*25;
      #pragma unroll
      for (int v=0;v<4;v++) acc[u][v] = bias[v];
    }
    #pragma unroll 1
    for (int tap=0; tap<9; tap++){
      int ki = tap/3, kj = tap - ki*3;
      const float* wt = &wl[tap*512 + co4*4];
      float xvv[4], msk[4];
      #pragma unroll
      for (int u=0;u<4;u++){
        int ii = 2*oi[u]-1+ki, jj = 2*oj[u]-1+kj;
        bool ok = (p[u]<625) & ((unsigned)ii<49u) & ((unsigned)jj<49u);
        xvv[u] = xv[ok ? (ii*49+jj) : 0];
        msk[u] = ok ? 1.f : 0.f;
      }
      #pragma unroll
      for (int ci=0;ci<16;ci++){
        const float4 wv = *(const float4*)&wt[ci*32];
        #pragma unroll
        for (int u=0;u<4;u++){
          float h = fmaxf(fmaf(A1r[ci], xvv[u], C1r[ci]), 0.f) * msk[u];
          acc[u][0] = fmaf(h, wv.x, acc[u][0]);
          acc[u][1] = fmaf(h, wv.y, acc[u][1]);
          acc[u][2] = fmaf(h, wv.z, acc[u][2]);
          acc[u][3] = fmaf(h, wv.w, acc[u][3]);
        }
      }
    }
    #pragma unroll
    for (int u=0;u<4;u++) if (p[u] < 625){
      #pragma unroll
      for (int v=0;v<4;v++){
        float y = acc[u][v];
        out[((size_t)b*32 + co4*4+v)*625 + p[u]] = y;
        sacc[v] += y; qacc[v] += y*y;
      }
    }
  }
  float* bk = bkt(hdr, b);
  #pragma unroll
  for (int v=0;v<4;v++){
    float s = sacc[v], q = qacc[v];
    for (int o=16;o;o>>=1){ s += __shfl_down(s,o,32); q += __shfl_down(q,o,32); }
    if (lane==0){ atomicAdd(&bk[H_S2+co4*4+v], s); atomicAdd(&bk[H_Q2+co4*4+v], q); }
  }
}

// ---------------- conv3: 32->64, 3x3 s2 p1, 25->13; 4 ci-quarter phases ----------------
__global__ __launch_bounds__(256) void k_conv3(
    const float* __restrict__ h2, const float* __restrict__ w3g, const float* __restrict__ b3g,
    float* __restrict__ hdr, float* __restrict__ out){
  __shared__ float inp[8*626];   // 8 ci, stride 626 (slot 625 == 0 for OOB taps)
  __shared__ float wl[9*8*64];   // [tap][ci8][co]
  const int b = blockIdx.x, tid = threadIdx.x;
  const int co4 = tid>>4, lane = tid&15;
  float bias[4];
  #pragma unroll
  for (int v=0;v<4;v++) bias[v] = b3g[co4*4+v];
  int oi_[3][4], oj_[3][4];
  float acc[3][4][4];
  #pragma unroll
  for (int it=0;it<3;it++)
  #pragma unroll
  for (int u=0;u<4;u++){
    int p = it*64 + u*16 + lane; if (p > 168) p = 168;
    oi_[it][u] = p/13; oj_[it][u] = p - oi_[it][u]*13;
    #pragma unroll
    for (int v=0;v<4;v++) acc[it][u][v] = bias[v];
  }
  for (int ph=0; ph<4; ph++){
    if (ph) __syncthreads();
    for (int i=tid;i<5008;i+=256){
      int ci8 = i/626, pp = i - ci8*626;
      int ci = ph*8 + ci8;
      float val = 0.f;
      if (pp < 625){
        float raw = h2[((size_t)b*32 + ci)*625 + pp];
        val = fmaxf(fmaf(hdr[H_A2+ci], raw, hdr[H_C2+ci]), 0.f);
      }
      inp[i] = val;
    }
    for (int i=tid;i<4608;i+=256){
      int co = i&63, t = i>>6, ci8 = t&7, tap = t>>3;
      wl[i] = w3g[(co*32 + ph*8 + ci8)*9 + tap];
    }
    __syncthreads();
    #pragma unroll 1
    for (int tap=0; tap<9; tap++){
      int ki = tap/3, kj = tap - ki*3;
      const float* wt = &wl[tap*512 + co4*4];
      #pragma unroll
      for (int it=0;it<3;it++){
        int idxu[4];
        #pragma unroll
        for (int u=0;u<4;u++){
          int p = it*64 + u*16 + lane;
          int ii = 2*oi_[it][u]-1+ki, jj = 2*oj_[it][u]-1+kj;
          bool ok = (p<169) & ((unsigned)ii<25u) & ((unsigned)jj<25u);
          idxu[u] = ok ? (ii*25+jj) : 625;
        }
        #pragma unroll 2
        for (int ci8=0;ci8<8;ci8++){
          const float4 wv = *(const float4*)&wt[ci8*64];
          #pragma unroll
          for (int u=0;u<4;u++){
            float xvv = inp[ci8*626 + idxu[u]];
            acc[it][u][0] = fmaf(xvv, wv.x, acc[it][u][0]);
            acc[it][u][1] = fmaf(xvv, wv.y, acc[it][u][1]);
            acc[it][u][2] = fmaf(xvv, wv.z, acc[it][u][2]);
            acc[it][u][3] = fmaf(xvv, wv.w, acc[it][u][3]);
          }
        }
      }
    }
  }
  float sacc[4]={0,0,0,0}, qacc[4]={0,0,0,0};
  #pragma unroll
  for (int it=0;it<3;it++)
  #pragma unroll
  for (int u=0;u<4;u++){
    int p = it*64 + u*16 + lane;
    if (p < 169){
      #pragma unroll
      for (int v=0;v<4;v++){
        float y = acc[it][u][v];
        out[((size_t)b*64 + co4*4+v)*169 + p] = y;
        sacc[v] += y; qacc[v] += y*y;
      }
    }
  }
  float* bk = bkt(hdr, b);
  #pragma unroll
  for (int v=0;v<4;v++){
    float s = sacc[v], q = qacc[v];
    for (int o=8;o;o>>=1){ s += __shfl_down(s,o,16); q += __shfl_down(q,o,16); }
    if (lane==0){ atomicAdd(&bk[H_S3+co4*4+v], s); atomicAdd(&bk[H_Q3+co4*4+v], q); }
  }
}

// ---------------- conv4: 64->64, 3x3 s2 p0, 13->6 (no padding) ----------------
__global__ __launch_bounds__(256) void k_conv4(
    const float* __restrict__ h3, const float* __restrict__ w4r, const float* __restrict__ b4g,
    float* __restrict__ hdr, float* __restrict__ out){
  __shared__ float inp[10816];   // 64 x 13 x 13, post bn3+relu
  const int b = blockIdx.x, tid = threadIdx.x;
  for (int i=tid;i<10816;i+=256){
    int ci = i/169;
    float raw = h3[(size_t)b*10816 + i];
    inp[i] = fmaxf(fmaf(hdr[H_A3+ci], raw, hdr[H_C3+ci]), 0.f);
  }
  __syncthreads();
  const int co4 = tid>>4, lane = tid&15;
  const bool act = lane < 12;
  float bias[4];
  #pragma unroll
  for (int v=0;v<4;v++) bias[v] = b4g[co4*4+v];
  int base_[3];
  float acc[3][4];
  #pragma unroll
  for (int u=0;u<3;u++){
    int p = u*12 + lane; if (p > 35) p = 35;
    int oi = p/6, oj = p - oi*6;
    base_[u] = (2*oi)*13 + 2*oj;
    #pragma unroll
    for (int v=0;v<4;v++) acc[u][v] = bias[v];
  }
  #pragma unroll 1
  for (int tap=0; tap<9; tap++){
    int ki = tap/3, kj = tap - ki*3;
    const int toff = ki*13 + kj;
    #pragma unroll 2
    for (int ci=0;ci<64;ci++){
      const float4 wv = *(const float4*)&w4r[((size_t)(tap*64+ci))*64 + co4*4];
      #pragma unroll
      for (int u=0;u<3;u++){
        float xvv = inp[ci*169 + base_[u] + toff];
        acc[u][0] = fmaf(xvv, wv.x, acc[u][0]);
        acc[u][1] = fmaf(xvv, wv.y, acc[u][1]);
        acc[u][2] = fmaf(xvv, wv.z, acc[u][2]);
        acc[u][3] = fmaf(xvv, wv.w, acc[u][3]);
      }
    }
  }
  float sacc[4]={0,0,0,0}, qacc[4]={0,0,0,0};
  if (act){
    #pragma unroll
    for (int u=0;u<3;u++){
      int p = u*12 + lane;
      #pragma unroll
      for (int v=0;v<4;v++){
        float y = acc[u][v];
        out[((size_t)b*64 + co4*4+v)*36 + p] = y;
        sacc[v] += y; qacc[v] += y*y;
      }
    }
  }
  float* bk = bkt(hdr, b);
  #pragma unroll
  for (int v=0;v<4;v++){
    float s = sacc[v], q = qacc[v];
    for (int o=8;o;o>>=1){ s += __shfl_down(s,o,16); q += __shfl_down(q,o,16); }
    if (lane==0){ atomicAdd(&bk[H_S4+co4*4+v], s); atomicAdd(&bk[H_Q4+co4*4+v], q); }
  }
}

// z = relu(bn4(conv4 raw)) -> bf16, plus per-row norm
__global__ __launch_bounds__(256) void k_z(const float* __restrict__ zraw, float* __restrict__ hdr,
                                           ushort_t* __restrict__ zbf){
  __shared__ float red[4];
  const int b = blockIdx.x, tid = threadIdx.x;
  float part = 0.f;
  for (int i=tid;i<2304;i+=256){
    int c = i/36;
    float h = fmaxf(fmaf(hdr[H_A4+c], zraw[(size_t)b*2304+i], hdr[H_C4+c]), 0.f);
    zbf[(size_t)b*2304+i] = f2bf(h);
    part += h*h;
  }
  for (int o=32;o;o>>=1) part += __shfl_down(part,o,64);
  if ((tid&63)==0) red[tid>>6] = part;
  __syncthreads();
  if (tid==0) hdr[H_ZN+b] = sqrtf(red[0]+red[1]+red[2]+red[3]);
}

// D[i][j] = sum_k A[i][k]*B[j][k], bf16 in / fp32 out, one 16x16 tile per wave
__global__ __launch_bounds__(256) void k_gemm_bt(const ushort_t* __restrict__ A, const ushort_t* __restrict__ Bm,
                                                 float* __restrict__ D, int Ntiles, int Kp, int kch, int N){
  const int gw = blockIdx.x*4 + (threadIdx.x>>6);
  const int lane = threadIdx.x & 63;
  const int ti = gw / Ntiles, tj = gw - ti*Ntiles;
  const int r = lane & 15, q = lane >> 4;
  const ushort_t* pa = A + (size_t)(ti*16+r)*Kp + q*8;
  const ushort_t* pb = Bm + (size_t)(tj*16+r)*Kp + q*8;
  f32x4 acc = {0.f,0.f,0.f,0.f};
  #pragma unroll 2
  for (int k=0;k<kch;k++){
    bf16x8 av = *(const bf16x8*)(pa + k*32);
    bf16x8 bv = *(const bf16x8*)(pb + k*32);
    acc = __builtin_amdgcn_mfma_f32_16x16x32_bf16(av, bv, acc, 0, 0, 0);
  }
  float* pd = D + (size_t)(ti*16 + q*4)*N + (size_t)tj*16 + r;
  #pragma unroll
  for (int reg=0; reg<4; reg++) pd[(size_t)reg*N] = acc[reg];
}

// softmax over M=2000 + hard-shrink + L1 renorm -> bf16 weights (K padded to 2016)
__global__ __launch_bounds__(256) void k_softmax(const float* __restrict__ sim, float* __restrict__ hdr,
                                                 ushort_t* __restrict__ wbf){
  __shared__ float e[2000];
  __shared__ float red[8];
  const int b = blockIdx.x, tid = threadIdx.x;
  const float znb = hdr[H_ZN+b];
  float part = 0.f;
  for (int m=tid;m<2000;m+=256){
    float s = sim[(size_t)b*2000+m] / fmaxf(znb * hdr[H_MN+m], 1e-8f);
    float ev = __expf(s);
    e[m] = ev; part += ev;
  }
  for (int o=32;o;o>>=1) part += __shfl_down(part,o,64);
  if ((tid&63)==0) red[tid>>6] = part;
  __syncthreads();
  const float denom = red[0]+red[1]+red[2]+red[3];
  const float t = 1.0f/2000.0f;
  float part2 = 0.f;
  for (int m=tid;m<2000;m+=256){
    float w = e[m]/denom;
    float d = w - t;
    float sh = fmaxf(d,0.f)*w/(fabsf(d)+0.01f);
    e[m] = sh; part2 += sh;
  }
  for (int o=32;o;o>>=1) part2 += __shfl_down(part2,o,64);
  if ((tid&63)==0) red[4+(tid>>6)] = part2;
  __syncthreads();
  const float inv = 1.0f/(red[4]+red[5]+red[6]+red[7]);
  for (int m=tid;m<2016;m+=256){
    ushort_t o = 0;
    if (m < 2000) o = f2bf(e[m]*inv);
    wbf[(size_t)b*2016+m] = o;
  }
}

// ---------------- deconv0: 64->64, k3 s2 p0, 6->13; parity classes, padded LDS grid ----------------
__global__ __launch_bounds__(256) void k_deconv0(
    const float* __restrict__ zh, const float* __restrict__ d0r, const float* __restrict__ b0g,
    float* __restrict__ hdr, float* __restrict__ out){
  __shared__ float inp[4096];   // [ci][8][8] zero-padded (rows/cols 0 and 7)
  const int b = blockIdx.x, tid = threadIdx.x;
  for (int i=tid;i<4096;i+=256){
    int ci = i>>6, rr = (i>>3)&7, cc = i&7;
    float v = 0.f;
    if (rr>=1 && rr<=6 && cc>=1 && cc<=6)
      v = zh[(size_t)b*2304 + ci*36 + (rr-1)*6 + (cc-1)];
    inp[i] = v;
  }
  __syncthreads();
  const int co4 = tid>>4, lane = tid&15;
  float bias[4];
  #pragma unroll
  for (int v=0;v<4;v++) bias[v] = b0g[co4*4+v];
  float sacc[4]={0,0,0,0}, qacc[4]={0,0,0,0};
  const int pis[4]={0,0,1,1}, pjs[4]={0,1,0,1};
  const int ncs[4]={7,6,7,6};
  const int nposs[4]={49,42,42,36};
  #pragma unroll
  for (int cl=0; cl<4; cl++){
    const int pi=pis[cl], pj=pjs[cl], nc=ncs[cl], npos=nposs[cl];
    int a_[4], c_[4]; bool val_[4];
    float acc[4][4];
    #pragma unroll
    for (int u=0;u<4;u++){
      int p = u*16 + lane;
      val_[u] = p < npos;
      int pc = val_[u] ? p : (npos-1);
      a_[u] = pc / nc; c_[u] = pc - a_[u]*nc;
      #pragma unroll
      for (int v=0;v<4;v++) acc[u][v] = bias[v];
    }
    const int nki = (pi==0)?2:1, nkj = (pj==0)?2:1;
    #pragma unroll
    for (int tki=0;tki<2;tki++){ if (tki<nki){
    #pragma unroll
    for (int tkj=0;tkj<2;tkj++){ if (tkj<nkj){
      const int ki = (pi==0)?(tki*2):1;
      const int kj = (pj==0)?(tkj*2):1;
      const int tap = ki*3+kj;
      int idx_[4];
      #pragma unroll
      for (int u=0;u<4;u++){
        int row = a_[u] + 1 - ((pi==0)?(ki>>1):0);
        int col = c_[u] + 1 - ((pj==0)?(kj>>1):0);
        idx_[u] = row*8 + col;
      }
      #pragma unroll 2
      for (int ci=0;ci<64;ci++){
        const float4 wv = *(const float4*)&d0r[((size_t)(tap*64+ci))*64 + co4*4];
        #pragma unroll
        for (int u=0;u<4;u++){
          float xvv = inp[(ci<<6) + idx_[u]];
          acc[u][0] = fmaf(xvv, wv.x, acc[u][0]);
          acc[u][1] = fmaf(xvv, wv.y, acc[u][1]);
          acc[u][2] = fmaf(xvv, wv.z, acc[u][2]);
          acc[u][3] = fmaf(xvv, wv.w, acc[u][3]);
        }
      }
    }}}}
    #pragma unroll
    for (int u=0;u<4;u++) if (val_[u]){
      int oi = 2*a_[u] + pi, oj = 2*c_[u] + pj;
      #pragma unroll
      for (int v=0;v<4;v++){
        float y = acc[u][v];
        out[((size_t)b*64 + co4*4+v)*169 + oi*13 + oj] = y;
        sacc[v] += y; qacc[v] += y*y;
      }
    }
  }
  float* bk = bkt(hdr, b);
  #pragma unroll
  for (int v=0;v<4;v++){
    float s = sacc[v], q = qacc[v];
    for (int o=8;o;o>>=1){ s += __shfl_down(s,o,16); q += __shfl_down(q,o,16); }
    if (lane==0){ atomicAdd(&bk[H_DS0+co4*4+v], s); atomicAdd(&bk[H_DQ0+co4*4+v], q); }
  }
}

// ---------------- deconv1: 64->32, k3 s2 p1, 13->25; two launches over ci-halves ----------------
__global__ __launch_bounds__(256) void k_deconv1(
    const float* __restrict__ g0, const float* __restrict__ d1wg, const float* __restrict__ b1g,
    float* __restrict__ hdr, float* __restrict__ out, int ph){
  __shared__ float inp[5408];   // [cih 32][13x13] post bn0+relu
  __shared__ float wl[9216];    // [tap][cih][co]
  const int b = blockIdx.x, tid = threadIdx.x;
  for (int i=tid;i<5408;i+=256){
    int ci = i/169, pp = i - ci*169;
    int cig = ph*32 + ci;
    float raw = g0[((size_t)b*64 + cig)*169 + pp];
    inp[i] = fmaxf(fmaf(hdr[H_DA0+cig], raw, hdr[H_DC0+cig]), 0.f);
  }
  for (int i=tid;i<9216;i+=256){
    int co = i&31, t = i>>5, cih = t&31, tap = t>>5;
    wl[i] = d1wg[((ph*32+cih)*32 + co)*9 + tap];
  }
  __syncthreads();
  const int co4 = tid>>5, lane = tid&31;
  float bias[4];
  #pragma unroll
  for (int v=0;v<4;v++) bias[v] = b1g[co4*4+v];
  float sacc[4]={0,0,0,0}, qacc[4]={0,0,0,0};
  const int pis[4]={0,0,1,1}, pjs[4]={0,1,0,1};
  const int ncs[4]={13,12,13,12};
  const int nposs[4]={169,156,156,144};
  #pragma unroll
  for (int cl=0; cl<4; cl++){
    const int pi=pis[cl], pj=pjs[cl], nc=ncs[cl], npos=nposs[cl];
    for (int itc=0; itc<2; itc++){
      int a_[4], c_[4]; bool val_[4];
      float acc[4][4];
      #pragma unroll
      for (int u=0;u<4;u++){
        int p = itc*128 + u*32 + lane;
        val_[u] = p < npos;
        int pc = val_[u] ? p : 0;
        a_[u] = pc/nc; c_[u] = pc - a_[u]*nc;
      }
      #pragma unroll
      for (int u=0;u<4;u++){
        int oi = 2*a_[u]+pi, oj = 2*c_[u]+pj;
        #pragma unroll
        for (int v=0;v<4;v++){
          if (ph == 0) acc[u][v] = bias[v];
          else acc[u][v] = val_[u] ? out[((size_t)b*32 + co4*4+v)*625 + oi*25+oj] : 0.f;
        }
      }
      const int nki = (pi==0)?1:2, nkj = (pj==0)?1:2;
      #pragma unroll
      for (int tki=0;tki<2;tki++){ if (tki<nki){
      #pragma unroll
      for (int tkj=0;tkj<2;tkj++){ if (tkj<nkj){
        const int ki = (pi==0)?1:(tki*2);
        const int kj = (pj==0)?1:(tkj*2);
        const int tap = ki*3+kj;
        const int ioff = (pi==0)?0:(1-tki);
        const int joff = (pj==0)?0:(1-tkj);
        int idx_[4];
        #pragma unroll
        for (int u=0;u<4;u++) idx_[u] = (a_[u]+ioff)*13 + (c_[u]+joff);
        const float* wt = &wl[tap*1024 + co4*4];
        #pragma unroll 2
        for (int cih=0;cih<32;cih++){
          const float4 wv = *(const float4*)&wt[cih*32];
          #pragma unroll
          for (int u=0;u<4;u++){
            float xvv = inp[cih*169 + idx_[u]];
            acc[u][0] = fmaf(xvv, wv.x, acc[u][0]);
            acc[u][1] = fmaf(xvv, wv.y, acc[u][1]);
            acc[u][2] = fmaf(xvv, wv.z, acc[u][2]);
            acc[u][3] = fmaf(xvv, wv.w, acc[u][3]);
          }
        }
      }}}}
      #pragma unroll
      for (int u=0;u<4;u++) if (val_[u]){
        int oi = 2*a_[u]+pi, oj = 2*c_[u]+pj;
        #pragma unroll
        for (int v=0;v<4;v++){
          float y = acc[u][v];
          out[((size_t)b*32 + co4*4+v)*625 + oi*25+oj] = y;
          if (ph==1){ sacc[v]+=y; qacc[v]+=y*y; }
        }
      }
    }
  }
  if (ph==1){
    float* bk = bkt(hdr, b);
    #pragma unroll
    for (int v=0;v<4;v++){
      float s = sacc[v], q = qacc[v];
      for (int o=16;o;o>>=1){ s += __shfl_down(s,o,32); q += __shfl_down(q,o,32); }
      if (lane==0){ atomicAdd(&bk[H_DS1+co4*4+v], s); atomicAdd(&bk[H_DQ1+co4*4+v], q); }
    }
  }
}

// ---------------- deconv2: 32->16, k2 s2 p1 op1, 25->49; 4 sub-pixel 1x1 convs ----------------
__global__ __launch_bounds__(256) void k_deconv2(
    const float* __restrict__ g1, const float* __restrict__ d2wg, const float* __restrict__ bg,
    float* __restrict__ hdr, float* __restrict__ out){
  __shared__ float inp[10400];   // [ci 32][<=13 rows x 25]
  __shared__ float wl[2048];     // [ci][n=class*16+co]
  __shared__ float sred[32];     // block-level per-channel sum/sumsq
  const int bh = blockIdx.x, b = bh>>1, hf = bh&1, tid = threadIdx.x;
  const int row0 = hf*13, nrows = hf ? 12 : 13, npos = nrows*25;
  if (tid < 32) sred[tid] = 0.f;
  for (int i=tid; i<32*npos; i+=256){
    int ci = i/npos, pp = i - ci*npos;
    float raw = g1[((size_t)b*32+ci)*625 + row0*25 + pp];
    inp[ci*325 + pp] = fmaxf(fmaf(hdr[H_DA1+ci], raw, hdr[H_DC1+ci]), 0.f);
  }
  for (int i=tid;i<2048;i+=256){
    int n = i&63, ci = i>>6;
    int pi = n>>5, pj = (n>>4)&1, co = n&15;
    wl[i] = d2wg[((ci*16+co)*2 + (1-pi))*2 + (1-pj)];
  }
  __syncthreads();
  const int n4 = tid>>4, lane = tid&15;
  float bias[4];
  #pragma unroll
  for (int v=0;v<4;v++) bias[v] = bg[(n4*4+v)&15];
  float sacc[4]={0,0,0,0}, qacc[4]={0,0,0,0};
  const int iters = (npos + 63)>>6;
  for (int itc=0; itc<iters; itc++){
    int p_[4]; bool val_[4];
    float acc[4][4];
    #pragma unroll
    for (int u=0;u<4;u++){
      int p = itc*64 + u*16 + lane;
      val_[u] = p < npos;
      p_[u] = val_[u] ? p : 0;
      #pragma unroll
      for (int v=0;v<4;v++) acc[u][v] = bias[v];
    }
    #pragma unroll 2
    for (int ci=0;ci<32;ci++){
      const float4 wv = *(const float4*)&wl[(ci<<6) + n4*4];
      #pragma unroll
      for (int u=0;u<4;u++){
        float xvv = inp[ci*325 + p_[u]];
        acc[u][0] = fmaf(xvv, wv.x, acc[u][0]);
        acc[u][1] = fmaf(xvv, wv.y, acc[u][1]);
        acc[u][2] = fmaf(xvv, wv.z, acc[u][2]);
        acc[u][3] = fmaf(xvv, wv.w, acc[u][3]);
      }
    }
    #pragma unroll
    for (int u=0;u<4;u++) if (val_[u]){
      int il = p_[u]/25, jj = p_[u] - il*25;
      int ii = row0 + il;
      #pragma unroll
      for (int v=0;v<4;v++){
        int n = n4*4+v, pi = n>>5, pj = (n>>4)&1, co = n&15;
        int oi = 2*ii - pi, oj = 2*jj - pj;
        if (oi>=0 && oj>=0){
          float y = acc[u][v];
          out[((size_t)b*16+co)*2401 + oi*49 + oj] = y;
          sacc[v]+=y; qacc[v]+=y*y;
        }
      }
    }
  }
  // block-level LDS reduction (4 n4-groups alias each channel), then bucketed atomics
  #pragma unroll
  for (int v=0;v<4;v++){
    float s = sacc[v], q = qacc[v];
    for (int o=8;o;o>>=1){ s += __shfl_down(s,o,16); q += __shfl_down(q,o,16); }
    if (lane==0){
      int ch = (n4*4+v)&15;
      atomicAdd(&sred[ch], s);
      atomicAdd(&sred[16+ch], q);
    }
  }
  __syncthreads();
  if (tid < 16)       atomicAdd(&bkt(hdr,bh)[H_DS2+tid], sred[tid]);
  else if (tid < 32)  atomicAdd(&bkt(hdr,bh)[H_DQ2+tid-16], sred[tid]);
}

// ---------------- deconv3: 16->1, k2 s2 p0, 49->98, + sigmoid ----------------
__global__ __launch_bounds__(256) void k_deconv3(const float* __restrict__ g2, const float* __restrict__ w,
                                                 const float* __restrict__ bias, const float* __restrict__ hdr,
                                                 float* __restrict__ out){
  int idx = blockIdx.x*256 + threadIdx.x;
  if (idx >= 512*9604) return;
  int b = idx / 9604; int r = idx - b*9604;
  int oi = r / 98, oj = r - oi*98;
  int ki = oi & 1, kj = oj & 1, ii = oi >> 1, jj = oj >> 1;
  float acc = bias[0];
  const float* gp = g2 + (size_t)b*16*2401 + ii*49 + jj;
  #pragma unroll
  for (int ci=0; ci<16; ci++){
    float raw = gp[(size_t)ci*2401];
    float h = fmaxf(fmaf(hdr[H_DA2+ci], raw, hdr[H_DC2+ci]), 0.f);
    acc = fmaf(h, w[ci*4 + ki*2 + kj], acc);
  }
  out[idx] = 1.f/(1.f + __expf(-acc));
}

// ======================================================================
extern "C" void kernel_launch(void* const* d_in, const int* in_sizes, int n_in,
                              void* d_out, int out_size, void* d_ws, size_t ws_size,
                              hipStream_t stream){
  (void)in_sizes; (void)n_in; (void)out_size; (void)ws_size;
  const float* x     = (const float*)d_in[0];
  const float* c1w   = (const float*)d_in[1];
  const float* c1b   = (const float*)d_in[2];
  const float* bn1g  = (const float*)d_in[3];
  const float* bn1b  = (const float*)d_in[4];
  const float* c2w   = (const float*)d_in[5];
  const float* c2b   = (const float*)d_in[6];
  const float* bn2g  = (const float*)d_in[7];
  const float* bn2b  = (const float*)d_in[8];
  const float* c3w   = (const float*)d_in[9];
  const float* c3b   = (const float*)d_in[10];
  const float* bn3g  = (const float*)d_in[11];
  const float* bn3b  = (const float*)d_in[12];
  const float* c4w   = (const float*)d_in[13];
  const float* c4b   = (const float*)d_in[14];
  const float* bn4g  = (const float*)d_in[15];
  const float* bn4b  = (const float*)d_in[16];
  const float* mem   = (const float*)d_in[17];
  const float* d0w   = (const float*)d_in[18];
  const float* d0b   = (const float*)d_in[19];
  const float* dbn0g = (const float*)d_in[20];
  const float* dbn0b = (const float*)d_in[21];
  const float* d1w   = (const float*)d_in[22];
  const float* d1b   = (const float*)d_in[23];
  const float* dbn1g = (const float*)d_in[24];
  const float* dbn1b = (const float*)d_in[25];
  const float* d2w   = (const float*)d_in[26];
  const float* d2b   = (const float*)d_in[27];
  const float* dbn2g = (const float*)d_in[28];
  const float* dbn2b = (const float*)d_in[29];
  const float* d3w   = (const float*)d_in[30];
  const float* d3b   = (const float*)d_in[31];

  float* hdr  = (float*)d_ws;
  float* H2   = hdr + HDR_FLOATS;        // 512*32*625   = 10,240,000  (reused as G1)
  float* H3   = H2 + 10240000;           // 512*64*169   = 5,537,792   (reused as G0)
  float* ZRAW = H3 + 5537792;            // 512*2304
  float* ZH   = ZRAW + 1179648;          // 512*2304
  float* SIM  = ZH + 1179648;            // 512*2000
  float* W4R  = SIM + 1024000;           // 36,864
  float* D0R  = W4R + 36864;             // 36,864
  float* G2   = D0R + 36864;             // 512*16*2401  = 19,668,992
  ushort_t* MEMBF = (ushort_t*)(G2 + 19668992); // 2000*2304
  ushort_t* MEMT  = MEMBF + 4608000;            // 2304*2016
  ushort_t* ZBF   = MEMT + 4644864;             // 512*2304
  ushort_t* WBF   = ZBF + 1179648;              // 512*2016
  float* G0 = H3;
  float* G1 = H2;
  float* OUT = (float*)d_out;
  float* BUK = hdr + H_BUK;

  hipMemsetAsync(hdr, 0, HDR_FLOATS*sizeof(float), stream);
  k_xstats  <<<1024, 256, 0, stream>>>(x, hdr);
  k_coef1   <<<1, 64, 0, stream>>>(hdr, c1w, c1b, bn1g, bn1b);
  k_wprep   <<<288, 256, 0, stream>>>(c4w, d0w, W4R, D0R);
  k_memrows <<<2000, 256, 0, stream>>>(mem, hdr, MEMBF);
  k_memT    <<<72*63, 256, 0, stream>>>(mem, MEMT);
  k_conv2   <<<512, 256, 0, stream>>>(x, c2w, c2b, hdr, H2);
  k_coef    <<<1, 64, 0, stream>>>(BUK, H_S2, H_Q2, bn2g, bn2b, hdr+H_A2, hdr+H_C2, 32, 1.f/(512.f*625.f));
  k_conv3   <<<512, 256, 0, stream>>>(H2, c3w, c3b, hdr, H3);
  k_coef    <<<1, 64, 0, stream>>>(BUK, H_S3, H_Q3, bn3g, bn3b, hdr+H_A3, hdr+H_C3, 64, 1.f/(512.f*169.f));
  k_conv4   <<<512, 256, 0, stream>>>(H3, W4R, c4b, hdr, ZRAW);
  k_coef    <<<1, 64, 0, stream>>>(BUK, H_S4, H_Q4, bn4g, bn4b, hdr+H_A4, hdr+H_C4, 64, 1.f/(512.f*36.f));
  k_z       <<<512, 256, 0, stream>>>(ZRAW, hdr, ZBF);
  k_gemm_bt <<<1000, 256, 0, stream>>>(ZBF, MEMBF, SIM, 125, 2304, 72, 2000);
  k_softmax <<<512, 256, 0, stream>>>(SIM, hdr, WBF);
  k_gemm_bt <<<1152, 256, 0, stream>>>(WBF, MEMT, ZH, 144, 2016, 63, 2304);
  k_deconv0 <<<512, 256, 0, stream>>>(ZH, D0R, d0b, hdr, G0);
  k_coef    <<<1, 64, 0, stream>>>(BUK, H_DS0, H_DQ0, dbn0g, dbn0b, hdr+H_DA0, hdr+H_DC0, 64, 1.f/(512.f*169.f));
  k_deconv1 <<<512, 256, 0, stream>>>(G0, d1w, d1b, hdr, G1, 0);
  k_deconv1 <<<512, 256, 0, stream>>>(G0, d1w, d1b, hdr, G1, 1);
  k_coef    <<<1, 64, 0, stream>>>(BUK, H_DS1, H_DQ1, dbn1g, dbn1b, hdr+H_DA1, hdr+H_DC1, 32, 1.f/(512.f*625.f));
  k_deconv2 <<<1024, 256, 0, stream>>>(G1, d2w, d2b, hdr, G2);
  k_coef    <<<1, 64, 0, stream>>>(BUK, H_DS2, H_DQ2, dbn2g, dbn2b, hdr+H_DA2, hdr+H_DC2, 16, 1.f/(512.f*2401.f));
  k_deconv3 <<<19208, 256, 0, stream>>>(G2, d3w, d3b, hdr, OUT);
}

// Round 4
// 522.090 us; speedup vs baseline: 2.5469x; 1.6262x over previous
//
#include <hip/hip_runtime.h>
#include <stdint.h>

// R4: R3 (MFMA implicit-GEMM conv stack) + fix conv2m padding-semantics bug:
// conv2's pad ring must stage 0.0, not relu(C1) — only cells inside the
// 49x49 conv1-output grid get the BN-affine+relu treatment.

typedef unsigned short ushort_t;
typedef __bf16 bf16x8 __attribute__((ext_vector_type(8)));
typedef float f32x4 __attribute__((ext_vector_type(4)));

#define DEV static __device__ __forceinline__

DEV ushort_t f2bf(float f){
  union { float f; uint32_t u; } v; v.f = f;
  return (ushort_t)((v.u + 0x7FFFu + ((v.u >> 16) & 1u)) >> 16);
}

// ---------------- header (stats/coeff) offsets in floats ----------------
#define H_XS   0
#define H_S2   64
#define H_Q2   96
#define H_S3   192
#define H_Q3   256
#define H_S4   448
#define H_Q4   512
#define H_DS0  704
#define H_DQ0  768
#define H_DS1  960
#define H_DQ1  992
#define H_DS2  1088
#define H_DQ2  1104
#define H_ZN   1152   // [512]
#define H_MN   1664   // [2000]
#define H_BUK  4096   // 16 bucket banks of 1280 floats each
#define NBUK   16
#define BSTRIDE 1280
#define HDR_FLOATS (H_BUK + NBUK*BSTRIDE)

// packed-weight (bf16) offsets in WPK
#define OW2 0        // [32][160]  k=tap*16+ci, taps 0..9 (tap9 = zero pad)
#define OW3 5120     // [64][288]  k=tap*32+ci
#define OW4 23552    // [64][576]  k=tap*64+ci
#define OD0 60416    // 4 classes [64][K], K={256,128,128,64}
#define OD1 97280    // 4 classes [32][K], K={64,128,128,256}
#define OD2 115712   // 4 classes [16][32]
#define NWPK 117760

DEV float* bkt(float* hdr, int blk){ return hdr + H_BUK + (size_t)(blk & (NBUK-1))*BSTRIDE; }

// compute per-channel affine (a,c) from buckets into LDS ac[2*nch]
DEV void coef_lds(const float* __restrict__ hdr, int offS, int offQ,
                  const float* __restrict__ g, const float* __restrict__ be,
                  float* ac, int nch, float invN, int tid){
  if (tid < nch){
    float s = 0.f, q = 0.f;
    #pragma unroll
    for (int k=0;k<NBUK;k++){
      s += hdr[H_BUK + k*BSTRIDE + offS + tid];
      q += hdr[H_BUK + k*BSTRIDE + offQ + tid];
    }
    float m = s*invN;
    float v = q*invN - m*m;
    float a = g[tid]*rsqrtf(v + 1e-5f);
    ac[tid] = a;
    ac[nch+tid] = be[tid] - m*a;
  }
}

// ---------------- stats of strided-sampled input (for bn1 fold) ----------------
__global__ __launch_bounds__(256) void k_xstats(const float* __restrict__ x, float* __restrict__ hdr){
  __shared__ float red[8];
  float s = 0.f, q = 0.f;
  const int total = 512*49*49;
  for (int idx = blockIdx.x*256 + threadIdx.x; idx < total; idx += gridDim.x*256){
    int b = idx / 2401;
    int r = idx - b*2401;
    int i = r / 49, j = r - i*49;
    float v = 0.f;
    if (i > 0 && j > 0) v = x[(size_t)b*9216 + (2*i-1)*96 + (2*j-1)];
    s += v; q += v*v;
  }
  for (int o=32;o;o>>=1){ s += __shfl_down(s,o,64); q += __shfl_down(q,o,64); }
  int w = threadIdx.x>>6;
  if ((threadIdx.x&63)==0){ red[w*2]=s; red[w*2+1]=q; }
  __syncthreads();
  if (threadIdx.x==0){
    float* bk = bkt(hdr, blockIdx.x);
    atomicAdd(&bk[H_XS+0], red[0]+red[2]+red[4]+red[6]);
    atomicAdd(&bk[H_XS+1], red[1]+red[3]+red[5]+red[7]);
  }
}

// ---------------- pack all conv/deconv weights to bf16 [co][k] ----------------
__global__ __launch_bounds__(256) void k_wprep2(
    const float* __restrict__ c2w, const float* __restrict__ c3w, const float* __restrict__ c4w,
    const float* __restrict__ d0w, const float* __restrict__ d1w, const float* __restrict__ d2w,
    ushort_t* __restrict__ WPK){
  int i = blockIdx.x*256 + threadIdx.x;
  if (i >= NWPK) return;
  float val = 0.f;
  if (i < OW3){                       // conv2 [32][160]
    int co = i/160, k = i - co*160, tap = k>>4, ci = k&15;
    if (tap < 9) val = c2w[(co*16+ci)*9+tap];
  } else if (i < OW4){                // conv3 [64][288]
    int r = i - OW3; int co = r/288, k = r - co*288, tap = k>>5, ci = k&31;
    val = c3w[(co*32+ci)*9+tap];
  } else if (i < OD0){                // conv4 [64][576]
    int r = i - OW4; int co = r/576, k = r - co*576, tap = k>>6, ci = k&63;
    val = c4w[(co*64+ci)*9+tap];
  } else if (i < OD1){                // deconv0 classes
    int r = i - OD0;
    const int base[4]={0,16384,24576,32768}, K[4]={256,128,128,64};
    const int T0[4][4] = {{0,2,6,8},{1,7,0,0},{3,5,0,0},{4,0,0,0}};
    int cl = (r<16384)?0:(r<24576)?1:(r<32768)?2:3;
    int rr = r - base[cl]; int co = rr/K[cl], k = rr - co*K[cl], t = k>>6, ci = k&63;
    val = d0w[(ci*64+co)*9 + T0[cl][t]];
  } else if (i < OD2){                // deconv1 classes
    int r = i - OD1;
    const int base[4]={0,2048,6144,10240}, K[4]={64,128,128,256};
    const int T1[4][4] = {{4,0,0,0},{3,5,0,0},{1,7,0,0},{0,2,6,8}};
    int cl = (r<2048)?0:(r<6144)?1:(r<10240)?2:3;
    int rr = r - base[cl]; int co = rr/K[cl], k = rr - co*K[cl], t = k>>6, ci = k&63;
    val = d1w[(ci*32+co)*9 + T1[cl][t]];
  } else {                            // deconv2 classes [4][16][32]
    int r = i - OD2;
    int cl = r>>9, s = r&511, co = s>>5, ci = s&31;
    const int pis[4]={0,0,1,1}, pjs[4]={0,1,0,1};
    val = d2w[((ci*16+co)*2 + (1-pis[cl]))*2 + (1-pjs[cl])];
  }
  WPK[i] = f2bf(val);
}

// ---------------- memory rows -> bf16 + row norms ----------------
__global__ __launch_bounds__(256) void k_memrows(const float* __restrict__ mem, float* __restrict__ hdr,
                                                 ushort_t* __restrict__ mbf){
  __shared__ float red[4];
  const int m = blockIdx.x, tid = threadIdx.x;
  float part = 0.f;
  for (int i=tid;i<2304;i+=256){
    float v = mem[(size_t)m*2304+i];
    mbf[(size_t)m*2304+i] = f2bf(v);
    part += v*v;
  }
  for (int o=32;o;o>>=1) part += __shfl_down(part,o,64);
  if ((tid&63)==0) red[tid>>6] = part;
  __syncthreads();
  if (tid==0) hdr[H_MN+m] = sqrtf(red[0]+red[1]+red[2]+red[3]);
}

__global__ __launch_bounds__(256) void k_memT(const float* __restrict__ mem, ushort_t* __restrict__ mt){
  __shared__ ushort_t tile[32][33];
  const int ft = blockIdx.x % 72, mtile = blockIdx.x / 72;
  const int tx = threadIdx.x & 31, ty = threadIdx.x >> 5;
  #pragma unroll
  for (int r0=0;r0<4;r0++){
    int m = mtile*32 + r0*8 + ty;
    int f = ft*32 + tx;
    float v = (m < 2000) ? mem[(size_t)m*2304 + f] : 0.f;
    tile[r0*8+ty][tx] = f2bf(v);
  }
  __syncthreads();
  #pragma unroll
  for (int r0=0;r0<4;r0++){
    int f = ft*32 + r0*8 + ty;
    mt[(size_t)f*2016 + mtile*32 + tx] = tile[tx][r0*8+ty];
  }
}

// ---------------- conv2 (MFMA): 16->32, 3x3 s2 p1 on folded conv1 output ----------------
__global__ __launch_bounds__(256) void k_conv2m(
    const float* __restrict__ x, const ushort_t* __restrict__ WPK, const float* __restrict__ b2g,
    const float* __restrict__ c1w, const float* __restrict__ c1b,
    const float* __restrict__ bn1g, const float* __restrict__ bn1b,
    float* __restrict__ hdr, float* __restrict__ out){
  __shared__ ushort_t inp[27*51*16];    // [row][col][ci16], halo'd 51-grid rows [2*ro..2*ro+26]
  __shared__ float ac[32];
  const int blk = blockIdx.x, b = blk>>1, h = blk&1, tid = threadIdx.x;
  const int ro = h*13, nr = h?12:13, npos = nr*25, ntiles = (npos+15)>>4;
  if (tid < 16){
    float sx=0.f, qx=0.f;
    #pragma unroll
    for (int k=0;k<NBUK;k++){ sx += hdr[H_BUK+k*BSTRIDE+H_XS]; qx += hdr[H_BUK+k*BSTRIDE+H_XS+1]; }
    const float N = 512.f*49.f*49.f;
    float mx = sx/N, vx = qx/N - mx*mx;
    float mean = c1w[tid]*mx + c1b[tid];
    float a = bn1g[tid]*rsqrtf(c1w[tid]*c1w[tid]*vx + 1e-5f);
    ac[tid] = a*c1w[tid];
    ac[16+tid] = a*(c1b[tid]-mean) + bn1b[tid];
  }
  __syncthreads();
  for (int e = tid; e < 27*51; e += 256){
    int lr = e/51, gc = e - lr*51;
    int grg = 2*ro + lr;
    // inside: cell is within the 49x49 conv1-output grid (else conv2 pad => 0)
    bool inside = (grg>=1 && grg<=49 && gc>=1 && gc<=49);
    float v = 0.f;
    if (grg>=2 && grg<=49 && gc>=2 && gc<=49) v = x[(size_t)b*9216 + (2*grg-3)*96 + (2*gc-3)];
    ushort_t hv[16];
    if (inside){
      #pragma unroll
      for (int c=0;c<16;c++) hv[c] = f2bf(fmaxf(fmaf(ac[c], v, ac[16+c]), 0.f));
    } else {
      #pragma unroll
      for (int c=0;c<16;c++) hv[c] = 0;
    }
    uint32_t w0[8];
    #pragma unroll
    for (int c=0;c<8;c++) w0[c] = (uint32_t)hv[2*c] | ((uint32_t)hv[2*c+1]<<16);
    uint4* dst = (uint4*)&inp[e*16];
    dst[0] = make_uint4(w0[0],w0[1],w0[2],w0[3]);
    dst[1] = make_uint4(w0[4],w0[5],w0[6],w0[7]);
  }
  __syncthreads();
  const int wv = tid>>6, lane = tid&63, r = lane&15, q = lane>>4;
  const int cotile = wv&1;
  bf16x8 af[5];
  #pragma unroll
  for (int c=0;c<5;c++) af[c] = *(const bf16x8*)(WPK + OW2 + (cotile*16+r)*160 + c*32 + q*8);
  float biasr[4];
  #pragma unroll
  for (int v=0;v<4;v++) biasr[v] = b2g[cotile*16 + q*4 + v];
  const int TOFF[10] = {0,1,2,51,52,53,102,103,104,0};
  const int qhi = q>>1, ci0 = (q&1)*8;
  float sacc[4]={0,0,0,0}, qacc[4]={0,0,0,0};
  for (int t = wv>>1; t < ntiles; t += 2){
    int p = t*16 + r;
    bool ok = p < npos;
    int pc = ok ? p : 0;
    int a_ = pc/25, c_ = pc - a_*25;
    int pb = (2*a_)*51 + 2*c_;
    f32x4 acc = {0.f,0.f,0.f,0.f};
    #pragma unroll
    for (int c=0;c<5;c++){
      int toff = qhi ? TOFF[2*c+1] : TOFF[2*c];
      bf16x8 bv = *(const bf16x8*)&inp[(pb + toff)*16 + ci0];
      acc = __builtin_amdgcn_mfma_f32_16x16x32_bf16(af[c], bv, acc, 0, 0, 0);
    }
    if (ok){
      int pg = (ro + a_)*25 + c_;
      #pragma unroll
      for (int reg=0;reg<4;reg++){
        float y = acc[reg] + biasr[reg];
        out[((size_t)b*32 + cotile*16 + q*4 + reg)*625 + pg] = y;
        sacc[reg] += y; qacc[reg] += y*y;
      }
    }
  }
  float* bk = bkt(hdr, blk);
  #pragma unroll
  for (int reg=0;reg<4;reg++){
    float s = sacc[reg], qq = qacc[reg];
    for (int o=8;o;o>>=1){ s += __shfl_down(s,o,16); qq += __shfl_down(qq,o,16); }
    if (r==0){ atomicAdd(&bk[H_S2+cotile*16+q*4+reg], s); atomicAdd(&bk[H_Q2+cotile*16+q*4+reg], qq); }
  }
}

// ---------------- conv3 (MFMA): 32->64, 3x3 s2 p1, 25->13 ----------------
__global__ __launch_bounds__(256) void k_conv3m(
    const float* __restrict__ h2, const ushort_t* __restrict__ WPK, const float* __restrict__ b3g,
    const float* __restrict__ g, const float* __restrict__ be,
    float* __restrict__ hdr, float* __restrict__ out){
  __shared__ ushort_t inp[27*27*32];   // [cell][ci32], halo'd 27-grid
  __shared__ float ac[64];
  const int b = blockIdx.x, tid = threadIdx.x;
  coef_lds(hdr, H_S2, H_Q2, g, be, ac, 32, 1.f/(512.f*625.f), tid);
  __syncthreads();
  for (int e = tid; e < 27*27*32; e += 256){
    int ci = e & 31, cell = e >> 5;
    int gr = cell/27, gc = cell - gr*27;
    int i = gr-1, j = gc-1;
    float v = 0.f;
    if ((unsigned)i < 25u && (unsigned)j < 25u){
      float raw = h2[((size_t)b*32 + ci)*625 + i*25 + j];
      v = fmaxf(fmaf(ac[ci], raw, ac[32+ci]), 0.f);
    }
    inp[e] = f2bf(v);
  }
  __syncthreads();
  const int wv = tid>>6, lane = tid&63, r = lane&15, q = lane>>4;
  bf16x8 af[9];
  #pragma unroll
  for (int c=0;c<9;c++) af[c] = *(const bf16x8*)(WPK + OW3 + (wv*16+r)*288 + c*32 + q*8);
  float biasr[4];
  #pragma unroll
  for (int v=0;v<4;v++) biasr[v] = b3g[wv*16 + q*4 + v];
  const int TOFF[9] = {0,1,2,27,28,29,54,55,56};
  const int ci0 = q*8;
  float sacc[4]={0,0,0,0}, qacc[4]={0,0,0,0};
  for (int t = 0; t < 11; t++){
    int p = t*16 + r;
    bool ok = p < 169;
    int pc = ok ? p : 0;
    int a_ = pc/13, c_ = pc - a_*13;
    int pb = (2*a_)*27 + 2*c_;
    f32x4 acc = {0.f,0.f,0.f,0.f};
    #pragma unroll
    for (int c=0;c<9;c++){
      bf16x8 bv = *(const bf16x8*)&inp[(pb + TOFF[c])*32 + ci0];
      acc = __builtin_amdgcn_mfma_f32_16x16x32_bf16(af[c], bv, acc, 0, 0, 0);
    }
    if (ok){
      #pragma unroll
      for (int reg=0;reg<4;reg++){
        float y = acc[reg] + biasr[reg];
        out[((size_t)b*64 + wv*16 + q*4 + reg)*169 + p] = y;
        sacc[reg] += y; qacc[reg] += y*y;
      }
    }
  }
  float* bk = bkt(hdr, b);
  #pragma unroll
  for (int reg=0;reg<4;reg++){
    float s = sacc[reg], qq = qacc[reg];
    for (int o=8;o;o>>=1){ s += __shfl_down(s,o,16); qq += __shfl_down(qq,o,16); }
    if (r==0){ atomicAdd(&bk[H_S3+wv*16+q*4+reg], s); atomicAdd(&bk[H_Q3+wv*16+q*4+reg], qq); }
  }
}

// ---------------- conv4 (MFMA): 64->64, 3x3 s2 p0, 13->6 ----------------
__global__ __launch_bounds__(256) void k_conv4m(
    const float* __restrict__ h3, const ushort_t* __restrict__ WPK, const float* __restrict__ b4g,
    const float* __restrict__ g, const float* __restrict__ be,
    float* __restrict__ hdr, float* __restrict__ out){
  __shared__ ushort_t inp[169*64];     // [cell][ci64]
  __shared__ float ac[128];
  const int b = blockIdx.x, tid = threadIdx.x;
  coef_lds(hdr, H_S3, H_Q3, g, be, ac, 64, 1.f/(512.f*169.f), tid);
  __syncthreads();
  for (int e = tid; e < 169*64; e += 256){
    int ci = e & 63, cell = e >> 6;
    float raw = h3[((size_t)b*64 + ci)*169 + cell];
    inp[e] = f2bf(fmaxf(fmaf(ac[ci], raw, ac[64+ci]), 0.f));
  }
  __syncthreads();
  const int wv = tid>>6, lane = tid&63, r = lane&15, q = lane>>4;
  bf16x8 af[18];
  #pragma unroll
  for (int c=0;c<18;c++) af[c] = *(const bf16x8*)(WPK + OW4 + (wv*16+r)*576 + c*32 + q*8);
  float biasr[4];
  #pragma unroll
  for (int v=0;v<4;v++) biasr[v] = b4g[wv*16 + q*4 + v];
  const int TOFF[9] = {0,1,2,13,14,15,26,27,28};
  float sacc[4]={0,0,0,0}, qacc[4]={0,0,0,0};
  for (int t = 0; t < 3; t++){
    int p = t*16 + r;
    bool ok = p < 36;
    int pc = ok ? p : 0;
    int a_ = pc/6, c_ = pc - a_*6;
    int pb = (2*a_)*13 + 2*c_;
    f32x4 acc = {0.f,0.f,0.f,0.f};
    #pragma unroll
    for (int c=0;c<18;c++){
      int ci0 = (c&1)*32 + q*8;
      bf16x8 bv = *(const bf16x8*)&inp[(pb + TOFF[c>>1])*64 + ci0];
      acc = __builtin_amdgcn_mfma_f32_16x16x32_bf16(af[c], bv, acc, 0, 0, 0);
    }
    if (ok){
      #pragma unroll
      for (int reg=0;reg<4;reg++){
        float y = acc[reg] + biasr[reg];
        out[((size_t)b*64 + wv*16 + q*4 + reg)*36 + p] = y;
        sacc[reg] += y; qacc[reg] += y*y;
      }
    }
  }
  float* bk = bkt(hdr, b);
  #pragma unroll
  for (int reg=0;reg<4;reg++){
    float s = sacc[reg], qq = qacc[reg];
    for (int o=8;o;o>>=1){ s += __shfl_down(s,o,16); qq += __shfl_down(qq,o,16); }
    if (r==0){ atomicAdd(&bk[H_S4+wv*16+q*4+reg], s); atomicAdd(&bk[H_Q4+wv*16+q*4+reg], qq); }
  }
}

// z = relu(bn4(conv4 raw)) -> bf16, plus per-row norm (computes A4/C4 itself)
__global__ __launch_bounds__(256) void k_z(const float* __restrict__ zraw, float* __restrict__ hdr,
                                           ushort_t* __restrict__ zbf,
                                           const float* __restrict__ g, const float* __restrict__ be){
  __shared__ float ac[128];
  __shared__ float red[4];
  const int b = blockIdx.x, tid = threadIdx.x;
  coef_lds(hdr, H_S4, H_Q4, g, be, ac, 64, 1.f/(512.f*36.f), tid);
  __syncthreads();
  float part = 0.f;
  for (int i=tid;i<2304;i+=256){
    int c = i/36;
    float h = fmaxf(fmaf(ac[c], zraw[(size_t)b*2304+i], ac[64+c]), 0.f);
    zbf[(size_t)b*2304+i] = f2bf(h);
    part += h*h;
  }
  for (int o=32;o;o>>=1) part += __shfl_down(part,o,64);
  if ((tid&63)==0) red[tid>>6] = part;
  __syncthreads();
  if (tid==0) hdr[H_ZN+b] = sqrtf(red[0]+red[1]+red[2]+red[3]);
}

// D[i][j] = sum_k A[i][k]*B[j][k], bf16 in / fp32 out, one 16x16 tile per wave
__global__ __launch_bounds__(256) void k_gemm_bt(const ushort_t* __restrict__ A, const ushort_t* __restrict__ Bm,
                                                 float* __restrict__ D, int Ntiles, int Kp, int kch, int N){
  const int gw = blockIdx.x*4 + (threadIdx.x>>6);
  const int lane = threadIdx.x & 63;
  const int ti = gw / Ntiles, tj = gw - ti*Ntiles;
  const int r = lane & 15, q = lane >> 4;
  const ushort_t* pa = A + (size_t)(ti*16+r)*Kp + q*8;
  const ushort_t* pb = Bm + (size_t)(tj*16+r)*Kp + q*8;
  f32x4 acc = {0.f,0.f,0.f,0.f};
  #pragma unroll 2
  for (int k=0;k<kch;k++){
    bf16x8 av = *(const bf16x8*)(pa + k*32);
    bf16x8 bv = *(const bf16x8*)(pb + k*32);
    acc = __builtin_amdgcn_mfma_f32_16x16x32_bf16(av, bv, acc, 0, 0, 0);
  }
  float* pd = D + (size_t)(ti*16 + q*4)*N + (size_t)tj*16 + r;
  #pragma unroll
  for (int reg=0; reg<4; reg++) pd[(size_t)reg*N] = acc[reg];
}

// softmax over M=2000 + hard-shrink + L1 renorm -> bf16 weights (K padded to 2016)
__global__ __launch_bounds__(256) void k_softmax(const float* __restrict__ sim, float* __restrict__ hdr,
                                                 ushort_t* __restrict__ wbf){
  __shared__ float e[2000];
  __shared__ float red[8];
  const int b = blockIdx.x, tid = threadIdx.x;
  const float znb = hdr[H_ZN+b];
  float part = 0.f;
  for (int m=tid;m<2000;m+=256){
    float s = sim[(size_t)b*2000+m] / fmaxf(znb * hdr[H_MN+m], 1e-8f);
    float ev = __expf(s);
    e[m] = ev; part += ev;
  }
  for (int o=32;o;o>>=1) part += __shfl_down(part,o,64);
  if ((tid&63)==0) red[tid>>6] = part;
  __syncthreads();
  const float denom = red[0]+red[1]+red[2]+red[3];
  const float t = 1.0f/2000.0f;
  float part2 = 0.f;
  for (int m=tid;m<2000;m+=256){
    float w = e[m]/denom;
    float d = w - t;
    float sh = fmaxf(d,0.f)*w/(fabsf(d)+0.01f);
    e[m] = sh; part2 += sh;
  }
  for (int o=32;o;o>>=1) part2 += __shfl_down(part2,o,64);
  if ((tid&63)==0) red[4+(tid>>6)] = part2;
  __syncthreads();
  const float inv = 1.0f/(red[4]+red[5]+red[6]+red[7]);
  for (int m=tid;m<2016;m+=256){
    ushort_t o = 0;
    if (m < 2000) o = f2bf(e[m]*inv);
    wbf[(size_t)b*2016+m] = o;
  }
}

// ---------------- deconv0 (MFMA): 64->64, k3 s2 p0, 6->13 ----------------
__global__ __launch_bounds__(256) void k_deconv0m(
    const float* __restrict__ zh, const ushort_t* __restrict__ WPK, const float* __restrict__ b0g,
    float* __restrict__ hdr, float* __restrict__ out){
  __shared__ ushort_t inp[64*64];      // [cell 8x8 halo][ci64]
  const int b = blockIdx.x, tid = threadIdx.x;
  for (int e = tid; e < 64*64; e += 256){
    int ci = e & 63, cell = e >> 6;
    int r8 = cell>>3, c8 = cell&7;
    float v = 0.f;
    if (r8>=1 && r8<=6 && c8>=1 && c8<=6)
      v = zh[(size_t)b*2304 + ci*36 + (r8-1)*6 + (c8-1)];
    inp[e] = f2bf(v);
  }
  __syncthreads();
  const int wv = tid>>6, lane = tid&63, r = lane&15, q = lane>>4;
  float biasr[4];
  #pragma unroll
  for (int v=0;v<4;v++) biasr[v] = b0g[wv*16 + q*4 + v];
  const int NCOL[4]={7,6,7,6}, NPOS[4]={49,42,42,36}, NT[4]={4,3,3,3},
            NCH[4]={8,4,4,2}, KB[4]={0,16384,24576,32768}, KK[4]={256,128,128,64},
            PI[4]={0,0,1,1}, PJ[4]={0,1,0,1};
  const int TOFF[4][4] = {{9,8,1,0},{9,1,0,0},{9,8,0,0},{9,0,0,0}};
  float sacc[4]={0,0,0,0}, qacc[4]={0,0,0,0};
  #pragma unroll
  for (int cl=0; cl<4; cl++){
    bf16x8 af[8];
    #pragma unroll
    for (int m=0;m<NCH[cl];m++)
      af[m] = *(const bf16x8*)(WPK + OD0 + KB[cl] + (wv*16+r)*KK[cl] + m*32 + q*8);
    for (int t = 0; t < NT[cl]; t++){
      int p = t*16 + r;
      bool ok = p < NPOS[cl];
      int pc = ok ? p : 0;
      int a_ = pc/NCOL[cl], c_ = pc - a_*NCOL[cl];
      int pb = a_*8 + c_;
      f32x4 acc = {0.f,0.f,0.f,0.f};
      #pragma unroll
      for (int m=0;m<NCH[cl];m++){
        int ci0 = (m&1)*32 + q*8;
        bf16x8 bv = *(const bf16x8*)&inp[(pb + TOFF[cl][m>>1])*64 + ci0];
        acc = __builtin_amdgcn_mfma_f32_16x16x32_bf16(af[m], bv, acc, 0, 0, 0);
      }
      if (ok){
        int pos = (2*a_+PI[cl])*13 + (2*c_+PJ[cl]);
        #pragma unroll
        for (int reg=0;reg<4;reg++){
          float y = acc[reg] + biasr[reg];
          out[((size_t)b*64 + wv*16 + q*4 + reg)*169 + pos] = y;
          sacc[reg] += y; qacc[reg] += y*y;
        }
      }
    }
  }
  float* bk = bkt(hdr, b);
  #pragma unroll
  for (int reg=0;reg<4;reg++){
    float s = sacc[reg], qq = qacc[reg];
    for (int o=8;o;o>>=1){ s += __shfl_down(s,o,16); qq += __shfl_down(qq,o,16); }
    if (r==0){ atomicAdd(&bk[H_DS0+wv*16+q*4+reg], s); atomicAdd(&bk[H_DQ0+wv*16+q*4+reg], qq); }
  }
}

// ---------------- deconv1 (MFMA): 64->32, k3 s2 p1, 13->25 ----------------
__global__ __launch_bounds__(256) void k_deconv1m(
    const float* __restrict__ g0, const ushort_t* __restrict__ WPK, const float* __restrict__ b1g,
    const float* __restrict__ g, const float* __restrict__ be,
    float* __restrict__ hdr, float* __restrict__ out){
  __shared__ ushort_t inp[169*64];     // [cell 13x13][ci64]
  __shared__ float ac[128];
  const int b = blockIdx.x, tid = threadIdx.x;
  coef_lds(hdr, H_DS0, H_DQ0, g, be, ac, 64, 1.f/(512.f*169.f), tid);
  __syncthreads();
  for (int e = tid; e < 169*64; e += 256){
    int ci = e & 63, cell = e >> 6;
    float raw = g0[((size_t)b*64 + ci)*169 + cell];
    inp[e] = f2bf(fmaxf(fmaf(ac[ci], raw, ac[64+ci]), 0.f));
  }
  __syncthreads();
  const int wv = tid>>6, lane = tid&63, r = lane&15, q = lane>>4;
  const int cotile = wv&1, ph = wv>>1;
  float biasr[4];
  #pragma unroll
  for (int v=0;v<4;v++) biasr[v] = b1g[cotile*16 + q*4 + v];
  const int NCOL[4]={13,12,13,12}, NPOS[4]={169,156,156,144}, NT[4]={11,10,10,9},
            NCH[4]={2,4,4,8}, KB[4]={0,2048,6144,10240}, KK[4]={64,128,128,256},
            PI[4]={0,0,1,1}, PJ[4]={0,1,0,1};
  const int TOFF[4][4] = {{0,0,0,0},{1,0,0,0},{13,0,0,0},{14,13,1,0}};
  float sacc[4]={0,0,0,0}, qacc[4]={0,0,0,0};
  #pragma unroll
  for (int cl=0; cl<4; cl++){
    bf16x8 af[8];
    #pragma unroll
    for (int m=0;m<NCH[cl];m++)
      af[m] = *(const bf16x8*)(WPK + OD1 + KB[cl] + (cotile*16+r)*KK[cl] + m*32 + q*8);
    for (int t = ph; t < NT[cl]; t += 2){
      int p = t*16 + r;
      bool ok = p < NPOS[cl];
      int pc = ok ? p : 0;
      int a_ = pc/NCOL[cl], c_ = pc - a_*NCOL[cl];
      int pb = a_*13 + c_;
      f32x4 acc = {0.f,0.f,0.f,0.f};
      #pragma unroll
      for (int m=0;m<NCH[cl];m++){
        int ci0 = (m&1)*32 + q*8;
        bf16x8 bv = *(const bf16x8*)&inp[(pb + TOFF[cl][m>>1])*64 + ci0];
        acc = __builtin_amdgcn_mfma_f32_16x16x32_bf16(af[m], bv, acc, 0, 0, 0);
      }
      if (ok){
        int pos = (2*a_+PI[cl])*25 + (2*c_+PJ[cl]);
        #pragma unroll
        for (int reg=0;reg<4;reg++){
          float y = acc[reg] + biasr[reg];
          out[((size_t)b*32 + cotile*16 + q*4 + reg)*625 + pos] = y;
          sacc[reg] += y; qacc[reg] += y*y;
        }
      }
    }
  }
  float* bk = bkt(hdr, b);
  #pragma unroll
  for (int reg=0;reg<4;reg++){
    float s = sacc[reg], qq = qacc[reg];
    for (int o=8;o;o>>=1){ s += __shfl_down(s,o,16); qq += __shfl_down(qq,o,16); }
    if (r==0){ atomicAdd(&bk[H_DS1+cotile*16+q*4+reg], s); atomicAdd(&bk[H_DQ1+cotile*16+q*4+reg], qq); }
  }
}

// ---------------- deconv2 (MFMA): 32->16, k2 s2 p1 op1, 25->49 ----------------
__global__ __launch_bounds__(256) void k_deconv2m(
    const float* __restrict__ g1, const ushort_t* __restrict__ WPK, const float* __restrict__ bg,
    const float* __restrict__ g, const float* __restrict__ be,
    float* __restrict__ hdr, float* __restrict__ out){
  __shared__ ushort_t inp[625*32];     // [cell 25x25][ci32]
  __shared__ float ac[64];
  const int b = blockIdx.x, tid = threadIdx.x;
  coef_lds(hdr, H_DS1, H_DQ1, g, be, ac, 32, 1.f/(512.f*625.f), tid);
  __syncthreads();
  for (int e = tid; e < 625*32; e += 256){
    int ci = e & 31, cell = e >> 5;
    float raw = g1[((size_t)b*32 + ci)*625 + cell];
    inp[e] = f2bf(fmaxf(fmaf(ac[ci], raw, ac[32+ci]), 0.f));
  }
  __syncthreads();
  const int wv = tid>>6, lane = tid&63, r = lane&15, q = lane>>4;
  float biasr[4];
  #pragma unroll
  for (int v=0;v<4;v++) biasr[v] = bg[q*4 + v];
  const int NCOL[4]={25,24,25,24}, NPOS[4]={625,600,600,576}, NT[4]={40,38,38,36},
            TOFF[4]={0,1,25,26}, PI[4]={0,0,1,1}, PJ[4]={0,1,0,1};
  const int ci0 = q*8;
  float sacc[4]={0,0,0,0}, qacc[4]={0,0,0,0};
  #pragma unroll
  for (int cl=0; cl<4; cl++){
    bf16x8 af = *(const bf16x8*)(WPK + OD2 + cl*512 + r*32 + q*8);
    for (int t = wv; t < NT[cl]; t += 4){
      int p = t*16 + r;
      bool ok = p < NPOS[cl];
      int pc = ok ? p : 0;
      int a_ = pc/NCOL[cl], c_ = pc - a_*NCOL[cl];
      int pb = a_*25 + c_;
      f32x4 acc = {0.f,0.f,0.f,0.f};
      bf16x8 bv = *(const bf16x8*)&inp[(pb + TOFF[cl])*32 + ci0];
      acc = __builtin_amdgcn_mfma_f32_16x16x32_bf16(af, bv, acc, 0, 0, 0);
      if (ok){
        int pos = (2*a_+PI[cl])*49 + (2*c_+PJ[cl]);
        #pragma unroll
        for (int reg=0;reg<4;reg++){
          float y = acc[reg] + biasr[reg];
          out[((size_t)b*16 + q*4 + reg)*2401 + pos] = y;
          sacc[reg] += y; qacc[reg] += y*y;
        }
      }
    }
  }
  float* bk = bkt(hdr, b);
  #pragma unroll
  for (int reg=0;reg<4;reg++){
    float s = sacc[reg], qq = qacc[reg];
    for (int o=8;o;o>>=1){ s += __shfl_down(s,o,16); qq += __shfl_down(qq,o,16); }
    if (r==0){ atomicAdd(&bk[H_DS2+q*4+reg], s); atomicAdd(&bk[H_DQ2+q*4+reg], qq); }
  }
}

// ---------------- deconv3: 16->1, k2 s2 p0, 49->98, + sigmoid ----------------
__global__ __launch_bounds__(256) void k_deconv3(const float* __restrict__ g2, const float* __restrict__ w,
                                                 const float* __restrict__ bias,
                                                 const float* __restrict__ g, const float* __restrict__ be,
                                                 float* __restrict__ hdr, float* __restrict__ out){
  __shared__ float ac[32];
  const int tid = threadIdx.x;
  coef_lds(hdr, H_DS2, H_DQ2, g, be, ac, 16, 1.f/(512.f*2401.f), tid);
  __syncthreads();
  int idx = blockIdx.x*256 + tid;
  if (idx >= 512*9604) return;
  int b = idx / 9604; int r = idx - b*9604;
  int oi = r / 98, oj = r - oi*98;
  int ki = oi & 1, kj = oj & 1, ii = oi >> 1, jj = oj >> 1;
  float acc = bias[0];
  const float* gp = g2 + (size_t)b*16*2401 + ii*49 + jj;
  #pragma unroll
  for (int ci=0; ci<16; ci++){
    float raw = gp[(size_t)ci*2401];
    float h = fmaxf(fmaf(ac[ci], raw, ac[16+ci]), 0.f);
    acc = fmaf(h, w[ci*4 + ki*2 + kj], acc);
  }
  out[idx] = 1.f/(1.f + __expf(-acc));
}

// ======================================================================
extern "C" void kernel_launch(void* const* d_in, const int* in_sizes, int n_in,
                              void* d_out, int out_size, void* d_ws, size_t ws_size,
                              hipStream_t stream){
  (void)in_sizes; (void)n_in; (void)out_size; (void)ws_size;
  const float* x     = (const float*)d_in[0];
  const float* c1w   = (const float*)d_in[1];
  const float* c1b   = (const float*)d_in[2];
  const float* bn1g  = (const float*)d_in[3];
  const float* bn1b  = (const float*)d_in[4];
  const float* c2w   = (const float*)d_in[5];
  const float* c2b   = (const float*)d_in[6];
  const float* bn2g  = (const float*)d_in[7];
  const float* bn2b  = (const float*)d_in[8];
  const float* c3w   = (const float*)d_in[9];
  const float* c3b   = (const float*)d_in[10];
  const float* bn3g  = (const float*)d_in[11];
  const float* bn3b  = (const float*)d_in[12];
  const float* c4w   = (const float*)d_in[13];
  const float* c4b   = (const float*)d_in[14];
  const float* bn4g  = (const float*)d_in[15];
  const float* bn4b  = (const float*)d_in[16];
  const float* mem   = (const float*)d_in[17];
  const float* d0w   = (const float*)d_in[18];
  const float* d0b   = (const float*)d_in[19];
  const float* dbn0g = (const float*)d_in[20];
  const float* dbn0b = (const float*)d_in[21];
  const float* d1w   = (const float*)d_in[22];
  const float* d1b   = (const float*)d_in[23];
  const float* dbn1g = (const float*)d_in[24];
  const float* dbn1b = (const float*)d_in[25];
  const float* d2w   = (const float*)d_in[26];
  const float* d2b   = (const float*)d_in[27];
  const float* dbn2g = (const float*)d_in[28];
  const float* dbn2b = (const float*)d_in[29];
  const float* d3w   = (const float*)d_in[30];
  const float* d3b   = (const float*)d_in[31];

  float* hdr  = (float*)d_ws;
  float* H2   = hdr + HDR_FLOATS;        // 512*32*625 (reused as G1)
  float* H3   = H2 + 10240000;           // 512*64*169 (reused as G0)
  float* ZRAW = H3 + 5537792;            // 512*2304
  float* ZH   = ZRAW + 1179648;          // 512*2304
  float* SIM  = ZH + 1179648;            // 512*2000
  float* WSLOT= SIM + 1024000;           // 73728 floats (holds WPK bf16)
  float* G2   = WSLOT + 73728;           // 512*16*2401
  ushort_t* MEMBF = (ushort_t*)(G2 + 19668992); // 2000*2304
  ushort_t* MEMT  = MEMBF + 4608000;            // 2304*2016
  ushort_t* ZBF   = MEMT + 4644864;             // 512*2304
  ushort_t* WBF   = ZBF + 1179648;              // 512*2016
  ushort_t* WPK   = (ushort_t*)WSLOT;
  float* G0 = H3;
  float* G1 = H2;
  float* OUT = (float*)d_out;

  hipMemsetAsync(hdr, 0, HDR_FLOATS*sizeof(float), stream);
  k_xstats   <<<1024, 256, 0, stream>>>(x, hdr);
  k_wprep2   <<<460, 256, 0, stream>>>(c2w, c3w, c4w, d0w, d1w, d2w, WPK);
  k_memrows  <<<2000, 256, 0, stream>>>(mem, hdr, MEMBF);
  k_memT     <<<72*63, 256, 0, stream>>>(mem, MEMT);
  k_conv2m   <<<1024, 256, 0, stream>>>(x, WPK, c2b, c1w, c1b, bn1g, bn1b, hdr, H2);
  k_conv3m   <<<512, 256, 0, stream>>>(H2, WPK, c3b, bn2g, bn2b, hdr, H3);
  k_conv4m   <<<512, 256, 0, stream>>>(H3, WPK, c4b, bn3g, bn3b, hdr, ZRAW);
  k_z        <<<512, 256, 0, stream>>>(ZRAW, hdr, ZBF, bn4g, bn4b);
  k_gemm_bt  <<<1000, 256, 0, stream>>>(ZBF, MEMBF, SIM, 125, 2304, 72, 2000);
  k_softmax  <<<512, 256, 0, stream>>>(SIM, hdr, WBF);
  k_gemm_bt  <<<1152, 256, 0, stream>>>(WBF, MEMT, ZH, 144, 2016, 63, 2304);
  k_deconv0m <<<512, 256, 0, stream>>>(ZH, WPK, d0b, hdr, G0);
  k_deconv1m <<<512, 256, 0, stream>>>(G0, WPK, d1b, dbn0g, dbn0b, hdr, G1);
  k_deconv2m <<<512, 256, 0, stream>>>(G1, WPK, d2b, dbn1g, dbn1b, hdr, G2);
  k_deconv3  <<<19208, 256, 0, stream>>>(G2, d3w, d3b, dbn2g, dbn2b, hdr, OUT);
}

// Round 5
// 521.116 us; speedup vs baseline: 2.5516x; 1.0019x over previous
//
#include <hip/hip_runtime.h>
#include <stdint.h>

// R5: R4 + blocked GEMM (k_gemmB) replacing the latency-bound per-wave-tile
// k_gemm_bt. 128x128 block, 4 waves x (64x64), BK=32; B staged via LDS
// (stride 40: aligned + conflict-free), A frags direct from L2 w/ prefetch.

typedef unsigned short ushort_t;
typedef __bf16 bf16x8 __attribute__((ext_vector_type(8)));
typedef float f32x4 __attribute__((ext_vector_type(4)));

#define DEV static __device__ __forceinline__

DEV ushort_t f2bf(float f){
  union { float f; uint32_t u; } v; v.f = f;
  return (ushort_t)((v.u + 0x7FFFu + ((v.u >> 16) & 1u)) >> 16);
}

// ---------------- header (stats/coeff) offsets in floats ----------------
#define H_XS   0
#define H_S2   64
#define H_Q2   96
#define H_S3   192
#define H_Q3   256
#define H_S4   448
#define H_Q4   512
#define H_DS0  704
#define H_DQ0  768
#define H_DS1  960
#define H_DQ1  992
#define H_DS2  1088
#define H_DQ2  1104
#define H_ZN   1152   // [512]
#define H_MN   1664   // [2000]
#define H_BUK  4096   // 16 bucket banks of 1280 floats each
#define NBUK   16
#define BSTRIDE 1280
#define HDR_FLOATS (H_BUK + NBUK*BSTRIDE)

// packed-weight (bf16) offsets in WPK
#define OW2 0        // [32][160]  k=tap*16+ci, taps 0..9 (tap9 = zero pad)
#define OW3 5120     // [64][288]  k=tap*32+ci
#define OW4 23552    // [64][576]  k=tap*64+ci
#define OD0 60416    // 4 classes [64][K], K={256,128,128,64}
#define OD1 97280    // 4 classes [32][K], K={64,128,128,256}
#define OD2 115712   // 4 classes [16][32]
#define NWPK 117760

DEV float* bkt(float* hdr, int blk){ return hdr + H_BUK + (size_t)(blk & (NBUK-1))*BSTRIDE; }

// compute per-channel affine (a,c) from buckets into LDS ac[2*nch]
DEV void coef_lds(const float* __restrict__ hdr, int offS, int offQ,
                  const float* __restrict__ g, const float* __restrict__ be,
                  float* ac, int nch, float invN, int tid){
  if (tid < nch){
    float s = 0.f, q = 0.f;
    #pragma unroll
    for (int k=0;k<NBUK;k++){
      s += hdr[H_BUK + k*BSTRIDE + offS + tid];
      q += hdr[H_BUK + k*BSTRIDE + offQ + tid];
    }
    float m = s*invN;
    float v = q*invN - m*m;
    float a = g[tid]*rsqrtf(v + 1e-5f);
    ac[tid] = a;
    ac[nch+tid] = be[tid] - m*a;
  }
}

// ---------------- stats of strided-sampled input (for bn1 fold) ----------------
__global__ __launch_bounds__(256) void k_xstats(const float* __restrict__ x, float* __restrict__ hdr){
  __shared__ float red[8];
  float s = 0.f, q = 0.f;
  const int total = 512*49*49;
  for (int idx = blockIdx.x*256 + threadIdx.x; idx < total; idx += gridDim.x*256){
    int b = idx / 2401;
    int r = idx - b*2401;
    int i = r / 49, j = r - i*49;
    float v = 0.f;
    if (i > 0 && j > 0) v = x[(size_t)b*9216 + (2*i-1)*96 + (2*j-1)];
    s += v; q += v*v;
  }
  for (int o=32;o;o>>=1){ s += __shfl_down(s,o,64); q += __shfl_down(q,o,64); }
  int w = threadIdx.x>>6;
  if ((threadIdx.x&63)==0){ red[w*2]=s; red[w*2+1]=q; }
  __syncthreads();
  if (threadIdx.x==0){
    float* bk = bkt(hdr, blockIdx.x);
    atomicAdd(&bk[H_XS+0], red[0]+red[2]+red[4]+red[6]);
    atomicAdd(&bk[H_XS+1], red[1]+red[3]+red[5]+red[7]);
  }
}

// ---------------- pack all conv/deconv weights to bf16 [co][k] ----------------
__global__ __launch_bounds__(256) void k_wprep2(
    const float* __restrict__ c2w, const float* __restrict__ c3w, const float* __restrict__ c4w,
    const float* __restrict__ d0w, const float* __restrict__ d1w, const float* __restrict__ d2w,
    ushort_t* __restrict__ WPK){
  int i = blockIdx.x*256 + threadIdx.x;
  if (i >= NWPK) return;
  float val = 0.f;
  if (i < OW3){                       // conv2 [32][160]
    int co = i/160, k = i - co*160, tap = k>>4, ci = k&15;
    if (tap < 9) val = c2w[(co*16+ci)*9+tap];
  } else if (i < OW4){                // conv3 [64][288]
    int r = i - OW3; int co = r/288, k = r - co*288, tap = k>>5, ci = k&31;
    val = c3w[(co*32+ci)*9+tap];
  } else if (i < OD0){                // conv4 [64][576]
    int r = i - OW4; int co = r/576, k = r - co*576, tap = k>>6, ci = k&63;
    val = c4w[(co*64+ci)*9+tap];
  } else if (i < OD1){                // deconv0 classes
    int r = i - OD0;
    const int base[4]={0,16384,24576,32768}, K[4]={256,128,128,64};
    const int T0[4][4] = {{0,2,6,8},{1,7,0,0},{3,5,0,0},{4,0,0,0}};
    int cl = (r<16384)?0:(r<24576)?1:(r<32768)?2:3;
    int rr = r - base[cl]; int co = rr/K[cl], k = rr - co*K[cl], t = k>>6, ci = k&63;
    val = d0w[(ci*64+co)*9 + T0[cl][t]];
  } else if (i < OD2){                // deconv1 classes
    int r = i - OD1;
    const int base[4]={0,2048,6144,10240}, K[4]={64,128,128,256};
    const int T1[4][4] = {{4,0,0,0},{3,5,0,0},{1,7,0,0},{0,2,6,8}};
    int cl = (r<2048)?0:(r<6144)?1:(r<10240)?2:3;
    int rr = r - base[cl]; int co = rr/K[cl], k = rr - co*K[cl], t = k>>6, ci = k&63;
    val = d1w[(ci*32+co)*9 + T1[cl][t]];
  } else {                            // deconv2 classes [4][16][32]
    int r = i - OD2;
    int cl = r>>9, s = r&511, co = s>>5, ci = s&31;
    const int pis[4]={0,0,1,1}, pjs[4]={0,1,0,1};
    val = d2w[((ci*16+co)*2 + (1-pis[cl]))*2 + (1-pjs[cl])];
  }
  WPK[i] = f2bf(val);
}

// ---------------- memory rows -> bf16 + row norms ----------------
__global__ __launch_bounds__(256) void k_memrows(const float* __restrict__ mem, float* __restrict__ hdr,
                                                 ushort_t* __restrict__ mbf){
  __shared__ float red[4];
  const int m = blockIdx.x, tid = threadIdx.x;
  float part = 0.f;
  for (int i=tid;i<2304;i+=256){
    float v = mem[(size_t)m*2304+i];
    mbf[(size_t)m*2304+i] = f2bf(v);
    part += v*v;
  }
  for (int o=32;o;o>>=1) part += __shfl_down(part,o,64);
  if ((tid&63)==0) red[tid>>6] = part;
  __syncthreads();
  if (tid==0) hdr[H_MN+m] = sqrtf(red[0]+red[1]+red[2]+red[3]);
}

__global__ __launch_bounds__(256) void k_memT(const float* __restrict__ mem, ushort_t* __restrict__ mt){
  __shared__ ushort_t tile[32][33];
  const int ft = blockIdx.x % 72, mtile = blockIdx.x / 72;
  const int tx = threadIdx.x & 31, ty = threadIdx.x >> 5;
  #pragma unroll
  for (int r0=0;r0<4;r0++){
    int m = mtile*32 + r0*8 + ty;
    int f = ft*32 + tx;
    float v = (m < 2000) ? mem[(size_t)m*2304 + f] : 0.f;
    tile[r0*8+ty][tx] = f2bf(v);
  }
  __syncthreads();
  #pragma unroll
  for (int r0=0;r0<4;r0++){
    int f = ft*32 + r0*8 + ty;
    mt[(size_t)f*2016 + mtile*32 + tx] = tile[tx][r0*8+ty];
  }
}

// ---------------- conv2 (MFMA): 16->32, 3x3 s2 p1 on folded conv1 output ----------------
__global__ __launch_bounds__(256) void k_conv2m(
    const float* __restrict__ x, const ushort_t* __restrict__ WPK, const float* __restrict__ b2g,
    const float* __restrict__ c1w, const float* __restrict__ c1b,
    const float* __restrict__ bn1g, const float* __restrict__ bn1b,
    float* __restrict__ hdr, float* __restrict__ out){
  __shared__ ushort_t inp[27*51*16];    // [row][col][ci16], halo'd 51-grid rows [2*ro..2*ro+26]
  __shared__ float ac[32];
  const int blk = blockIdx.x, b = blk>>1, h = blk&1, tid = threadIdx.x;
  const int ro = h*13, nr = h?12:13, npos = nr*25, ntiles = (npos+15)>>4;
  if (tid < 16){
    float sx=0.f, qx=0.f;
    #pragma unroll
    for (int k=0;k<NBUK;k++){ sx += hdr[H_BUK+k*BSTRIDE+H_XS]; qx += hdr[H_BUK+k*BSTRIDE+H_XS+1]; }
    const float N = 512.f*49.f*49.f;
    float mx = sx/N, vx = qx/N - mx*mx;
    float mean = c1w[tid]*mx + c1b[tid];
    float a = bn1g[tid]*rsqrtf(c1w[tid]*c1w[tid]*vx + 1e-5f);
    ac[tid] = a*c1w[tid];
    ac[16+tid] = a*(c1b[tid]-mean) + bn1b[tid];
  }
  __syncthreads();
  for (int e = tid; e < 27*51; e += 256){
    int lr = e/51, gc = e - lr*51;
    int grg = 2*ro + lr;
    // inside: cell is within the 49x49 conv1-output grid (else conv2 pad => 0)
    bool inside = (grg>=1 && grg<=49 && gc>=1 && gc<=49);
    float v = 0.f;
    if (grg>=2 && grg<=49 && gc>=2 && gc<=49) v = x[(size_t)b*9216 + (2*grg-3)*96 + (2*gc-3)];
    ushort_t hv[16];
    if (inside){
      #pragma unroll
      for (int c=0;c<16;c++) hv[c] = f2bf(fmaxf(fmaf(ac[c], v, ac[16+c]), 0.f));
    } else {
      #pragma unroll
      for (int c=0;c<16;c++) hv[c] = 0;
    }
    uint32_t w0[8];
    #pragma unroll
    for (int c=0;c<8;c++) w0[c] = (uint32_t)hv[2*c] | ((uint32_t)hv[2*c+1]<<16);
    uint4* dst = (uint4*)&inp[e*16];
    dst[0] = make_uint4(w0[0],w0[1],w0[2],w0[3]);
    dst[1] = make_uint4(w0[4],w0[5],w0[6],w0[7]);
  }
  __syncthreads();
  const int wv = tid>>6, lane = tid&63, r = lane&15, q = lane>>4;
  const int cotile = wv&1;
  bf16x8 af[5];
  #pragma unroll
  for (int c=0;c<5;c++) af[c] = *(const bf16x8*)(WPK + OW2 + (cotile*16+r)*160 + c*32 + q*8);
  float biasr[4];
  #pragma unroll
  for (int v=0;v<4;v++) biasr[v] = b2g[cotile*16 + q*4 + v];
  const int TOFF[10] = {0,1,2,51,52,53,102,103,104,0};
  const int qhi = q>>1, ci0 = (q&1)*8;
  float sacc[4]={0,0,0,0}, qacc[4]={0,0,0,0};
  for (int t = wv>>1; t < ntiles; t += 2){
    int p = t*16 + r;
    bool ok = p < npos;
    int pc = ok ? p : 0;
    int a_ = pc/25, c_ = pc - a_*25;
    int pb = (2*a_)*51 + 2*c_;
    f32x4 acc = {0.f,0.f,0.f,0.f};
    #pragma unroll
    for (int c=0;c<5;c++){
      int toff = qhi ? TOFF[2*c+1] : TOFF[2*c];
      bf16x8 bv = *(const bf16x8*)&inp[(pb + toff)*16 + ci0];
      acc = __builtin_amdgcn_mfma_f32_16x16x32_bf16(af[c], bv, acc, 0, 0, 0);
    }
    if (ok){
      int pg = (ro + a_)*25 + c_;
      #pragma unroll
      for (int reg=0;reg<4;reg++){
        float y = acc[reg] + biasr[reg];
        out[((size_t)b*32 + cotile*16 + q*4 + reg)*625 + pg] = y;
        sacc[reg] += y; qacc[reg] += y*y;
      }
    }
  }
  float* bk = bkt(hdr, blk);
  #pragma unroll
  for (int reg=0;reg<4;reg++){
    float s = sacc[reg], qq = qacc[reg];
    for (int o=8;o;o>>=1){ s += __shfl_down(s,o,16); qq += __shfl_down(qq,o,16); }
    if (r==0){ atomicAdd(&bk[H_S2+cotile*16+q*4+reg], s); atomicAdd(&bk[H_Q2+cotile*16+q*4+reg], qq); }
  }
}

// ---------------- conv3 (MFMA): 32->64, 3x3 s2 p1, 25->13 ----------------
__global__ __launch_bounds__(256) void k_conv3m(
    const float* __restrict__ h2, const ushort_t* __restrict__ WPK, const float* __restrict__ b3g,
    const float* __restrict__ g, const float* __restrict__ be,
    float* __restrict__ hdr, float* __restrict__ out){
  __shared__ ushort_t inp[27*27*32];   // [cell][ci32], halo'd 27-grid
  __shared__ float ac[64];
  const int b = blockIdx.x, tid = threadIdx.x;
  coef_lds(hdr, H_S2, H_Q2, g, be, ac, 32, 1.f/(512.f*625.f), tid);
  __syncthreads();
  for (int e = tid; e < 27*27*32; e += 256){
    int ci = e & 31, cell = e >> 5;
    int gr = cell/27, gc = cell - gr*27;
    int i = gr-1, j = gc-1;
    float v = 0.f;
    if ((unsigned)i < 25u && (unsigned)j < 25u){
      float raw = h2[((size_t)b*32 + ci)*625 + i*25 + j];
      v = fmaxf(fmaf(ac[ci], raw, ac[32+ci]), 0.f);
    }
    inp[e] = f2bf(v);
  }
  __syncthreads();
  const int wv = tid>>6, lane = tid&63, r = lane&15, q = lane>>4;
  bf16x8 af[9];
  #pragma unroll
  for (int c=0;c<9;c++) af[c] = *(const bf16x8*)(WPK + OW3 + (wv*16+r)*288 + c*32 + q*8);
  float biasr[4];
  #pragma unroll
  for (int v=0;v<4;v++) biasr[v] = b3g[wv*16 + q*4 + v];
  const int TOFF[9] = {0,1,2,27,28,29,54,55,56};
  const int ci0 = q*8;
  float sacc[4]={0,0,0,0}, qacc[4]={0,0,0,0};
  for (int t = 0; t < 11; t++){
    int p = t*16 + r;
    bool ok = p < 169;
    int pc = ok ? p : 0;
    int a_ = pc/13, c_ = pc - a_*13;
    int pb = (2*a_)*27 + 2*c_;
    f32x4 acc = {0.f,0.f,0.f,0.f};
    #pragma unroll
    for (int c=0;c<9;c++){
      bf16x8 bv = *(const bf16x8*)&inp[(pb + TOFF[c])*32 + ci0];
      acc = __builtin_amdgcn_mfma_f32_16x16x32_bf16(af[c], bv, acc, 0, 0, 0);
    }
    if (ok){
      #pragma unroll
      for (int reg=0;reg<4;reg++){
        float y = acc[reg] + biasr[reg];
        out[((size_t)b*64 + wv*16 + q*4 + reg)*169 + p] = y;
        sacc[reg] += y; qacc[reg] += y*y;
      }
    }
  }
  float* bk = bkt(hdr, b);
  #pragma unroll
  for (int reg=0;reg<4;reg++){
    float s = sacc[reg], qq = qacc[reg];
    for (int o=8;o;o>>=1){ s += __shfl_down(s,o,16); qq += __shfl_down(qq,o,16); }
    if (r==0){ atomicAdd(&bk[H_S3+wv*16+q*4+reg], s); atomicAdd(&bk[H_Q3+wv*16+q*4+reg], qq); }
  }
}

// ---------------- conv4 (MFMA): 64->64, 3x3 s2 p0, 13->6 ----------------
__global__ __launch_bounds__(256) void k_conv4m(
    const float* __restrict__ h3, const ushort_t* __restrict__ WPK, const float* __restrict__ b4g,
    const float* __restrict__ g, const float* __restrict__ be,
    float* __restrict__ hdr, float* __restrict__ out){
  __shared__ ushort_t inp[169*64];     // [cell][ci64]
  __shared__ float ac[128];
  const int b = blockIdx.x, tid = threadIdx.x;
  coef_lds(hdr, H_S3, H_Q3, g, be, ac, 64, 1.f/(512.f*169.f), tid);
  __syncthreads();
  for (int e = tid; e < 169*64; e += 256){
    int ci = e & 63, cell = e >> 6;
    float raw = h3[((size_t)b*64 + ci)*169 + cell];
    inp[e] = f2bf(fmaxf(fmaf(ac[ci], raw, ac[64+ci]), 0.f));
  }
  __syncthreads();
  const int wv = tid>>6, lane = tid&63, r = lane&15, q = lane>>4;
  bf16x8 af[18];
  #pragma unroll
  for (int c=0;c<18;c++) af[c] = *(const bf16x8*)(WPK + OW4 + (wv*16+r)*576 + c*32 + q*8);
  float biasr[4];
  #pragma unroll
  for (int v=0;v<4;v++) biasr[v] = b4g[wv*16 + q*4 + v];
  const int TOFF[9] = {0,1,2,13,14,15,26,27,28};
  float sacc[4]={0,0,0,0}, qacc[4]={0,0,0,0};
  for (int t = 0; t < 3; t++){
    int p = t*16 + r;
    bool ok = p < 36;
    int pc = ok ? p : 0;
    int a_ = pc/6, c_ = pc - a_*6;
    int pb = (2*a_)*13 + 2*c_;
    f32x4 acc = {0.f,0.f,0.f,0.f};
    #pragma unroll
    for (int c=0;c<18;c++){
      int ci0 = (c&1)*32 + q*8;
      bf16x8 bv = *(const bf16x8*)&inp[(pb + TOFF[c>>1])*64 + ci0];
      acc = __builtin_amdgcn_mfma_f32_16x16x32_bf16(af[c], bv, acc, 0, 0, 0);
    }
    if (ok){
      #pragma unroll
      for (int reg=0;reg<4;reg++){
        float y = acc[reg] + biasr[reg];
        out[((size_t)b*64 + wv*16 + q*4 + reg)*36 + p] = y;
        sacc[reg] += y; qacc[reg] += y*y;
      }
    }
  }
  float* bk = bkt(hdr, b);
  #pragma unroll
  for (int reg=0;reg<4;reg++){
    float s = sacc[reg], qq = qacc[reg];
    for (int o=8;o;o>>=1){ s += __shfl_down(s,o,16); qq += __shfl_down(qq,o,16); }
    if (r==0){ atomicAdd(&bk[H_S4+wv*16+q*4+reg], s); atomicAdd(&bk[H_Q4+wv*16+q*4+reg], qq); }
  }
}

// z = relu(bn4(conv4 raw)) -> bf16, plus per-row norm (computes A4/C4 itself)
__global__ __launch_bounds__(256) void k_z(const float* __restrict__ zraw, float* __restrict__ hdr,
                                           ushort_t* __restrict__ zbf,
                                           const float* __restrict__ g, const float* __restrict__ be){
  __shared__ float ac[128];
  __shared__ float red[4];
  const int b = blockIdx.x, tid = threadIdx.x;
  coef_lds(hdr, H_S4, H_Q4, g, be, ac, 64, 1.f/(512.f*36.f), tid);
  __syncthreads();
  float part = 0.f;
  for (int i=tid;i<2304;i+=256){
    int c = i/36;
    float h = fmaxf(fmaf(ac[c], zraw[(size_t)b*2304+i], ac[64+c]), 0.f);
    zbf[(size_t)b*2304+i] = f2bf(h);
    part += h*h;
  }
  for (int o=32;o;o>>=1) part += __shfl_down(part,o,64);
  if ((tid&63)==0) red[tid>>6] = part;
  __syncthreads();
  if (tid==0) hdr[H_ZN+b] = sqrtf(red[0]+red[1]+red[2]+red[3]);
}

// ---------------- blocked GEMM: D[M][N] = A[M][Kp] * B[N][Kp]^T (bf16 in, fp32 out)
// 128x128 block, 4 waves x (64x64), BK=32. B via LDS (stride 40), A direct from L2.
__global__ __launch_bounds__(256) void k_gemmB(const ushort_t* __restrict__ A, const ushort_t* __restrict__ Bm,
                                               float* __restrict__ D, int Nb, int N, int Kp, int kch){
  __shared__ __align__(16) ushort_t lB[128*40];
  const int blk = blockIdx.x;
  const int bi = blk / Nb, bj = blk - bi*Nb;
  const int m0 = bi*128, n0 = bj*128;
  const int tid = threadIdx.x;
  const int lane = tid & 63, wv = tid >> 6;
  const int r = lane & 15, q = lane >> 4;
  const int wr = wv >> 1, wc = wv & 1;
  // B staging: thread t -> row t>>1, k-offset (t&1)*16 (two 16B chunks)
  const int srow = tid >> 1, skq = (tid & 1) * 16;
  const bool bok = (n0 + srow) < N;
  const ushort_t* pb = Bm + (size_t)(n0 + srow)*Kp + skq;
  uint4* wB = (uint4*)&lB[srow*40 + skq];
  const uint4 zz = make_uint4(0,0,0,0);
  uint4 rb0 = bok ? *(const uint4*)(pb)     : zz;
  uint4 rb1 = bok ? *(const uint4*)(pb + 8) : zz;
  // A frags: direct global, rows m0 + wr*64 + mt*16 + r, k chunk q*8
  const ushort_t* pa = A + (size_t)(m0 + wr*64 + r)*Kp + q*8;
  bf16x8 aN[4];
  #pragma unroll
  for (int mt=0;mt<4;mt++) aN[mt] = *(const bf16x8*)(pa + (size_t)(mt*16)*Kp);
  f32x4 acc[4][4];
  #pragma unroll
  for (int i=0;i<4;i++)
    #pragma unroll
    for (int j=0;j<4;j++) acc[i][j] = (f32x4){0.f,0.f,0.f,0.f};
  for (int k=0; k<kch; k++){
    if (k) __syncthreads();
    wB[0] = rb0; wB[1] = rb1;
    bf16x8 aF[4];
    #pragma unroll
    for (int mt=0;mt<4;mt++) aF[mt] = aN[mt];
    if (k+1 < kch){
      const ushort_t* nb = pb + (k+1)*32;
      rb0 = bok ? *(const uint4*)(nb)     : zz;
      rb1 = bok ? *(const uint4*)(nb + 8) : zz;
      const ushort_t* na = pa + (k+1)*32;
      #pragma unroll
      for (int mt=0;mt<4;mt++) aN[mt] = *(const bf16x8*)(na + (size_t)(mt*16)*Kp);
    }
    __syncthreads();
    bf16x8 bF[4];
    #pragma unroll
    for (int nt=0;nt<4;nt++) bF[nt] = *(const bf16x8*)&lB[(wc*64+nt*16+r)*40 + q*8];
    #pragma unroll
    for (int mt=0;mt<4;mt++)
      #pragma unroll
      for (int nt=0;nt<4;nt++)
        acc[mt][nt] = __builtin_amdgcn_mfma_f32_16x16x32_bf16(aF[mt], bF[nt], acc[mt][nt], 0, 0, 0);
  }
  #pragma unroll
  for (int mt=0;mt<4;mt++){
    int row = m0 + wr*64 + mt*16 + q*4;
    #pragma unroll
    for (int nt=0;nt<4;nt++){
      int col = n0 + wc*64 + nt*16 + r;
      if (col < N){
        #pragma unroll
        for (int reg=0;reg<4;reg++)
          D[(size_t)(row+reg)*N + col] = acc[mt][nt][reg];
      }
    }
  }
}

// softmax over M=2000 + hard-shrink + L1 renorm -> bf16 weights (K padded to 2016)
__global__ __launch_bounds__(256) void k_softmax(const float* __restrict__ sim, float* __restrict__ hdr,
                                                 ushort_t* __restrict__ wbf){
  __shared__ float e[2000];
  __shared__ float red[8];
  const int b = blockIdx.x, tid = threadIdx.x;
  const float znb = hdr[H_ZN+b];
  float part = 0.f;
  for (int m=tid;m<2000;m+=256){
    float s = sim[(size_t)b*2000+m] / fmaxf(znb * hdr[H_MN+m], 1e-8f);
    float ev = __expf(s);
    e[m] = ev; part += ev;
  }
  for (int o=32;o;o>>=1) part += __shfl_down(part,o,64);
  if ((tid&63)==0) red[tid>>6] = part;
  __syncthreads();
  const float denom = red[0]+red[1]+red[2]+red[3];
  const float t = 1.0f/2000.0f;
  float part2 = 0.f;
  for (int m=tid;m<2000;m+=256){
    float w = e[m]/denom;
    float d = w - t;
    float sh = fmaxf(d,0.f)*w/(fabsf(d)+0.01f);
    e[m] = sh; part2 += sh;
  }
  for (int o=32;o;o>>=1) part2 += __shfl_down(part2,o,64);
  if ((tid&63)==0) red[4+(tid>>6)] = part2;
  __syncthreads();
  const float inv = 1.0f/(red[4]+red[5]+red[6]+red[7]);
  for (int m=tid;m<2016;m+=256){
    ushort_t o = 0;
    if (m < 2000) o = f2bf(e[m]*inv);
    wbf[(size_t)b*2016+m] = o;
  }
}

// ---------------- deconv0 (MFMA): 64->64, k3 s2 p0, 6->13 ----------------
__global__ __launch_bounds__(256) void k_deconv0m(
    const float* __restrict__ zh, const ushort_t* __restrict__ WPK, const float* __restrict__ b0g,
    float* __restrict__ hdr, float* __restrict__ out){
  __shared__ ushort_t inp[64*64];      // [cell 8x8 halo][ci64]
  const int b = blockIdx.x, tid = threadIdx.x;
  for (int e = tid; e < 64*64; e += 256){
    int ci = e & 63, cell = e >> 6;
    int r8 = cell>>3, c8 = cell&7;
    float v = 0.f;
    if (r8>=1 && r8<=6 && c8>=1 && c8<=6)
      v = zh[(size_t)b*2304 + ci*36 + (r8-1)*6 + (c8-1)];
    inp[e] = f2bf(v);
  }
  __syncthreads();
  const int wv = tid>>6, lane = tid&63, r = lane&15, q = lane>>4;
  float biasr[4];
  #pragma unroll
  for (int v=0;v<4;v++) biasr[v] = b0g[wv*16 + q*4 + v];
  const int NCOL[4]={7,6,7,6}, NPOS[4]={49,42,42,36}, NT[4]={4,3,3,3},
            NCH[4]={8,4,4,2}, KB[4]={0,16384,24576,32768}, KK[4]={256,128,128,64},
            PI[4]={0,0,1,1}, PJ[4]={0,1,0,1};
  const int TOFF[4][4] = {{9,8,1,0},{9,1,0,0},{9,8,0,0},{9,0,0,0}};
  float sacc[4]={0,0,0,0}, qacc[4]={0,0,0,0};
  #pragma unroll
  for (int cl=0; cl<4; cl++){
    bf16x8 af[8];
    #pragma unroll
    for (int m=0;m<NCH[cl];m++)
      af[m] = *(const bf16x8*)(WPK + OD0 + KB[cl] + (wv*16+r)*KK[cl] + m*32 + q*8);
    for (int t = 0; t < NT[cl]; t++){
      int p = t*16 + r;
      bool ok = p < NPOS[cl];
      int pc = ok ? p : 0;
      int a_ = pc/NCOL[cl], c_ = pc - a_*NCOL[cl];
      int pb = a_*8 + c_;
      f32x4 acc = {0.f,0.f,0.f,0.f};
      #pragma unroll
      for (int m=0;m<NCH[cl];m++){
        int ci0 = (m&1)*32 + q*8;
        bf16x8 bv = *(const bf16x8*)&inp[(pb + TOFF[cl][m>>1])*64 + ci0];
        acc = __builtin_amdgcn_mfma_f32_16x16x32_bf16(af[m], bv, acc, 0, 0, 0);
      }
      if (ok){
        int pos = (2*a_+PI[cl])*13 + (2*c_+PJ[cl]);
        #pragma unroll
        for (int reg=0;reg<4;reg++){
          float y = acc[reg] + biasr[reg];
          out[((size_t)b*64 + wv*16 + q*4 + reg)*169 + pos] = y;
          sacc[reg] += y; qacc[reg] += y*y;
        }
      }
    }
  }
  float* bk = bkt(hdr, b);
  #pragma unroll
  for (int reg=0;reg<4;reg++){
    float s = sacc[reg], qq = qacc[reg];
    for (int o=8;o;o>>=1){ s += __shfl_down(s,o,16); qq += __shfl_down(qq,o,16); }
    if (r==0){ atomicAdd(&bk[H_DS0+wv*16+q*4+reg], s); atomicAdd(&bk[H_DQ0+wv*16+q*4+reg], qq); }
  }
}

// ---------------- deconv1 (MFMA): 64->32, k3 s2 p1, 13->25 ----------------
__global__ __launch_bounds__(256) void k_deconv1m(
    const float* __restrict__ g0, const ushort_t* __restrict__ WPK, const float* __restrict__ b1g,
    const float* __restrict__ g, const float* __restrict__ be,
    float* __restrict__ hdr, float* __restrict__ out){
  __shared__ ushort_t inp[169*64];     // [cell 13x13][ci64]
  __shared__ float ac[128];
  const int b = blockIdx.x, tid = threadIdx.x;
  coef_lds(hdr, H_DS0, H_DQ0, g, be, ac, 64, 1.f/(512.f*169.f), tid);
  __syncthreads();
  for (int e = tid; e < 169*64; e += 256){
    int ci = e & 63, cell = e >> 6;
    float raw = g0[((size_t)b*64 + ci)*169 + cell];
    inp[e] = f2bf(fmaxf(fmaf(ac[ci], raw, ac[64+ci]), 0.f));
  }
  __syncthreads();
  const int wv = tid>>6, lane = tid&63, r = lane&15, q = lane>>4;
  const int cotile = wv&1, ph = wv>>1;
  float biasr[4];
  #pragma unroll
  for (int v=0;v<4;v++) biasr[v] = b1g[cotile*16 + q*4 + v];
  const int NCOL[4]={13,12,13,12}, NPOS[4]={169,156,156,144}, NT[4]={11,10,10,9},
            NCH[4]={2,4,4,8}, KB[4]={0,2048,6144,10240}, KK[4]={64,128,128,256},
            PI[4]={0,0,1,1}, PJ[4]={0,1,0,1};
  const int TOFF[4][4] = {{0,0,0,0},{1,0,0,0},{13,0,0,0},{14,13,1,0}};
  float sacc[4]={0,0,0,0}, qacc[4]={0,0,0,0};
  #pragma unroll
  for (int cl=0; cl<4; cl++){
    bf16x8 af[8];
    #pragma unroll
    for (int m=0;m<NCH[cl];m++)
      af[m] = *(const bf16x8*)(WPK + OD1 + KB[cl] + (cotile*16+r)*KK[cl] + m*32 + q*8);
    for (int t = ph; t < NT[cl]; t += 2){
      int p = t*16 + r;
      bool ok = p < NPOS[cl];
      int pc = ok ? p : 0;
      int a_ = pc/NCOL[cl], c_ = pc - a_*NCOL[cl];
      int pb = a_*13 + c_;
      f32x4 acc = {0.f,0.f,0.f,0.f};
      #pragma unroll
      for (int m=0;m<NCH[cl];m++){
        int ci0 = (m&1)*32 + q*8;
        bf16x8 bv = *(const bf16x8*)&inp[(pb + TOFF[cl][m>>1])*64 + ci0];
        acc = __builtin_amdgcn_mfma_f32_16x16x32_bf16(af[m], bv, acc, 0, 0, 0);
      }
      if (ok){
        int pos = (2*a_+PI[cl])*25 + (2*c_+PJ[cl]);
        #pragma unroll
        for (int reg=0;reg<4;reg++){
          float y = acc[reg] + biasr[reg];
          out[((size_t)b*32 + cotile*16 + q*4 + reg)*625 + pos] = y;
          sacc[reg] += y; qacc[reg] += y*y;
        }
      }
    }
  }
  float* bk = bkt(hdr, b);
  #pragma unroll
  for (int reg=0;reg<4;reg++){
    float s = sacc[reg], qq = qacc[reg];
    for (int o=8;o;o>>=1){ s += __shfl_down(s,o,16); qq += __shfl_down(qq,o,16); }
    if (r==0){ atomicAdd(&bk[H_DS1+cotile*16+q*4+reg], s); atomicAdd(&bk[H_DQ1+cotile*16+q*4+reg], qq); }
  }
}

// ---------------- deconv2 (MFMA): 32->16, k2 s2 p1 op1, 25->49 ----------------
__global__ __launch_bounds__(256) void k_deconv2m(
    const float* __restrict__ g1, const ushort_t* __restrict__ WPK, const float* __restrict__ bg,
    const float* __restrict__ g, const float* __restrict__ be,
    float* __restrict__ hdr, float* __restrict__ out){
  __shared__ ushort_t inp[625*32];     // [cell 25x25][ci32]
  __shared__ float ac[64];
  const int b = blockIdx.x, tid = threadIdx.x;
  coef_lds(hdr, H_DS1, H_DQ1, g, be, ac, 32, 1.f/(512.f*625.f), tid);
  __syncthreads();
  for (int e = tid; e < 625*32; e += 256){
    int ci = e & 31, cell = e >> 5;
    float raw = g1[((size_t)b*32 + ci)*625 + cell];
    inp[e] = f2bf(fmaxf(fmaf(ac[ci], raw, ac[32+ci]), 0.f));
  }
  __syncthreads();
  const int wv = tid>>6, lane = tid&63, r = lane&15, q = lane>>4;
  float biasr[4];
  #pragma unroll
  for (int v=0;v<4;v++) biasr[v] = bg[q*4 + v];
  const int NCOL[4]={25,24,25,24}, NPOS[4]={625,600,600,576}, NT[4]={40,38,38,36},
            TOFF[4]={0,1,25,26}, PI[4]={0,0,1,1}, PJ[4]={0,1,0,1};
  const int ci0 = q*8;
  float sacc[4]={0,0,0,0}, qacc[4]={0,0,0,0};
  #pragma unroll
  for (int cl=0; cl<4; cl++){
    bf16x8 af = *(const bf16x8*)(WPK + OD2 + cl*512 + r*32 + q*8);
    for (int t = wv; t < NT[cl]; t += 4){
      int p = t*16 + r;
      bool ok = p < NPOS[cl];
      int pc = ok ? p : 0;
      int a_ = pc/NCOL[cl], c_ = pc - a_*NCOL[cl];
      int pb = a_*25 + c_;
      f32x4 acc = {0.f,0.f,0.f,0.f};
      bf16x8 bv = *(const bf16x8*)&inp[(pb + TOFF[cl])*32 + ci0];
      acc = __builtin_amdgcn_mfma_f32_16x16x32_bf16(af, bv, acc, 0, 0, 0);
      if (ok){
        int pos = (2*a_+PI[cl])*49 + (2*c_+PJ[cl]);
        #pragma unroll
        for (int reg=0;reg<4;reg++){
          float y = acc[reg] + biasr[reg];
          out[((size_t)b*16 + q*4 + reg)*2401 + pos] = y;
          sacc[reg] += y; qacc[reg] += y*y;
        }
      }
    }
  }
  float* bk = bkt(hdr, b);
  #pragma unroll
  for (int reg=0;reg<4;reg++){
    float s = sacc[reg], qq = qacc[reg];
    for (int o=8;o;o>>=1){ s += __shfl_down(s,o,16); qq += __shfl_down(qq,o,16); }
    if (r==0){ atomicAdd(&bk[H_DS2+q*4+reg], s); atomicAdd(&bk[H_DQ2+q*4+reg], qq); }
  }
}

// ---------------- deconv3: 16->1, k2 s2 p0, 49->98, + sigmoid ----------------
__global__ __launch_bounds__(256) void k_deconv3(const float* __restrict__ g2, const float* __restrict__ w,
                                                 const float* __restrict__ bias,
                                                 const float* __restrict__ g, const float* __restrict__ be,
                                                 float* __restrict__ hdr, float* __restrict__ out){
  __shared__ float ac[32];
  const int tid = threadIdx.x;
  coef_lds(hdr, H_DS2, H_DQ2, g, be, ac, 16, 1.f/(512.f*2401.f), tid);
  __syncthreads();
  int idx = blockIdx.x*256 + tid;
  if (idx >= 512*9604) return;
  int b = idx / 9604; int r = idx - b*9604;
  int oi = r / 98, oj = r - oi*98;
  int ki = oi & 1, kj = oj & 1, ii = oi >> 1, jj = oj >> 1;
  float acc = bias[0];
  const float* gp = g2 + (size_t)b*16*2401 + ii*49 + jj;
  #pragma unroll
  for (int ci=0; ci<16; ci++){
    float raw = gp[(size_t)ci*2401];
    float h = fmaxf(fmaf(ac[ci], raw, ac[16+ci]), 0.f);
    acc = fmaf(h, w[ci*4 + ki*2 + kj], acc);
  }
  out[idx] = 1.f/(1.f + __expf(-acc));
}

// ======================================================================
extern "C" void kernel_launch(void* const* d_in, const int* in_sizes, int n_in,
                              void* d_out, int out_size, void* d_ws, size_t ws_size,
                              hipStream_t stream){
  (void)in_sizes; (void)n_in; (void)out_size; (void)ws_size;
  const float* x     = (const float*)d_in[0];
  const float* c1w   = (const float*)d_in[1];
  const float* c1b   = (const float*)d_in[2];
  const float* bn1g  = (const float*)d_in[3];
  const float* bn1b  = (const float*)d_in[4];
  const float* c2w   = (const float*)d_in[5];
  const float* c2b   = (const float*)d_in[6];
  const float* bn2g  = (const float*)d_in[7];
  const float* bn2b  = (const float*)d_in[8];
  const float* c3w   = (const float*)d_in[9];
  const float* c3b   = (const float*)d_in[10];
  const float* bn3g  = (const float*)d_in[11];
  const float* bn3b  = (const float*)d_in[12];
  const float* c4w   = (const float*)d_in[13];
  const float* c4b   = (const float*)d_in[14];
  const float* bn4g  = (const float*)d_in[15];
  const float* bn4b  = (const float*)d_in[16];
  const float* mem   = (const float*)d_in[17];
  const float* d0w   = (const float*)d_in[18];
  const float* d0b   = (const float*)d_in[19];
  const float* dbn0g = (const float*)d_in[20];
  const float* dbn0b = (const float*)d_in[21];
  const float* d1w   = (const float*)d_in[22];
  const float* d1b   = (const float*)d_in[23];
  const float* dbn1g = (const float*)d_in[24];
  const float* dbn1b = (const float*)d_in[25];
  const float* d2w   = (const float*)d_in[26];
  const float* d2b   = (const float*)d_in[27];
  const float* dbn2g = (const float*)d_in[28];
  const float* dbn2b = (const float*)d_in[29];
  const float* d3w   = (const float*)d_in[30];
  const float* d3b   = (const float*)d_in[31];

  float* hdr  = (float*)d_ws;
  float* H2   = hdr + HDR_FLOATS;        // 512*32*625 (reused as G1)
  float* H3   = H2 + 10240000;           // 512*64*169 (reused as G0)
  float* ZRAW = H3 + 5537792;            // 512*2304
  float* ZH   = ZRAW + 1179648;          // 512*2304
  float* SIM  = ZH + 1179648;            // 512*2000
  float* WSLOT= SIM + 1024000;           // 73728 floats (holds WPK bf16)
  float* G2   = WSLOT + 73728;           // 512*16*2401
  ushort_t* MEMBF = (ushort_t*)(G2 + 19668992); // 2000*2304
  ushort_t* MEMT  = MEMBF + 4608000;            // 2304*2016
  ushort_t* ZBF   = MEMT + 4644864;             // 512*2304
  ushort_t* WBF   = ZBF + 1179648;              // 512*2016
  ushort_t* WPK   = (ushort_t*)WSLOT;
  float* G0 = H3;
  float* G1 = H2;
  float* OUT = (float*)d_out;

  hipMemsetAsync(hdr, 0, HDR_FLOATS*sizeof(float), stream);
  k_xstats   <<<1024, 256, 0, stream>>>(x, hdr);
  k_wprep2   <<<460, 256, 0, stream>>>(c2w, c3w, c4w, d0w, d1w, d2w, WPK);
  k_memrows  <<<2000, 256, 0, stream>>>(mem, hdr, MEMBF);
  k_memT     <<<72*63, 256, 0, stream>>>(mem, MEMT);
  k_conv2m   <<<1024, 256, 0, stream>>>(x, WPK, c2b, c1w, c1b, bn1g, bn1b, hdr, H2);
  k_conv3m   <<<512, 256, 0, stream>>>(H2, WPK, c3b, bn2g, bn2b, hdr, H3);
  k_conv4m   <<<512, 256, 0, stream>>>(H3, WPK, c4b, bn3g, bn3b, hdr, ZRAW);
  k_z        <<<512, 256, 0, stream>>>(ZRAW, hdr, ZBF, bn4g, bn4b);
  k_gemmB    <<<64, 256, 0, stream>>>(ZBF, MEMBF, SIM, 16, 2000, 2304, 72);
  k_softmax  <<<512, 256, 0, stream>>>(SIM, hdr, WBF);
  k_gemmB    <<<72, 256, 0, stream>>>(WBF, MEMT, ZH, 18, 2304, 2016, 63);
  k_deconv0m <<<512, 256, 0, stream>>>(ZH, WPK, d0b, hdr, G0);
  k_deconv1m <<<512, 256, 0, stream>>>(G0, WPK, d1b, dbn0g, dbn0b, hdr, G1);
  k_deconv2m <<<512, 256, 0, stream>>>(G1, WPK, d2b, dbn1g, dbn1b, hdr, G2);
  k_deconv3  <<<19208, 256, 0, stream>>>(G2, d3w, d3b, dbn2g, dbn2b, hdr, OUT);
}

// Round 6
// 451.993 us; speedup vs baseline: 2.9419x; 1.1529x over previous
//
#include <hip/hip_runtime.h>
#include <stdint.h>

// R6: R5 + split-K GEMM (4-way): 256/288 blocks instead of 64/72, K-chain
// 18/16 iters instead of 72/63. Partials in 4 fp32 buffers (overlaid on G2);
// k_softmax / k_deconv0m sum the partials on load.

typedef unsigned short ushort_t;
typedef __bf16 bf16x8 __attribute__((ext_vector_type(8)));
typedef float f32x4 __attribute__((ext_vector_type(4)));

#define DEV static __device__ __forceinline__

DEV ushort_t f2bf(float f){
  union { float f; uint32_t u; } v; v.f = f;
  return (ushort_t)((v.u + 0x7FFFu + ((v.u >> 16) & 1u)) >> 16);
}

// ---------------- header (stats/coeff) offsets in floats ----------------
#define H_XS   0
#define H_S2   64
#define H_Q2   96
#define H_S3   192
#define H_Q3   256
#define H_S4   448
#define H_Q4   512
#define H_DS0  704
#define H_DQ0  768
#define H_DS1  960
#define H_DQ1  992
#define H_DS2  1088
#define H_DQ2  1104
#define H_ZN   1152   // [512]
#define H_MN   1664   // [2000]
#define H_BUK  4096   // 16 bucket banks of 1280 floats each
#define NBUK   16
#define BSTRIDE 1280
#define HDR_FLOATS (H_BUK + NBUK*BSTRIDE)

// packed-weight (bf16) offsets in WPK
#define OW2 0        // [32][160]  k=tap*16+ci, taps 0..9 (tap9 = zero pad)
#define OW3 5120     // [64][288]  k=tap*32+ci
#define OW4 23552    // [64][576]  k=tap*64+ci
#define OD0 60416    // 4 classes [64][K], K={256,128,128,64}
#define OD1 97280    // 4 classes [32][K], K={64,128,128,256}
#define OD2 115712   // 4 classes [16][32]
#define NWPK 117760

#define SIMSTRIDE 1024000   // 512*2000
#define ZHSTRIDE  1179648   // 512*2304

DEV float* bkt(float* hdr, int blk){ return hdr + H_BUK + (size_t)(blk & (NBUK-1))*BSTRIDE; }

// compute per-channel affine (a,c) from buckets into LDS ac[2*nch]
DEV void coef_lds(const float* __restrict__ hdr, int offS, int offQ,
                  const float* __restrict__ g, const float* __restrict__ be,
                  float* ac, int nch, float invN, int tid){
  if (tid < nch){
    float s = 0.f, q = 0.f;
    #pragma unroll
    for (int k=0;k<NBUK;k++){
      s += hdr[H_BUK + k*BSTRIDE + offS + tid];
      q += hdr[H_BUK + k*BSTRIDE + offQ + tid];
    }
    float m = s*invN;
    float v = q*invN - m*m;
    float a = g[tid]*rsqrtf(v + 1e-5f);
    ac[tid] = a;
    ac[nch+tid] = be[tid] - m*a;
  }
}

// ---------------- stats of strided-sampled input (for bn1 fold) ----------------
__global__ __launch_bounds__(256) void k_xstats(const float* __restrict__ x, float* __restrict__ hdr){
  __shared__ float red[8];
  float s = 0.f, q = 0.f;
  const int total = 512*49*49;
  for (int idx = blockIdx.x*256 + threadIdx.x; idx < total; idx += gridDim.x*256){
    int b = idx / 2401;
    int r = idx - b*2401;
    int i = r / 49, j = r - i*49;
    float v = 0.f;
    if (i > 0 && j > 0) v = x[(size_t)b*9216 + (2*i-1)*96 + (2*j-1)];
    s += v; q += v*v;
  }
  for (int o=32;o;o>>=1){ s += __shfl_down(s,o,64); q += __shfl_down(q,o,64); }
  int w = threadIdx.x>>6;
  if ((threadIdx.x&63)==0){ red[w*2]=s; red[w*2+1]=q; }
  __syncthreads();
  if (threadIdx.x==0){
    float* bk = bkt(hdr, blockIdx.x);
    atomicAdd(&bk[H_XS+0], red[0]+red[2]+red[4]+red[6]);
    atomicAdd(&bk[H_XS+1], red[1]+red[3]+red[5]+red[7]);
  }
}

// ---------------- pack all conv/deconv weights to bf16 [co][k] ----------------
__global__ __launch_bounds__(256) void k_wprep2(
    const float* __restrict__ c2w, const float* __restrict__ c3w, const float* __restrict__ c4w,
    const float* __restrict__ d0w, const float* __restrict__ d1w, const float* __restrict__ d2w,
    ushort_t* __restrict__ WPK){
  int i = blockIdx.x*256 + threadIdx.x;
  if (i >= NWPK) return;
  float val = 0.f;
  if (i < OW3){                       // conv2 [32][160]
    int co = i/160, k = i - co*160, tap = k>>4, ci = k&15;
    if (tap < 9) val = c2w[(co*16+ci)*9+tap];
  } else if (i < OW4){                // conv3 [64][288]
    int r = i - OW3; int co = r/288, k = r - co*288, tap = k>>5, ci = k&31;
    val = c3w[(co*32+ci)*9+tap];
  } else if (i < OD0){                // conv4 [64][576]
    int r = i - OW4; int co = r/576, k = r - co*576, tap = k>>6, ci = k&63;
    val = c4w[(co*64+ci)*9+tap];
  } else if (i < OD1){                // deconv0 classes
    int r = i - OD0;
    const int base[4]={0,16384,24576,32768}, K[4]={256,128,128,64};
    const int T0[4][4] = {{0,2,6,8},{1,7,0,0},{3,5,0,0},{4,0,0,0}};
    int cl = (r<16384)?0:(r<24576)?1:(r<32768)?2:3;
    int rr = r - base[cl]; int co = rr/K[cl], k = rr - co*K[cl], t = k>>6, ci = k&63;
    val = d0w[(ci*64+co)*9 + T0[cl][t]];
  } else if (i < OD2){                // deconv1 classes
    int r = i - OD1;
    const int base[4]={0,2048,6144,10240}, K[4]={64,128,128,256};
    const int T1[4][4] = {{4,0,0,0},{3,5,0,0},{1,7,0,0},{0,2,6,8}};
    int cl = (r<2048)?0:(r<6144)?1:(r<10240)?2:3;
    int rr = r - base[cl]; int co = rr/K[cl], k = rr - co*K[cl], t = k>>6, ci = k&63;
    val = d1w[(ci*32+co)*9 + T1[cl][t]];
  } else {                            // deconv2 classes [4][16][32]
    int r = i - OD2;
    int cl = r>>9, s = r&511, co = s>>5, ci = s&31;
    const int pis[4]={0,0,1,1}, pjs[4]={0,1,0,1};
    val = d2w[((ci*16+co)*2 + (1-pis[cl]))*2 + (1-pjs[cl])];
  }
  WPK[i] = f2bf(val);
}

// ---------------- memory rows -> bf16 + row norms ----------------
__global__ __launch_bounds__(256) void k_memrows(const float* __restrict__ mem, float* __restrict__ hdr,
                                                 ushort_t* __restrict__ mbf){
  __shared__ float red[4];
  const int m = blockIdx.x, tid = threadIdx.x;
  float part = 0.f;
  for (int i=tid;i<2304;i+=256){
    float v = mem[(size_t)m*2304+i];
    mbf[(size_t)m*2304+i] = f2bf(v);
    part += v*v;
  }
  for (int o=32;o;o>>=1) part += __shfl_down(part,o,64);
  if ((tid&63)==0) red[tid>>6] = part;
  __syncthreads();
  if (tid==0) hdr[H_MN+m] = sqrtf(red[0]+red[1]+red[2]+red[3]);
}

__global__ __launch_bounds__(256) void k_memT(const float* __restrict__ mem, ushort_t* __restrict__ mt){
  __shared__ ushort_t tile[32][33];
  const int ft = blockIdx.x % 72, mtile = blockIdx.x / 72;
  const int tx = threadIdx.x & 31, ty = threadIdx.x >> 5;
  #pragma unroll
  for (int r0=0;r0<4;r0++){
    int m = mtile*32 + r0*8 + ty;
    int f = ft*32 + tx;
    float v = (m < 2000) ? mem[(size_t)m*2304 + f] : 0.f;
    tile[r0*8+ty][tx] = f2bf(v);
  }
  __syncthreads();
  #pragma unroll
  for (int r0=0;r0<4;r0++){
    int f = ft*32 + r0*8 + ty;
    mt[(size_t)f*2016 + mtile*32 + tx] = tile[tx][r0*8+ty];
  }
}

// ---------------- conv2 (MFMA): 16->32, 3x3 s2 p1 on folded conv1 output ----------------
__global__ __launch_bounds__(256) void k_conv2m(
    const float* __restrict__ x, const ushort_t* __restrict__ WPK, const float* __restrict__ b2g,
    const float* __restrict__ c1w, const float* __restrict__ c1b,
    const float* __restrict__ bn1g, const float* __restrict__ bn1b,
    float* __restrict__ hdr, float* __restrict__ out){
  __shared__ ushort_t inp[27*51*16];    // [row][col][ci16], halo'd 51-grid rows [2*ro..2*ro+26]
  __shared__ float ac[32];
  const int blk = blockIdx.x, b = blk>>1, h = blk&1, tid = threadIdx.x;
  const int ro = h*13, nr = h?12:13, npos = nr*25, ntiles = (npos+15)>>4;
  if (tid < 16){
    float sx=0.f, qx=0.f;
    #pragma unroll
    for (int k=0;k<NBUK;k++){ sx += hdr[H_BUK+k*BSTRIDE+H_XS]; qx += hdr[H_BUK+k*BSTRIDE+H_XS+1]; }
    const float N = 512.f*49.f*49.f;
    float mx = sx/N, vx = qx/N - mx*mx;
    float mean = c1w[tid]*mx + c1b[tid];
    float a = bn1g[tid]*rsqrtf(c1w[tid]*c1w[tid]*vx + 1e-5f);
    ac[tid] = a*c1w[tid];
    ac[16+tid] = a*(c1b[tid]-mean) + bn1b[tid];
  }
  __syncthreads();
  for (int e = tid; e < 27*51; e += 256){
    int lr = e/51, gc = e - lr*51;
    int grg = 2*ro + lr;
    bool inside = (grg>=1 && grg<=49 && gc>=1 && gc<=49);
    float v = 0.f;
    if (grg>=2 && grg<=49 && gc>=2 && gc<=49) v = x[(size_t)b*9216 + (2*grg-3)*96 + (2*gc-3)];
    ushort_t hv[16];
    if (inside){
      #pragma unroll
      for (int c=0;c<16;c++) hv[c] = f2bf(fmaxf(fmaf(ac[c], v, ac[16+c]), 0.f));
    } else {
      #pragma unroll
      for (int c=0;c<16;c++) hv[c] = 0;
    }
    uint32_t w0[8];
    #pragma unroll
    for (int c=0;c<8;c++) w0[c] = (uint32_t)hv[2*c] | ((uint32_t)hv[2*c+1]<<16);
    uint4* dst = (uint4*)&inp[e*16];
    dst[0] = make_uint4(w0[0],w0[1],w0[2],w0[3]);
    dst[1] = make_uint4(w0[4],w0[5],w0[6],w0[7]);
  }
  __syncthreads();
  const int wv = tid>>6, lane = tid&63, r = lane&15, q = lane>>4;
  const int cotile = wv&1;
  bf16x8 af[5];
  #pragma unroll
  for (int c=0;c<5;c++) af[c] = *(const bf16x8*)(WPK + OW2 + (cotile*16+r)*160 + c*32 + q*8);
  float biasr[4];
  #pragma unroll
  for (int v=0;v<4;v++) biasr[v] = b2g[cotile*16 + q*4 + v];
  const int TOFF[10] = {0,1,2,51,52,53,102,103,104,0};
  const int qhi = q>>1, ci0 = (q&1)*8;
  float sacc[4]={0,0,0,0}, qacc[4]={0,0,0,0};
  for (int t = wv>>1; t < ntiles; t += 2){
    int p = t*16 + r;
    bool ok = p < npos;
    int pc = ok ? p : 0;
    int a_ = pc/25, c_ = pc - a_*25;
    int pb = (2*a_)*51 + 2*c_;
    f32x4 acc = {0.f,0.f,0.f,0.f};
    #pragma unroll
    for (int c=0;c<5;c++){
      int toff = qhi ? TOFF[2*c+1] : TOFF[2*c];
      bf16x8 bv = *(const bf16x8*)&inp[(pb + toff)*16 + ci0];
      acc = __builtin_amdgcn_mfma_f32_16x16x32_bf16(af[c], bv, acc, 0, 0, 0);
    }
    if (ok){
      int pg = (ro + a_)*25 + c_;
      #pragma unroll
      for (int reg=0;reg<4;reg++){
        float y = acc[reg] + biasr[reg];
        out[((size_t)b*32 + cotile*16 + q*4 + reg)*625 + pg] = y;
        sacc[reg] += y; qacc[reg] += y*y;
      }
    }
  }
  float* bk = bkt(hdr, blk);
  #pragma unroll
  for (int reg=0;reg<4;reg++){
    float s = sacc[reg], qq = qacc[reg];
    for (int o=8;o;o>>=1){ s += __shfl_down(s,o,16); qq += __shfl_down(qq,o,16); }
    if (r==0){ atomicAdd(&bk[H_S2+cotile*16+q*4+reg], s); atomicAdd(&bk[H_Q2+cotile*16+q*4+reg], qq); }
  }
}

// ---------------- conv3 (MFMA): 32->64, 3x3 s2 p1, 25->13 ----------------
__global__ __launch_bounds__(256) void k_conv3m(
    const float* __restrict__ h2, const ushort_t* __restrict__ WPK, const float* __restrict__ b3g,
    const float* __restrict__ g, const float* __restrict__ be,
    float* __restrict__ hdr, float* __restrict__ out){
  __shared__ ushort_t inp[27*27*32];   // [cell][ci32], halo'd 27-grid
  __shared__ float ac[64];
  const int b = blockIdx.x, tid = threadIdx.x;
  coef_lds(hdr, H_S2, H_Q2, g, be, ac, 32, 1.f/(512.f*625.f), tid);
  __syncthreads();
  for (int e = tid; e < 27*27*32; e += 256){
    int ci = e & 31, cell = e >> 5;
    int gr = cell/27, gc = cell - gr*27;
    int i = gr-1, j = gc-1;
    float v = 0.f;
    if ((unsigned)i < 25u && (unsigned)j < 25u){
      float raw = h2[((size_t)b*32 + ci)*625 + i*25 + j];
      v = fmaxf(fmaf(ac[ci], raw, ac[32+ci]), 0.f);
    }
    inp[e] = f2bf(v);
  }
  __syncthreads();
  const int wv = tid>>6, lane = tid&63, r = lane&15, q = lane>>4;
  bf16x8 af[9];
  #pragma unroll
  for (int c=0;c<9;c++) af[c] = *(const bf16x8*)(WPK + OW3 + (wv*16+r)*288 + c*32 + q*8);
  float biasr[4];
  #pragma unroll
  for (int v=0;v<4;v++) biasr[v] = b3g[wv*16 + q*4 + v];
  const int TOFF[9] = {0,1,2,27,28,29,54,55,56};
  const int ci0 = q*8;
  float sacc[4]={0,0,0,0}, qacc[4]={0,0,0,0};
  for (int t = 0; t < 11; t++){
    int p = t*16 + r;
    bool ok = p < 169;
    int pc = ok ? p : 0;
    int a_ = pc/13, c_ = pc - a_*13;
    int pb = (2*a_)*27 + 2*c_;
    f32x4 acc = {0.f,0.f,0.f,0.f};
    #pragma unroll
    for (int c=0;c<9;c++){
      bf16x8 bv = *(const bf16x8*)&inp[(pb + TOFF[c])*32 + ci0];
      acc = __builtin_amdgcn_mfma_f32_16x16x32_bf16(af[c], bv, acc, 0, 0, 0);
    }
    if (ok){
      #pragma unroll
      for (int reg=0;reg<4;reg++){
        float y = acc[reg] + biasr[reg];
        out[((size_t)b*64 + wv*16 + q*4 + reg)*169 + p] = y;
        sacc[reg] += y; qacc[reg] += y*y;
      }
    }
  }
  float* bk = bkt(hdr, b);
  #pragma unroll
  for (int reg=0;reg<4;reg++){
    float s = sacc[reg], qq = qacc[reg];
    for (int o=8;o;o>>=1){ s += __shfl_down(s,o,16); qq += __shfl_down(qq,o,16); }
    if (r==0){ atomicAdd(&bk[H_S3+wv*16+q*4+reg], s); atomicAdd(&bk[H_Q3+wv*16+q*4+reg], qq); }
  }
}

// ---------------- conv4 (MFMA): 64->64, 3x3 s2 p0, 13->6 ----------------
__global__ __launch_bounds__(256) void k_conv4m(
    const float* __restrict__ h3, const ushort_t* __restrict__ WPK, const float* __restrict__ b4g,
    const float* __restrict__ g, const float* __restrict__ be,
    float* __restrict__ hdr, float* __restrict__ out){
  __shared__ ushort_t inp[169*64];     // [cell][ci64]
  __shared__ float ac[128];
  const int b = blockIdx.x, tid = threadIdx.x;
  coef_lds(hdr, H_S3, H_Q3, g, be, ac, 64, 1.f/(512.f*169.f), tid);
  __syncthreads();
  for (int e = tid; e < 169*64; e += 256){
    int ci = e & 63, cell = e >> 6;
    float raw = h3[((size_t)b*64 + ci)*169 + cell];
    inp[e] = f2bf(fmaxf(fmaf(ac[ci], raw, ac[64+ci]), 0.f));
  }
  __syncthreads();
  const int wv = tid>>6, lane = tid&63, r = lane&15, q = lane>>4;
  bf16x8 af[18];
  #pragma unroll
  for (int c=0;c<18;c++) af[c] = *(const bf16x8*)(WPK + OW4 + (wv*16+r)*576 + c*32 + q*8);
  float biasr[4];
  #pragma unroll
  for (int v=0;v<4;v++) biasr[v] = b4g[wv*16 + q*4 + v];
  const int TOFF[9] = {0,1,2,13,14,15,26,27,28};
  float sacc[4]={0,0,0,0}, qacc[4]={0,0,0,0};
  for (int t = 0; t < 3; t++){
    int p = t*16 + r;
    bool ok = p < 36;
    int pc = ok ? p : 0;
    int a_ = pc/6, c_ = pc - a_*6;
    int pb = (2*a_)*13 + 2*c_;
    f32x4 acc = {0.f,0.f,0.f,0.f};
    #pragma unroll
    for (int c=0;c<18;c++){
      int ci0 = (c&1)*32 + q*8;
      bf16x8 bv = *(const bf16x8*)&inp[(pb + TOFF[c>>1])*64 + ci0];
      acc = __builtin_amdgcn_mfma_f32_16x16x32_bf16(af[c], bv, acc, 0, 0, 0);
    }
    if (ok){
      #pragma unroll
      for (int reg=0;reg<4;reg++){
        float y = acc[reg] + biasr[reg];
        out[((size_t)b*64 + wv*16 + q*4 + reg)*36 + p] = y;
        sacc[reg] += y; qacc[reg] += y*y;
      }
    }
  }
  float* bk = bkt(hdr, b);
  #pragma unroll
  for (int reg=0;reg<4;reg++){
    float s = sacc[reg], qq = qacc[reg];
    for (int o=8;o;o>>=1){ s += __shfl_down(s,o,16); qq += __shfl_down(qq,o,16); }
    if (r==0){ atomicAdd(&bk[H_S4+wv*16+q*4+reg], s); atomicAdd(&bk[H_Q4+wv*16+q*4+reg], qq); }
  }
}

// z = relu(bn4(conv4 raw)) -> bf16, plus per-row norm (computes A4/C4 itself)
__global__ __launch_bounds__(256) void k_z(const float* __restrict__ zraw, float* __restrict__ hdr,
                                           ushort_t* __restrict__ zbf,
                                           const float* __restrict__ g, const float* __restrict__ be){
  __shared__ float ac[128];
  __shared__ float red[4];
  const int b = blockIdx.x, tid = threadIdx.x;
  coef_lds(hdr, H_S4, H_Q4, g, be, ac, 64, 1.f/(512.f*36.f), tid);
  __syncthreads();
  float part = 0.f;
  for (int i=tid;i<2304;i+=256){
    int c = i/36;
    float h = fmaxf(fmaf(ac[c], zraw[(size_t)b*2304+i], ac[64+c]), 0.f);
    zbf[(size_t)b*2304+i] = f2bf(h);
    part += h*h;
  }
  for (int o=32;o;o>>=1) part += __shfl_down(part,o,64);
  if ((tid&63)==0) red[tid>>6] = part;
  __syncthreads();
  if (tid==0) hdr[H_ZN+b] = sqrtf(red[0]+red[1]+red[2]+red[3]);
}

// ---------------- blocked GEMM, split-K: D_s[M][N] = A[M][ks] * B[N][ks]^T
// 128x128 block, 4 waves x (64x64), BK=32; nsplit=4 partial buffers.
__global__ __launch_bounds__(256) void k_gemmB(const ushort_t* __restrict__ A, const ushort_t* __restrict__ Bm,
                                               float* __restrict__ D, int Nb, int N, int Kp, int kch,
                                               int tiles, int ksp, size_t dstride){
  __shared__ __align__(16) ushort_t lB[128*40];
  const int blk = blockIdx.x;
  const int s = blk / tiles, t = blk - s*tiles;
  const int bi = t / Nb, bj = t - bi*Nb;
  const int m0 = bi*128, n0 = bj*128;
  const int k0 = s*ksp, k1 = min(kch, k0 + ksp);
  const int tid = threadIdx.x;
  const int lane = tid & 63, wv = tid >> 6;
  const int r = lane & 15, q = lane >> 4;
  const int wr = wv >> 1, wc = wv & 1;
  float* Ds = D + (size_t)s*dstride;
  // B staging: thread t -> row t>>1, k-offset (t&1)*16 (two 16B chunks)
  const int srow = tid >> 1, skq = (tid & 1) * 16;
  const bool bok = (n0 + srow) < N;
  const ushort_t* pb = Bm + (size_t)(n0 + srow)*Kp + skq;
  uint4* wB = (uint4*)&lB[srow*40 + skq];
  const uint4 zz = make_uint4(0,0,0,0);
  uint4 rb0 = bok ? *(const uint4*)(pb + k0*32)     : zz;
  uint4 rb1 = bok ? *(const uint4*)(pb + k0*32 + 8) : zz;
  // A frags: direct global, rows m0 + wr*64 + mt*16 + r, k chunk q*8
  const ushort_t* pa = A + (size_t)(m0 + wr*64 + r)*Kp + q*8;
  bf16x8 aN[4];
  #pragma unroll
  for (int mt=0;mt<4;mt++) aN[mt] = *(const bf16x8*)(pa + k0*32 + (size_t)(mt*16)*Kp);
  f32x4 acc[4][4];
  #pragma unroll
  for (int i=0;i<4;i++)
    #pragma unroll
    for (int j=0;j<4;j++) acc[i][j] = (f32x4){0.f,0.f,0.f,0.f};
  for (int k=k0; k<k1; k++){
    if (k > k0) __syncthreads();
    wB[0] = rb0; wB[1] = rb1;
    bf16x8 aF[4];
    #pragma unroll
    for (int mt=0;mt<4;mt++) aF[mt] = aN[mt];
    if (k+1 < k1){
      const ushort_t* nb = pb + (k+1)*32;
      rb0 = bok ? *(const uint4*)(nb)     : zz;
      rb1 = bok ? *(const uint4*)(nb + 8) : zz;
      const ushort_t* na = pa + (k+1)*32;
      #pragma unroll
      for (int mt=0;mt<4;mt++) aN[mt] = *(const bf16x8*)(na + (size_t)(mt*16)*Kp);
    }
    __syncthreads();
    bf16x8 bF[4];
    #pragma unroll
    for (int nt=0;nt<4;nt++) bF[nt] = *(const bf16x8*)&lB[(wc*64+nt*16+r)*40 + q*8];
    #pragma unroll
    for (int mt=0;mt<4;mt++)
      #pragma unroll
      for (int nt=0;nt<4;nt++)
        acc[mt][nt] = __builtin_amdgcn_mfma_f32_16x16x32_bf16(aF[mt], bF[nt], acc[mt][nt], 0, 0, 0);
  }
  #pragma unroll
  for (int mt=0;mt<4;mt++){
    int row = m0 + wr*64 + mt*16 + q*4;
    #pragma unroll
    for (int nt=0;nt<4;nt++){
      int col = n0 + wc*64 + nt*16 + r;
      if (col < N){
        #pragma unroll
        for (int reg=0;reg<4;reg++)
          Ds[(size_t)(row+reg)*N + col] = acc[mt][nt][reg];
      }
    }
  }
}

// softmax over M=2000 (sums 4 split-K partials) + hard-shrink + L1 renorm -> bf16
__global__ __launch_bounds__(256) void k_softmax(const float* __restrict__ sim, float* __restrict__ hdr,
                                                 ushort_t* __restrict__ wbf){
  __shared__ float e[2000];
  __shared__ float red[8];
  const int b = blockIdx.x, tid = threadIdx.x;
  const float znb = hdr[H_ZN+b];
  float part = 0.f;
  for (int m=tid;m<2000;m+=256){
    size_t ix = (size_t)b*2000+m;
    float sv = sim[ix] + sim[ix+SIMSTRIDE] + sim[ix+2*SIMSTRIDE] + sim[ix+3*SIMSTRIDE];
    float s = sv / fmaxf(znb * hdr[H_MN+m], 1e-8f);
    float ev = __expf(s);
    e[m] = ev; part += ev;
  }
  for (int o=32;o;o>>=1) part += __shfl_down(part,o,64);
  if ((tid&63)==0) red[tid>>6] = part;
  __syncthreads();
  const float denom = red[0]+red[1]+red[2]+red[3];
  const float t = 1.0f/2000.0f;
  float part2 = 0.f;
  for (int m=tid;m<2000;m+=256){
    float w = e[m]/denom;
    float d = w - t;
    float sh = fmaxf(d,0.f)*w/(fabsf(d)+0.01f);
    e[m] = sh; part2 += sh;
  }
  for (int o=32;o;o>>=1) part2 += __shfl_down(part2,o,64);
  if ((tid&63)==0) red[4+(tid>>6)] = part2;
  __syncthreads();
  const float inv = 1.0f/(red[4]+red[5]+red[6]+red[7]);
  for (int m=tid;m<2016;m+=256){
    ushort_t o = 0;
    if (m < 2000) o = f2bf(e[m]*inv);
    wbf[(size_t)b*2016+m] = o;
  }
}

// ---------------- deconv0 (MFMA): 64->64, k3 s2 p0, 6->13 (sums 4 zh partials) ----------------
__global__ __launch_bounds__(256) void k_deconv0m(
    const float* __restrict__ zh, const ushort_t* __restrict__ WPK, const float* __restrict__ b0g,
    float* __restrict__ hdr, float* __restrict__ out){
  __shared__ ushort_t inp[64*64];      // [cell 8x8 halo][ci64]
  const int b = blockIdx.x, tid = threadIdx.x;
  for (int e = tid; e < 64*64; e += 256){
    int ci = e & 63, cell = e >> 6;
    int r8 = cell>>3, c8 = cell&7;
    float v = 0.f;
    if (r8>=1 && r8<=6 && c8>=1 && c8<=6){
      size_t ix = (size_t)b*2304 + ci*36 + (r8-1)*6 + (c8-1);
      v = zh[ix] + zh[ix+ZHSTRIDE] + zh[ix+2*ZHSTRIDE] + zh[ix+3*ZHSTRIDE];
    }
    inp[e] = f2bf(v);
  }
  __syncthreads();
  const int wv = tid>>6, lane = tid&63, r = lane&15, q = lane>>4;
  float biasr[4];
  #pragma unroll
  for (int v=0;v<4;v++) biasr[v] = b0g[wv*16 + q*4 + v];
  const int NCOL[4]={7,6,7,6}, NPOS[4]={49,42,42,36}, NT[4]={4,3,3,3},
            NCH[4]={8,4,4,2}, KB[4]={0,16384,24576,32768}, KK[4]={256,128,128,64},
            PI[4]={0,0,1,1}, PJ[4]={0,1,0,1};
  const int TOFF[4][4] = {{9,8,1,0},{9,1,0,0},{9,8,0,0},{9,0,0,0}};
  float sacc[4]={0,0,0,0}, qacc[4]={0,0,0,0};
  #pragma unroll
  for (int cl=0; cl<4; cl++){
    bf16x8 af[8];
    #pragma unroll
    for (int m=0;m<NCH[cl];m++)
      af[m] = *(const bf16x8*)(WPK + OD0 + KB[cl] + (wv*16+r)*KK[cl] + m*32 + q*8);
    for (int t = 0; t < NT[cl]; t++){
      int p = t*16 + r;
      bool ok = p < NPOS[cl];
      int pc = ok ? p : 0;
      int a_ = pc/NCOL[cl], c_ = pc - a_*NCOL[cl];
      int pb = a_*8 + c_;
      f32x4 acc = {0.f,0.f,0.f,0.f};
      #pragma unroll
      for (int m=0;m<NCH[cl];m++){
        int ci0 = (m&1)*32 + q*8;
        bf16x8 bv = *(const bf16x8*)&inp[(pb + TOFF[cl][m>>1])*64 + ci0];
        acc = __builtin_amdgcn_mfma_f32_16x16x32_bf16(af[m], bv, acc, 0, 0, 0);
      }
      if (ok){
        int pos = (2*a_+PI[cl])*13 + (2*c_+PJ[cl]);
        #pragma unroll
        for (int reg=0;reg<4;reg++){
          float y = acc[reg] + biasr[reg];
          out[((size_t)b*64 + wv*16 + q*4 + reg)*169 + pos] = y;
          sacc[reg] += y; qacc[reg] += y*y;
        }
      }
    }
  }
  float* bk = bkt(hdr, b);
  #pragma unroll
  for (int reg=0;reg<4;reg++){
    float s = sacc[reg], qq = qacc[reg];
    for (int o=8;o;o>>=1){ s += __shfl_down(s,o,16); qq += __shfl_down(qq,o,16); }
    if (r==0){ atomicAdd(&bk[H_DS0+wv*16+q*4+reg], s); atomicAdd(&bk[H_DQ0+wv*16+q*4+reg], qq); }
  }
}

// ---------------- deconv1 (MFMA): 64->32, k3 s2 p1, 13->25 ----------------
__global__ __launch_bounds__(256) void k_deconv1m(
    const float* __restrict__ g0, const ushort_t* __restrict__ WPK, const float* __restrict__ b1g,
    const float* __restrict__ g, const float* __restrict__ be,
    float* __restrict__ hdr, float* __restrict__ out){
  __shared__ ushort_t inp[169*64];     // [cell 13x13][ci64]
  __shared__ float ac[128];
  const int b = blockIdx.x, tid = threadIdx.x;
  coef_lds(hdr, H_DS0, H_DQ0, g, be, ac, 64, 1.f/(512.f*169.f), tid);
  __syncthreads();
  for (int e = tid; e < 169*64; e += 256){
    int ci = e & 63, cell = e >> 6;
    float raw = g0[((size_t)b*64 + ci)*169 + cell];
    inp[e] = f2bf(fmaxf(fmaf(ac[ci], raw, ac[64+ci]), 0.f));
  }
  __syncthreads();
  const int wv = tid>>6, lane = tid&63, r = lane&15, q = lane>>4;
  const int cotile = wv&1, ph = wv>>1;
  float biasr[4];
  #pragma unroll
  for (int v=0;v<4;v++) biasr[v] = b1g[cotile*16 + q*4 + v];
  const int NCOL[4]={13,12,13,12}, NPOS[4]={169,156,156,144}, NT[4]={11,10,10,9},
            NCH[4]={2,4,4,8}, KB[4]={0,2048,6144,10240}, KK[4]={64,128,128,256},
            PI[4]={0,0,1,1}, PJ[4]={0,1,0,1};
  const int TOFF[4][4] = {{0,0,0,0},{1,0,0,0},{13,0,0,0},{14,13,1,0}};
  float sacc[4]={0,0,0,0}, qacc[4]={0,0,0,0};
  #pragma unroll
  for (int cl=0; cl<4; cl++){
    bf16x8 af[8];
    #pragma unroll
    for (int m=0;m<NCH[cl];m++)
      af[m] = *(const bf16x8*)(WPK + OD1 + KB[cl] + (cotile*16+r)*KK[cl] + m*32 + q*8);
    for (int t = ph; t < NT[cl]; t += 2){
      int p = t*16 + r;
      bool ok = p < NPOS[cl];
      int pc = ok ? p : 0;
      int a_ = pc/NCOL[cl], c_ = pc - a_*NCOL[cl];
      int pb = a_*13 + c_;
      f32x4 acc = {0.f,0.f,0.f,0.f};
      #pragma unroll
      for (int m=0;m<NCH[cl];m++){
        int ci0 = (m&1)*32 + q*8;
        bf16x8 bv = *(const bf16x8*)&inp[(pb + TOFF[cl][m>>1])*64 + ci0];
        acc = __builtin_amdgcn_mfma_f32_16x16x32_bf16(af[m], bv, acc, 0, 0, 0);
      }
      if (ok){
        int pos = (2*a_+PI[cl])*25 + (2*c_+PJ[cl]);
        #pragma unroll
        for (int reg=0;reg<4;reg++){
          float y = acc[reg] + biasr[reg];
          out[((size_t)b*32 + cotile*16 + q*4 + reg)*625 + pos] = y;
          sacc[reg] += y; qacc[reg] += y*y;
        }
      }
    }
  }
  float* bk = bkt(hdr, b);
  #pragma unroll
  for (int reg=0;reg<4;reg++){
    float s = sacc[reg], qq = qacc[reg];
    for (int o=8;o;o>>=1){ s += __shfl_down(s,o,16); qq += __shfl_down(qq,o,16); }
    if (r==0){ atomicAdd(&bk[H_DS1+cotile*16+q*4+reg], s); atomicAdd(&bk[H_DQ1+cotile*16+q*4+reg], qq); }
  }
}

// ---------------- deconv2 (MFMA): 32->16, k2 s2 p1 op1, 25->49 ----------------
__global__ __launch_bounds__(256) void k_deconv2m(
    const float* __restrict__ g1, const ushort_t* __restrict__ WPK, const float* __restrict__ bg,
    const float* __restrict__ g, const float* __restrict__ be,
    float* __restrict__ hdr, float* __restrict__ out){
  __shared__ ushort_t inp[625*32];     // [cell 25x25][ci32]
  __shared__ float ac[64];
  const int b = blockIdx.x, tid = threadIdx.x;
  coef_lds(hdr, H_DS1, H_DQ1, g, be, ac, 32, 1.f/(512.f*625.f), tid);
  __syncthreads();
  for (int e = tid; e < 625*32; e += 256){
    int ci = e & 31, cell = e >> 5;
    float raw = g1[((size_t)b*32 + ci)*625 + cell];
    inp[e] = f2bf(fmaxf(fmaf(ac[ci], raw, ac[32+ci]), 0.f));
  }
  __syncthreads();
  const int wv = tid>>6, lane = tid&63, r = lane&15, q = lane>>4;
  float biasr[4];
  #pragma unroll
  for (int v=0;v<4;v++) biasr[v] = bg[q*4 + v];
  const int NCOL[4]={25,24,25,24}, NPOS[4]={625,600,600,576}, NT[4]={40,38,38,36},
            TOFF[4]={0,1,25,26}, PI[4]={0,0,1,1}, PJ[4]={0,1,0,1};
  const int ci0 = q*8;
  float sacc[4]={0,0,0,0}, qacc[4]={0,0,0,0};
  #pragma unroll
  for (int cl=0; cl<4; cl++){
    bf16x8 af = *(const bf16x8*)(WPK + OD2 + cl*512 + r*32 + q*8);
    for (int t = wv; t < NT[cl]; t += 4){
      int p = t*16 + r;
      bool ok = p < NPOS[cl];
      int pc = ok ? p : 0;
      int a_ = pc/NCOL[cl], c_ = pc - a_*NCOL[cl];
      int pb = a_*25 + c_;
      f32x4 acc = {0.f,0.f,0.f,0.f};
      bf16x8 bv = *(const bf16x8*)&inp[(pb + TOFF[cl])*32 + ci0];
      acc = __builtin_amdgcn_mfma_f32_16x16x32_bf16(af, bv, acc, 0, 0, 0);
      if (ok){
        int pos = (2*a_+PI[cl])*49 + (2*c_+PJ[cl]);
        #pragma unroll
        for (int reg=0;reg<4;reg++){
          float y = acc[reg] + biasr[reg];
          out[((size_t)b*16 + q*4 + reg)*2401 + pos] = y;
          sacc[reg] += y; qacc[reg] += y*y;
        }
      }
    }
  }
  float* bk = bkt(hdr, b);
  #pragma unroll
  for (int reg=0;reg<4;reg++){
    float s = sacc[reg], qq = qacc[reg];
    for (int o=8;o;o>>=1){ s += __shfl_down(s,o,16); qq += __shfl_down(qq,o,16); }
    if (r==0){ atomicAdd(&bk[H_DS2+q*4+reg], s); atomicAdd(&bk[H_DQ2+q*4+reg], qq); }
  }
}

// ---------------- deconv3: 16->1, k2 s2 p0, 49->98, + sigmoid ----------------
__global__ __launch_bounds__(256) void k_deconv3(const float* __restrict__ g2, const float* __restrict__ w,
                                                 const float* __restrict__ bias,
                                                 const float* __restrict__ g, const float* __restrict__ be,
                                                 float* __restrict__ hdr, float* __restrict__ out){
  __shared__ float ac[32];
  const int tid = threadIdx.x;
  coef_lds(hdr, H_DS2, H_DQ2, g, be, ac, 16, 1.f/(512.f*2401.f), tid);
  __syncthreads();
  int idx = blockIdx.x*256 + tid;
  if (idx >= 512*9604) return;
  int b = idx / 9604; int r = idx - b*9604;
  int oi = r / 98, oj = r - oi*98;
  int ki = oi & 1, kj = oj & 1, ii = oi >> 1, jj = oj >> 1;
  float acc = bias[0];
  const float* gp = g2 + (size_t)b*16*2401 + ii*49 + jj;
  #pragma unroll
  for (int ci=0; ci<16; ci++){
    float raw = gp[(size_t)ci*2401];
    float h = fmaxf(fmaf(ac[ci], raw, ac[16+ci]), 0.f);
    acc = fmaf(h, w[ci*4 + ki*2 + kj], acc);
  }
  out[idx] = 1.f/(1.f + __expf(-acc));
}

// ======================================================================
extern "C" void kernel_launch(void* const* d_in, const int* in_sizes, int n_in,
                              void* d_out, int out_size, void* d_ws, size_t ws_size,
                              hipStream_t stream){
  (void)in_sizes; (void)n_in; (void)out_size; (void)ws_size;
  const float* x     = (const float*)d_in[0];
  const float* c1w   = (const float*)d_in[1];
  const float* c1b   = (const float*)d_in[2];
  const float* bn1g  = (const float*)d_in[3];
  const float* bn1b  = (const float*)d_in[4];
  const float* c2w   = (const float*)d_in[5];
  const float* c2b   = (const float*)d_in[6];
  const float* bn2g  = (const float*)d_in[7];
  const float* bn2b  = (const float*)d_in[8];
  const float* c3w   = (const float*)d_in[9];
  const float* c3b   = (const float*)d_in[10];
  const float* bn3g  = (const float*)d_in[11];
  const float* bn3b  = (const float*)d_in[12];
  const float* c4w   = (const float*)d_in[13];
  const float* c4b   = (const float*)d_in[14];
  const float* bn4g  = (const float*)d_in[15];
  const float* bn4b  = (const float*)d_in[16];
  const float* mem   = (const float*)d_in[17];
  const float* d0w   = (const float*)d_in[18];
  const float* d0b   = (const float*)d_in[19];
  const float* dbn0g = (const float*)d_in[20];
  const float* dbn0b = (const float*)d_in[21];
  const float* d1w   = (const float*)d_in[22];
  const float* d1b   = (const float*)d_in[23];
  const float* dbn1g = (const float*)d_in[24];
  const float* dbn1b = (const float*)d_in[25];
  const float* d2w   = (const float*)d_in[26];
  const float* d2b   = (const float*)d_in[27];
  const float* dbn2g = (const float*)d_in[28];
  const float* dbn2b = (const float*)d_in[29];
  const float* d3w   = (const float*)d_in[30];
  const float* d3b   = (const float*)d_in[31];

  float* hdr  = (float*)d_ws;
  float* H2   = hdr + HDR_FLOATS;        // 512*32*625 (reused as G1)
  float* H3   = H2 + 10240000;           // 512*64*169 (reused as G0)
  float* ZRAW = H3 + 5537792;            // 512*2304
  float* WSLOT= ZRAW + 1179648;          // 73728 floats (holds WPK bf16)
  float* G2   = WSLOT + 73728;           // 512*16*2401 = 19,668,992
  ushort_t* MEMBF = (ushort_t*)(G2 + 19668992); // 2000*2304
  ushort_t* MEMT  = MEMBF + 4608000;            // 2304*2016
  ushort_t* ZBF   = MEMT + 4644864;             // 512*2304
  ushort_t* WBF   = ZBF + 1179648;              // 512*2016
  ushort_t* WPK   = (ushort_t*)WSLOT;
  // split-K partials overlaid on G2 (written before deconv2m overwrites G2):
  float* SIMP = G2;                      // 4 * 512*2000
  float* ZHP  = G2 + 4*SIMSTRIDE;        // 4 * 512*2304  (needs 8.8M floats <= 19.6M: fits w/ SIMP? SIMP 4.1M + ZHP 4.7M = 8.8M < 19.6M ok)
  float* G0 = H3;
  float* G1 = H2;
  float* OUT = (float*)d_out;

  hipMemsetAsync(hdr, 0, HDR_FLOATS*sizeof(float), stream);
  k_xstats   <<<1024, 256, 0, stream>>>(x, hdr);
  k_wprep2   <<<460, 256, 0, stream>>>(c2w, c3w, c4w, d0w, d1w, d2w, WPK);
  k_memrows  <<<2000, 256, 0, stream>>>(mem, hdr, MEMBF);
  k_memT     <<<72*63, 256, 0, stream>>>(mem, MEMT);
  k_conv2m   <<<1024, 256, 0, stream>>>(x, WPK, c2b, c1w, c1b, bn1g, bn1b, hdr, H2);
  k_conv3m   <<<512, 256, 0, stream>>>(H2, WPK, c3b, bn2g, bn2b, hdr, H3);
  k_conv4m   <<<512, 256, 0, stream>>>(H3, WPK, c4b, bn3g, bn3b, hdr, ZRAW);
  k_z        <<<512, 256, 0, stream>>>(ZRAW, hdr, ZBF, bn4g, bn4b);
  k_gemmB    <<<256, 256, 0, stream>>>(ZBF, MEMBF, SIMP, 16, 2000, 2304, 72, 64, 18, SIMSTRIDE);
  k_softmax  <<<512, 256, 0, stream>>>(SIMP, hdr, WBF);
  k_gemmB    <<<288, 256, 0, stream>>>(WBF, MEMT, ZHP, 18, 2304, 2016, 63, 72, 16, ZHSTRIDE);
  k_deconv0m <<<512, 256, 0, stream>>>(ZHP, WPK, d0b, hdr, G0);
  k_deconv1m <<<512, 256, 0, stream>>>(G0, WPK, d1b, dbn0g, dbn0b, hdr, G1);
  k_deconv2m <<<512, 256, 0, stream>>>(G1, WPK, d2b, dbn1g, dbn1b, hdr, G2);
  k_deconv3  <<<19208, 256, 0, stream>>>(G2, d3w, d3b, dbn2g, dbn2b, hdr, OUT);
}

// Round 7
// 447.359 us; speedup vs baseline: 2.9723x; 1.0104x over previous
//
#include <hip/hip_runtime.h>
#include <stdint.h>

// R7: R6 + deconv2 output re-layout: bf16 parity-plane format [b][co][cl][625]
// (dense per-class writes -> no write amplification, half the bytes) and
// class-per-wave loop in k_deconv2m. k_deconv3 does the inverse index map.

typedef unsigned short ushort_t;
typedef __bf16 bf16x8 __attribute__((ext_vector_type(8)));
typedef float f32x4 __attribute__((ext_vector_type(4)));

#define DEV static __device__ __forceinline__

DEV ushort_t f2bf(float f){
  union { float f; uint32_t u; } v; v.f = f;
  return (ushort_t)((v.u + 0x7FFFu + ((v.u >> 16) & 1u)) >> 16);
}
DEV float bf2f(ushort_t u){
  union { uint32_t u; float f; } v; v.u = ((uint32_t)u) << 16;
  return v.f;
}

// ---------------- header (stats/coeff) offsets in floats ----------------
#define H_XS   0
#define H_S2   64
#define H_Q2   96
#define H_S3   192
#define H_Q3   256
#define H_S4   448
#define H_Q4   512
#define H_DS0  704
#define H_DQ0  768
#define H_DS1  960
#define H_DQ1  992
#define H_DS2  1088
#define H_DQ2  1104
#define H_ZN   1152   // [512]
#define H_MN   1664   // [2000]
#define H_BUK  4096   // 16 bucket banks of 1280 floats each
#define NBUK   16
#define BSTRIDE 1280
#define HDR_FLOATS (H_BUK + NBUK*BSTRIDE)

// packed-weight (bf16) offsets in WPK
#define OW2 0        // [32][160]  k=tap*16+ci, taps 0..9 (tap9 = zero pad)
#define OW3 5120     // [64][288]  k=tap*32+ci
#define OW4 23552    // [64][576]  k=tap*64+ci
#define OD0 60416    // 4 classes [64][K], K={256,128,128,64}
#define OD1 97280    // 4 classes [32][K], K={64,128,128,256}
#define OD2 115712   // 4 classes [16][32]
#define NWPK 117760

#define SIMSTRIDE 1024000   // 512*2000
#define ZHSTRIDE  1179648   // 512*2304

DEV float* bkt(float* hdr, int blk){ return hdr + H_BUK + (size_t)(blk & (NBUK-1))*BSTRIDE; }

// compute per-channel affine (a,c) from buckets into LDS ac[2*nch]
DEV void coef_lds(const float* __restrict__ hdr, int offS, int offQ,
                  const float* __restrict__ g, const float* __restrict__ be,
                  float* ac, int nch, float invN, int tid){
  if (tid < nch){
    float s = 0.f, q = 0.f;
    #pragma unroll
    for (int k=0;k<NBUK;k++){
      s += hdr[H_BUK + k*BSTRIDE + offS + tid];
      q += hdr[H_BUK + k*BSTRIDE + offQ + tid];
    }
    float m = s*invN;
    float v = q*invN - m*m;
    float a = g[tid]*rsqrtf(v + 1e-5f);
    ac[tid] = a;
    ac[nch+tid] = be[tid] - m*a;
  }
}

// ---------------- stats of strided-sampled input (for bn1 fold) ----------------
__global__ __launch_bounds__(256) void k_xstats(const float* __restrict__ x, float* __restrict__ hdr){
  __shared__ float red[8];
  float s = 0.f, q = 0.f;
  const int total = 512*49*49;
  for (int idx = blockIdx.x*256 + threadIdx.x; idx < total; idx += gridDim.x*256){
    int b = idx / 2401;
    int r = idx - b*2401;
    int i = r / 49, j = r - i*49;
    float v = 0.f;
    if (i > 0 && j > 0) v = x[(size_t)b*9216 + (2*i-1)*96 + (2*j-1)];
    s += v; q += v*v;
  }
  for (int o=32;o;o>>=1){ s += __shfl_down(s,o,64); q += __shfl_down(q,o,64); }
  int w = threadIdx.x>>6;
  if ((threadIdx.x&63)==0){ red[w*2]=s; red[w*2+1]=q; }
  __syncthreads();
  if (threadIdx.x==0){
    float* bk = bkt(hdr, blockIdx.x);
    atomicAdd(&bk[H_XS+0], red[0]+red[2]+red[4]+red[6]);
    atomicAdd(&bk[H_XS+1], red[1]+red[3]+red[5]+red[7]);
  }
}

// ---------------- pack all conv/deconv weights to bf16 [co][k] ----------------
__global__ __launch_bounds__(256) void k_wprep2(
    const float* __restrict__ c2w, const float* __restrict__ c3w, const float* __restrict__ c4w,
    const float* __restrict__ d0w, const float* __restrict__ d1w, const float* __restrict__ d2w,
    ushort_t* __restrict__ WPK){
  int i = blockIdx.x*256 + threadIdx.x;
  if (i >= NWPK) return;
  float val = 0.f;
  if (i < OW3){                       // conv2 [32][160]
    int co = i/160, k = i - co*160, tap = k>>4, ci = k&15;
    if (tap < 9) val = c2w[(co*16+ci)*9+tap];
  } else if (i < OW4){                // conv3 [64][288]
    int r = i - OW3; int co = r/288, k = r - co*288, tap = k>>5, ci = k&31;
    val = c3w[(co*32+ci)*9+tap];
  } else if (i < OD0){                // conv4 [64][576]
    int r = i - OW4; int co = r/576, k = r - co*576, tap = k>>6, ci = k&63;
    val = c4w[(co*64+ci)*9+tap];
  } else if (i < OD1){                // deconv0 classes
    int r = i - OD0;
    const int base[4]={0,16384,24576,32768}, K[4]={256,128,128,64};
    const int T0[4][4] = {{0,2,6,8},{1,7,0,0},{3,5,0,0},{4,0,0,0}};
    int cl = (r<16384)?0:(r<24576)?1:(r<32768)?2:3;
    int rr = r - base[cl]; int co = rr/K[cl], k = rr - co*K[cl], t = k>>6, ci = k&63;
    val = d0w[(ci*64+co)*9 + T0[cl][t]];
  } else if (i < OD2){                // deconv1 classes
    int r = i - OD1;
    const int base[4]={0,2048,6144,10240}, K[4]={64,128,128,256};
    const int T1[4][4] = {{4,0,0,0},{3,5,0,0},{1,7,0,0},{0,2,6,8}};
    int cl = (r<2048)?0:(r<6144)?1:(r<10240)?2:3;
    int rr = r - base[cl]; int co = rr/K[cl], k = rr - co*K[cl], t = k>>6, ci = k&63;
    val = d1w[(ci*32+co)*9 + T1[cl][t]];
  } else {                            // deconv2 classes [4][16][32]
    int r = i - OD2;
    int cl = r>>9, s = r&511, co = s>>5, ci = s&31;
    const int pis[4]={0,0,1,1}, pjs[4]={0,1,0,1};
    val = d2w[((ci*16+co)*2 + (1-pis[cl]))*2 + (1-pjs[cl])];
  }
  WPK[i] = f2bf(val);
}

// ---------------- memory rows -> bf16 + row norms ----------------
__global__ __launch_bounds__(256) void k_memrows(const float* __restrict__ mem, float* __restrict__ hdr,
                                                 ushort_t* __restrict__ mbf){
  __shared__ float red[4];
  const int m = blockIdx.x, tid = threadIdx.x;
  float part = 0.f;
  for (int i=tid;i<2304;i+=256){
    float v = mem[(size_t)m*2304+i];
    mbf[(size_t)m*2304+i] = f2bf(v);
    part += v*v;
  }
  for (int o=32;o;o>>=1) part += __shfl_down(part,o,64);
  if ((tid&63)==0) red[tid>>6] = part;
  __syncthreads();
  if (tid==0) hdr[H_MN+m] = sqrtf(red[0]+red[1]+red[2]+red[3]);
}

__global__ __launch_bounds__(256) void k_memT(const float* __restrict__ mem, ushort_t* __restrict__ mt){
  __shared__ ushort_t tile[32][33];
  const int ft = blockIdx.x % 72, mtile = blockIdx.x / 72;
  const int tx = threadIdx.x & 31, ty = threadIdx.x >> 5;
  #pragma unroll
  for (int r0=0;r0<4;r0++){
    int m = mtile*32 + r0*8 + ty;
    int f = ft*32 + tx;
    float v = (m < 2000) ? mem[(size_t)m*2304 + f] : 0.f;
    tile[r0*8+ty][tx] = f2bf(v);
  }
  __syncthreads();
  #pragma unroll
  for (int r0=0;r0<4;r0++){
    int f = ft*32 + r0*8 + ty;
    mt[(size_t)f*2016 + mtile*32 + tx] = tile[tx][r0*8+ty];
  }
}

// ---------------- conv2 (MFMA): 16->32, 3x3 s2 p1 on folded conv1 output ----------------
__global__ __launch_bounds__(256) void k_conv2m(
    const float* __restrict__ x, const ushort_t* __restrict__ WPK, const float* __restrict__ b2g,
    const float* __restrict__ c1w, const float* __restrict__ c1b,
    const float* __restrict__ bn1g, const float* __restrict__ bn1b,
    float* __restrict__ hdr, float* __restrict__ out){
  __shared__ ushort_t inp[27*51*16];    // [row][col][ci16], halo'd 51-grid rows [2*ro..2*ro+26]
  __shared__ float ac[32];
  const int blk = blockIdx.x, b = blk>>1, h = blk&1, tid = threadIdx.x;
  const int ro = h*13, nr = h?12:13, npos = nr*25, ntiles = (npos+15)>>4;
  if (tid < 16){
    float sx=0.f, qx=0.f;
    #pragma unroll
    for (int k=0;k<NBUK;k++){ sx += hdr[H_BUK+k*BSTRIDE+H_XS]; qx += hdr[H_BUK+k*BSTRIDE+H_XS+1]; }
    const float N = 512.f*49.f*49.f;
    float mx = sx/N, vx = qx/N - mx*mx;
    float mean = c1w[tid]*mx + c1b[tid];
    float a = bn1g[tid]*rsqrtf(c1w[tid]*c1w[tid]*vx + 1e-5f);
    ac[tid] = a*c1w[tid];
    ac[16+tid] = a*(c1b[tid]-mean) + bn1b[tid];
  }
  __syncthreads();
  for (int e = tid; e < 27*51; e += 256){
    int lr = e/51, gc = e - lr*51;
    int grg = 2*ro + lr;
    bool inside = (grg>=1 && grg<=49 && gc>=1 && gc<=49);
    float v = 0.f;
    if (grg>=2 && grg<=49 && gc>=2 && gc<=49) v = x[(size_t)b*9216 + (2*grg-3)*96 + (2*gc-3)];
    ushort_t hv[16];
    if (inside){
      #pragma unroll
      for (int c=0;c<16;c++) hv[c] = f2bf(fmaxf(fmaf(ac[c], v, ac[16+c]), 0.f));
    } else {
      #pragma unroll
      for (int c=0;c<16;c++) hv[c] = 0;
    }
    uint32_t w0[8];
    #pragma unroll
    for (int c=0;c<8;c++) w0[c] = (uint32_t)hv[2*c] | ((uint32_t)hv[2*c+1]<<16);
    uint4* dst = (uint4*)&inp[e*16];
    dst[0] = make_uint4(w0[0],w0[1],w0[2],w0[3]);
    dst[1] = make_uint4(w0[4],w0[5],w0[6],w0[7]);
  }
  __syncthreads();
  const int wv = tid>>6, lane = tid&63, r = lane&15, q = lane>>4;
  const int cotile = wv&1;
  bf16x8 af[5];
  #pragma unroll
  for (int c=0;c<5;c++) af[c] = *(const bf16x8*)(WPK + OW2 + (cotile*16+r)*160 + c*32 + q*8);
  float biasr[4];
  #pragma unroll
  for (int v=0;v<4;v++) biasr[v] = b2g[cotile*16 + q*4 + v];
  const int TOFF[10] = {0,1,2,51,52,53,102,103,104,0};
  const int qhi = q>>1, ci0 = (q&1)*8;
  float sacc[4]={0,0,0,0}, qacc[4]={0,0,0,0};
  for (int t = wv>>1; t < ntiles; t += 2){
    int p = t*16 + r;
    bool ok = p < npos;
    int pc = ok ? p : 0;
    int a_ = pc/25, c_ = pc - a_*25;
    int pb = (2*a_)*51 + 2*c_;
    f32x4 acc = {0.f,0.f,0.f,0.f};
    #pragma unroll
    for (int c=0;c<5;c++){
      int toff = qhi ? TOFF[2*c+1] : TOFF[2*c];
      bf16x8 bv = *(const bf16x8*)&inp[(pb + toff)*16 + ci0];
      acc = __builtin_amdgcn_mfma_f32_16x16x32_bf16(af[c], bv, acc, 0, 0, 0);
    }
    if (ok){
      int pg = (ro + a_)*25 + c_;
      #pragma unroll
      for (int reg=0;reg<4;reg++){
        float y = acc[reg] + biasr[reg];
        out[((size_t)b*32 + cotile*16 + q*4 + reg)*625 + pg] = y;
        sacc[reg] += y; qacc[reg] += y*y;
      }
    }
  }
  float* bk = bkt(hdr, blk);
  #pragma unroll
  for (int reg=0;reg<4;reg++){
    float s = sacc[reg], qq = qacc[reg];
    for (int o=8;o;o>>=1){ s += __shfl_down(s,o,16); qq += __shfl_down(qq,o,16); }
    if (r==0){ atomicAdd(&bk[H_S2+cotile*16+q*4+reg], s); atomicAdd(&bk[H_Q2+cotile*16+q*4+reg], qq); }
  }
}

// ---------------- conv3 (MFMA): 32->64, 3x3 s2 p1, 25->13 ----------------
__global__ __launch_bounds__(256) void k_conv3m(
    const float* __restrict__ h2, const ushort_t* __restrict__ WPK, const float* __restrict__ b3g,
    const float* __restrict__ g, const float* __restrict__ be,
    float* __restrict__ hdr, float* __restrict__ out){
  __shared__ ushort_t inp[27*27*32];   // [cell][ci32], halo'd 27-grid
  __shared__ float ac[64];
  const int b = blockIdx.x, tid = threadIdx.x;
  coef_lds(hdr, H_S2, H_Q2, g, be, ac, 32, 1.f/(512.f*625.f), tid);
  __syncthreads();
  for (int e = tid; e < 27*27*32; e += 256){
    int ci = e & 31, cell = e >> 5;
    int gr = cell/27, gc = cell - gr*27;
    int i = gr-1, j = gc-1;
    float v = 0.f;
    if ((unsigned)i < 25u && (unsigned)j < 25u){
      float raw = h2[((size_t)b*32 + ci)*625 + i*25 + j];
      v = fmaxf(fmaf(ac[ci], raw, ac[32+ci]), 0.f);
    }
    inp[e] = f2bf(v);
  }
  __syncthreads();
  const int wv = tid>>6, lane = tid&63, r = lane&15, q = lane>>4;
  bf16x8 af[9];
  #pragma unroll
  for (int c=0;c<9;c++) af[c] = *(const bf16x8*)(WPK + OW3 + (wv*16+r)*288 + c*32 + q*8);
  float biasr[4];
  #pragma unroll
  for (int v=0;v<4;v++) biasr[v] = b3g[wv*16 + q*4 + v];
  const int TOFF[9] = {0,1,2,27,28,29,54,55,56};
  const int ci0 = q*8;
  float sacc[4]={0,0,0,0}, qacc[4]={0,0,0,0};
  for (int t = 0; t < 11; t++){
    int p = t*16 + r;
    bool ok = p < 169;
    int pc = ok ? p : 0;
    int a_ = pc/13, c_ = pc - a_*13;
    int pb = (2*a_)*27 + 2*c_;
    f32x4 acc = {0.f,0.f,0.f,0.f};
    #pragma unroll
    for (int c=0;c<9;c++){
      bf16x8 bv = *(const bf16x8*)&inp[(pb + TOFF[c])*32 + ci0];
      acc = __builtin_amdgcn_mfma_f32_16x16x32_bf16(af[c], bv, acc, 0, 0, 0);
    }
    if (ok){
      #pragma unroll
      for (int reg=0;reg<4;reg++){
        float y = acc[reg] + biasr[reg];
        out[((size_t)b*64 + wv*16 + q*4 + reg)*169 + p] = y;
        sacc[reg] += y; qacc[reg] += y*y;
      }
    }
  }
  float* bk = bkt(hdr, b);
  #pragma unroll
  for (int reg=0;reg<4;reg++){
    float s = sacc[reg], qq = qacc[reg];
    for (int o=8;o;o>>=1){ s += __shfl_down(s,o,16); qq += __shfl_down(qq,o,16); }
    if (r==0){ atomicAdd(&bk[H_S3+wv*16+q*4+reg], s); atomicAdd(&bk[H_Q3+wv*16+q*4+reg], qq); }
  }
}

// ---------------- conv4 (MFMA): 64->64, 3x3 s2 p0, 13->6 ----------------
__global__ __launch_bounds__(256) void k_conv4m(
    const float* __restrict__ h3, const ushort_t* __restrict__ WPK, const float* __restrict__ b4g,
    const float* __restrict__ g, const float* __restrict__ be,
    float* __restrict__ hdr, float* __restrict__ out){
  __shared__ ushort_t inp[169*64];     // [cell][ci64]
  __shared__ float ac[128];
  const int b = blockIdx.x, tid = threadIdx.x;
  coef_lds(hdr, H_S3, H_Q3, g, be, ac, 64, 1.f/(512.f*169.f), tid);
  __syncthreads();
  for (int e = tid; e < 169*64; e += 256){
    int ci = e & 63, cell = e >> 6;
    float raw = h3[((size_t)b*64 + ci)*169 + cell];
    inp[e] = f2bf(fmaxf(fmaf(ac[ci], raw, ac[64+ci]), 0.f));
  }
  __syncthreads();
  const int wv = tid>>6, lane = tid&63, r = lane&15, q = lane>>4;
  bf16x8 af[18];
  #pragma unroll
  for (int c=0;c<18;c++) af[c] = *(const bf16x8*)(WPK + OW4 + (wv*16+r)*576 + c*32 + q*8);
  float biasr[4];
  #pragma unroll
  for (int v=0;v<4;v++) biasr[v] = b4g[wv*16 + q*4 + v];
  const int TOFF[9] = {0,1,2,13,14,15,26,27,28};
  float sacc[4]={0,0,0,0}, qacc[4]={0,0,0,0};
  for (int t = 0; t < 3; t++){
    int p = t*16 + r;
    bool ok = p < 36;
    int pc = ok ? p : 0;
    int a_ = pc/6, c_ = pc - a_*6;
    int pb = (2*a_)*13 + 2*c_;
    f32x4 acc = {0.f,0.f,0.f,0.f};
    #pragma unroll
    for (int c=0;c<18;c++){
      int ci0 = (c&1)*32 + q*8;
      bf16x8 bv = *(const bf16x8*)&inp[(pb + TOFF[c>>1])*64 + ci0];
      acc = __builtin_amdgcn_mfma_f32_16x16x32_bf16(af[c], bv, acc, 0, 0, 0);
    }
    if (ok){
      #pragma unroll
      for (int reg=0;reg<4;reg++){
        float y = acc[reg] + biasr[reg];
        out[((size_t)b*64 + wv*16 + q*4 + reg)*36 + p] = y;
        sacc[reg] += y; qacc[reg] += y*y;
      }
    }
  }
  float* bk = bkt(hdr, b);
  #pragma unroll
  for (int reg=0;reg<4;reg++){
    float s = sacc[reg], qq = qacc[reg];
    for (int o=8;o;o>>=1){ s += __shfl_down(s,o,16); qq += __shfl_down(qq,o,16); }
    if (r==0){ atomicAdd(&bk[H_S4+wv*16+q*4+reg], s); atomicAdd(&bk[H_Q4+wv*16+q*4+reg], qq); }
  }
}

// z = relu(bn4(conv4 raw)) -> bf16, plus per-row norm (computes A4/C4 itself)
__global__ __launch_bounds__(256) void k_z(const float* __restrict__ zraw, float* __restrict__ hdr,
                                           ushort_t* __restrict__ zbf,
                                           const float* __restrict__ g, const float* __restrict__ be){
  __shared__ float ac[128];
  __shared__ float red[4];
  const int b = blockIdx.x, tid = threadIdx.x;
  coef_lds(hdr, H_S4, H_Q4, g, be, ac, 64, 1.f/(512.f*36.f), tid);
  __syncthreads();
  float part = 0.f;
  for (int i=tid;i<2304;i+=256){
    int c = i/36;
    float h = fmaxf(fmaf(ac[c], zraw[(size_t)b*2304+i], ac[64+c]), 0.f);
    zbf[(size_t)b*2304+i] = f2bf(h);
    part += h*h;
  }
  for (int o=32;o;o>>=1) part += __shfl_down(part,o,64);
  if ((tid&63)==0) red[tid>>6] = part;
  __syncthreads();
  if (tid==0) hdr[H_ZN+b] = sqrtf(red[0]+red[1]+red[2]+red[3]);
}

// ---------------- blocked GEMM, split-K: D_s[M][N] = A[M][ks] * B[N][ks]^T
__global__ __launch_bounds__(256) void k_gemmB(const ushort_t* __restrict__ A, const ushort_t* __restrict__ Bm,
                                               float* __restrict__ D, int Nb, int N, int Kp, int kch,
                                               int tiles, int ksp, size_t dstride){
  __shared__ __align__(16) ushort_t lB[128*40];
  const int blk = blockIdx.x;
  const int s = blk / tiles, t = blk - s*tiles;
  const int bi = t / Nb, bj = t - bi*Nb;
  const int m0 = bi*128, n0 = bj*128;
  const int k0 = s*ksp, k1 = min(kch, k0 + ksp);
  const int tid = threadIdx.x;
  const int lane = tid & 63, wv = tid >> 6;
  const int r = lane & 15, q = lane >> 4;
  const int wr = wv >> 1, wc = wv & 1;
  float* Ds = D + (size_t)s*dstride;
  const int srow = tid >> 1, skq = (tid & 1) * 16;
  const bool bok = (n0 + srow) < N;
  const ushort_t* pb = Bm + (size_t)(n0 + srow)*Kp + skq;
  uint4* wB = (uint4*)&lB[srow*40 + skq];
  const uint4 zz = make_uint4(0,0,0,0);
  uint4 rb0 = bok ? *(const uint4*)(pb + k0*32)     : zz;
  uint4 rb1 = bok ? *(const uint4*)(pb + k0*32 + 8) : zz;
  const ushort_t* pa = A + (size_t)(m0 + wr*64 + r)*Kp + q*8;
  bf16x8 aN[4];
  #pragma unroll
  for (int mt=0;mt<4;mt++) aN[mt] = *(const bf16x8*)(pa + k0*32 + (size_t)(mt*16)*Kp);
  f32x4 acc[4][4];
  #pragma unroll
  for (int i=0;i<4;i++)
    #pragma unroll
    for (int j=0;j<4;j++) acc[i][j] = (f32x4){0.f,0.f,0.f,0.f};
  for (int k=k0; k<k1; k++){
    if (k > k0) __syncthreads();
    wB[0] = rb0; wB[1] = rb1;
    bf16x8 aF[4];
    #pragma unroll
    for (int mt=0;mt<4;mt++) aF[mt] = aN[mt];
    if (k+1 < k1){
      const ushort_t* nb = pb + (k+1)*32;
      rb0 = bok ? *(const uint4*)(nb)     : zz;
      rb1 = bok ? *(const uint4*)(nb + 8) : zz;
      const ushort_t* na = pa + (k+1)*32;
      #pragma unroll
      for (int mt=0;mt<4;mt++) aN[mt] = *(const bf16x8*)(na + (size_t)(mt*16)*Kp);
    }
    __syncthreads();
    bf16x8 bF[4];
    #pragma unroll
    for (int nt=0;nt<4;nt++) bF[nt] = *(const bf16x8*)&lB[(wc*64+nt*16+r)*40 + q*8];
    #pragma unroll
    for (int mt=0;mt<4;mt++)
      #pragma unroll
      for (int nt=0;nt<4;nt++)
        acc[mt][nt] = __builtin_amdgcn_mfma_f32_16x16x32_bf16(aF[mt], bF[nt], acc[mt][nt], 0, 0, 0);
  }
  #pragma unroll
  for (int mt=0;mt<4;mt++){
    int row = m0 + wr*64 + mt*16 + q*4;
    #pragma unroll
    for (int nt=0;nt<4;nt++){
      int col = n0 + wc*64 + nt*16 + r;
      if (col < N){
        #pragma unroll
        for (int reg=0;reg<4;reg++)
          Ds[(size_t)(row+reg)*N + col] = acc[mt][nt][reg];
      }
    }
  }
}

// softmax over M=2000 (sums 4 split-K partials) + hard-shrink + L1 renorm -> bf16
__global__ __launch_bounds__(256) void k_softmax(const float* __restrict__ sim, float* __restrict__ hdr,
                                                 ushort_t* __restrict__ wbf){
  __shared__ float e[2000];
  __shared__ float red[8];
  const int b = blockIdx.x, tid = threadIdx.x;
  const float znb = hdr[H_ZN+b];
  float part = 0.f;
  for (int m=tid;m<2000;m+=256){
    size_t ix = (size_t)b*2000+m;
    float sv = sim[ix] + sim[ix+SIMSTRIDE] + sim[ix+2*SIMSTRIDE] + sim[ix+3*SIMSTRIDE];
    float s = sv / fmaxf(znb * hdr[H_MN+m], 1e-8f);
    float ev = __expf(s);
    e[m] = ev; part += ev;
  }
  for (int o=32;o;o>>=1) part += __shfl_down(part,o,64);
  if ((tid&63)==0) red[tid>>6] = part;
  __syncthreads();
  const float denom = red[0]+red[1]+red[2]+red[3];
  const float t = 1.0f/2000.0f;
  float part2 = 0.f;
  for (int m=tid;m<2000;m+=256){
    float w = e[m]/denom;
    float d = w - t;
    float sh = fmaxf(d,0.f)*w/(fabsf(d)+0.01f);
    e[m] = sh; part2 += sh;
  }
  for (int o=32;o;o>>=1) part2 += __shfl_down(part2,o,64);
  if ((tid&63)==0) red[4+(tid>>6)] = part2;
  __syncthreads();
  const float inv = 1.0f/(red[4]+red[5]+red[6]+red[7]);
  for (int m=tid;m<2016;m+=256){
    ushort_t o = 0;
    if (m < 2000) o = f2bf(e[m]*inv);
    wbf[(size_t)b*2016+m] = o;
  }
}

// ---------------- deconv0 (MFMA): 64->64, k3 s2 p0, 6->13 (sums 4 zh partials) ----------------
__global__ __launch_bounds__(256) void k_deconv0m(
    const float* __restrict__ zh, const ushort_t* __restrict__ WPK, const float* __restrict__ b0g,
    float* __restrict__ hdr, float* __restrict__ out){
  __shared__ ushort_t inp[64*64];      // [cell 8x8 halo][ci64]
  const int b = blockIdx.x, tid = threadIdx.x;
  for (int e = tid; e < 64*64; e += 256){
    int ci = e & 63, cell = e >> 6;
    int r8 = cell>>3, c8 = cell&7;
    float v = 0.f;
    if (r8>=1 && r8<=6 && c8>=1 && c8<=6){
      size_t ix = (size_t)b*2304 + ci*36 + (r8-1)*6 + (c8-1);
      v = zh[ix] + zh[ix+ZHSTRIDE] + zh[ix+2*ZHSTRIDE] + zh[ix+3*ZHSTRIDE];
    }
    inp[e] = f2bf(v);
  }
  __syncthreads();
  const int wv = tid>>6, lane = tid&63, r = lane&15, q = lane>>4;
  float biasr[4];
  #pragma unroll
  for (int v=0;v<4;v++) biasr[v] = b0g[wv*16 + q*4 + v];
  const int NCOL[4]={7,6,7,6}, NPOS[4]={49,42,42,36}, NT[4]={4,3,3,3},
            NCH[4]={8,4,4,2}, KB[4]={0,16384,24576,32768}, KK[4]={256,128,128,64},
            PI[4]={0,0,1,1}, PJ[4]={0,1,0,1};
  const int TOFF[4][4] = {{9,8,1,0},{9,1,0,0},{9,8,0,0},{9,0,0,0}};
  float sacc[4]={0,0,0,0}, qacc[4]={0,0,0,0};
  #pragma unroll
  for (int cl=0; cl<4; cl++){
    bf16x8 af[8];
    #pragma unroll
    for (int m=0;m<NCH[cl];m++)
      af[m] = *(const bf16x8*)(WPK + OD0 + KB[cl] + (wv*16+r)*KK[cl] + m*32 + q*8);
    for (int t = 0; t < NT[cl]; t++){
      int p = t*16 + r;
      bool ok = p < NPOS[cl];
      int pc = ok ? p : 0;
      int a_ = pc/NCOL[cl], c_ = pc - a_*NCOL[cl];
      int pb = a_*8 + c_;
      f32x4 acc = {0.f,0.f,0.f,0.f};
      #pragma unroll
      for (int m=0;m<NCH[cl];m++){
        int ci0 = (m&1)*32 + q*8;
        bf16x8 bv = *(const bf16x8*)&inp[(pb + TOFF[cl][m>>1])*64 + ci0];
        acc = __builtin_amdgcn_mfma_f32_16x16x32_bf16(af[m], bv, acc, 0, 0, 0);
      }
      if (ok){
        int pos = (2*a_+PI[cl])*13 + (2*c_+PJ[cl]);
        #pragma unroll
        for (int reg=0;reg<4;reg++){
          float y = acc[reg] + biasr[reg];
          out[((size_t)b*64 + wv*16 + q*4 + reg)*169 + pos] = y;
          sacc[reg] += y; qacc[reg] += y*y;
        }
      }
    }
  }
  float* bk = bkt(hdr, b);
  #pragma unroll
  for (int reg=0;reg<4;reg++){
    float s = sacc[reg], qq = qacc[reg];
    for (int o=8;o;o>>=1){ s += __shfl_down(s,o,16); qq += __shfl_down(qq,o,16); }
    if (r==0){ atomicAdd(&bk[H_DS0+wv*16+q*4+reg], s); atomicAdd(&bk[H_DQ0+wv*16+q*4+reg], qq); }
  }
}

// ---------------- deconv1 (MFMA): 64->32, k3 s2 p1, 13->25 ----------------
__global__ __launch_bounds__(256) void k_deconv1m(
    const float* __restrict__ g0, const ushort_t* __restrict__ WPK, const float* __restrict__ b1g,
    const float* __restrict__ g, const float* __restrict__ be,
    float* __restrict__ hdr, float* __restrict__ out){
  __shared__ ushort_t inp[169*64];     // [cell 13x13][ci64]
  __shared__ float ac[128];
  const int b = blockIdx.x, tid = threadIdx.x;
  coef_lds(hdr, H_DS0, H_DQ0, g, be, ac, 64, 1.f/(512.f*169.f), tid);
  __syncthreads();
  for (int e = tid; e < 169*64; e += 256){
    int ci = e & 63, cell = e >> 6;
    float raw = g0[((size_t)b*64 + ci)*169 + cell];
    inp[e] = f2bf(fmaxf(fmaf(ac[ci], raw, ac[64+ci]), 0.f));
  }
  __syncthreads();
  const int wv = tid>>6, lane = tid&63, r = lane&15, q = lane>>4;
  const int cotile = wv&1, ph = wv>>1;
  float biasr[4];
  #pragma unroll
  for (int v=0;v<4;v++) biasr[v] = b1g[cotile*16 + q*4 + v];
  const int NCOL[4]={13,12,13,12}, NPOS[4]={169,156,156,144}, NT[4]={11,10,10,9},
            NCH[4]={2,4,4,8}, KB[4]={0,2048,6144,10240}, KK[4]={64,128,128,256},
            PI[4]={0,0,1,1}, PJ[4]={0,1,0,1};
  const int TOFF[4][4] = {{0,0,0,0},{1,0,0,0},{13,0,0,0},{14,13,1,0}};
  float sacc[4]={0,0,0,0}, qacc[4]={0,0,0,0};
  #pragma unroll
  for (int cl=0; cl<4; cl++){
    bf16x8 af[8];
    #pragma unroll
    for (int m=0;m<NCH[cl];m++)
      af[m] = *(const bf16x8*)(WPK + OD1 + KB[cl] + (cotile*16+r)*KK[cl] + m*32 + q*8);
    for (int t = ph; t < NT[cl]; t += 2){
      int p = t*16 + r;
      bool ok = p < NPOS[cl];
      int pc = ok ? p : 0;
      int a_ = pc/NCOL[cl], c_ = pc - a_*NCOL[cl];
      int pb = a_*13 + c_;
      f32x4 acc = {0.f,0.f,0.f,0.f};
      #pragma unroll
      for (int m=0;m<NCH[cl];m++){
        int ci0 = (m&1)*32 + q*8;
        bf16x8 bv = *(const bf16x8*)&inp[(pb + TOFF[cl][m>>1])*64 + ci0];
        acc = __builtin_amdgcn_mfma_f32_16x16x32_bf16(af[m], bv, acc, 0, 0, 0);
      }
      if (ok){
        int pos = (2*a_+PI[cl])*25 + (2*c_+PJ[cl]);
        #pragma unroll
        for (int reg=0;reg<4;reg++){
          float y = acc[reg] + biasr[reg];
          out[((size_t)b*32 + cotile*16 + q*4 + reg)*625 + pos] = y;
          sacc[reg] += y; qacc[reg] += y*y;
        }
      }
    }
  }
  float* bk = bkt(hdr, b);
  #pragma unroll
  for (int reg=0;reg<4;reg++){
    float s = sacc[reg], qq = qacc[reg];
    for (int o=8;o;o>>=1){ s += __shfl_down(s,o,16); qq += __shfl_down(qq,o,16); }
    if (r==0){ atomicAdd(&bk[H_DS1+cotile*16+q*4+reg], s); atomicAdd(&bk[H_DQ1+cotile*16+q*4+reg], qq); }
  }
}

// ---------------- deconv2 (MFMA): 32->16, k2 s2 p1 op1, 25->49 ----------------
// Output: bf16 parity-plane layout G2BF[b][co][cl][625] (cl=(oi&1)*2+(oj&1))
__global__ __launch_bounds__(256) void k_deconv2m(
    const float* __restrict__ g1, const ushort_t* __restrict__ WPK, const float* __restrict__ bg,
    const float* __restrict__ g, const float* __restrict__ be,
    float* __restrict__ hdr, ushort_t* __restrict__ out){
  __shared__ ushort_t inp[625*32];     // [cell 25x25][ci32]
  __shared__ float ac[64];
  const int b = blockIdx.x, tid = threadIdx.x;
  coef_lds(hdr, H_DS1, H_DQ1, g, be, ac, 32, 1.f/(512.f*625.f), tid);
  __syncthreads();
  for (int e = tid; e < 625*32; e += 256){
    int ci = e & 31, cell = e >> 5;
    float raw = g1[((size_t)b*32 + ci)*625 + cell];
    inp[e] = f2bf(fmaxf(fmaf(ac[ci], raw, ac[32+ci]), 0.f));
  }
  __syncthreads();
  const int wv = tid>>6, lane = tid&63, r = lane&15, q = lane>>4;
  const int cl = wv;   // one parity class per wave
  float biasr[4];
  #pragma unroll
  for (int v=0;v<4;v++) biasr[v] = bg[q*4 + v];
  const int NCOL[4]={25,24,25,24}, NPOS[4]={625,600,600,576}, NT[4]={40,38,38,36},
            TOFF[4]={0,1,25,26};
  const int ci0 = q*8;
  const int nc = NCOL[cl], npos = NPOS[cl], nt = NT[cl], toff = TOFF[cl];
  bf16x8 af = *(const bf16x8*)(WPK + OD2 + cl*512 + r*32 + q*8);
  float sacc[4]={0,0,0,0}, qacc[4]={0,0,0,0};
  for (int t = 0; t < nt; t++){
    int p = t*16 + r;
    bool ok = p < npos;
    int pc = ok ? p : 0;
    int a_ = pc/nc, c_ = pc - a_*nc;
    int pb = a_*25 + c_;
    f32x4 acc = {0.f,0.f,0.f,0.f};
    bf16x8 bv = *(const bf16x8*)&inp[(pb + toff)*32 + ci0];
    acc = __builtin_amdgcn_mfma_f32_16x16x32_bf16(af, bv, acc, 0, 0, 0);
    if (ok){
      #pragma unroll
      for (int reg=0;reg<4;reg++){
        float y = acc[reg] + biasr[reg];
        out[((size_t)(b*16 + q*4 + reg)*4 + cl)*625 + p] = f2bf(y);
        sacc[reg] += y; qacc[reg] += y*y;
      }
    }
  }
  float* bk = bkt(hdr, b);
  #pragma unroll
  for (int reg=0;reg<4;reg++){
    float s = sacc[reg], qq = qacc[reg];
    for (int o=8;o;o>>=1){ s += __shfl_down(s,o,16); qq += __shfl_down(qq,o,16); }
    if (r==0){ atomicAdd(&bk[H_DS2+q*4+reg], s); atomicAdd(&bk[H_DQ2+q*4+reg], qq); }
  }
}

// ---------------- deconv3: 16->1, k2 s2 p0, 49->98, + sigmoid (plane-layout input) ----------------
__global__ __launch_bounds__(256) void k_deconv3(const ushort_t* __restrict__ g2, const float* __restrict__ w,
                                                 const float* __restrict__ bias,
                                                 const float* __restrict__ g, const float* __restrict__ be,
                                                 float* __restrict__ hdr, float* __restrict__ out){
  __shared__ float ac[32];
  const int tid = threadIdx.x;
  coef_lds(hdr, H_DS2, H_DQ2, g, be, ac, 16, 1.f/(512.f*2401.f), tid);
  __syncthreads();
  int idx = blockIdx.x*256 + tid;
  if (idx >= 512*9604) return;
  int b = idx / 9604; int rr = idx - b*9604;
  int oi = rr / 98, oj = rr - oi*98;
  int ki = oi & 1, kj = oj & 1, ii = oi >> 1, jj = oj >> 1;
  int pi = ii & 1, pj = jj & 1, cl = pi*2 + pj;
  int a = ii >> 1, c = jj >> 1;
  int nc = pj ? 24 : 25;
  float acc = bias[0];
  const ushort_t* gp = g2 + ((size_t)(b*16)*4 + cl)*625 + a*nc + c;
  #pragma unroll
  for (int ci=0; ci<16; ci++){
    float raw = bf2f(gp[(size_t)ci*4*625]);
    float h = fmaxf(fmaf(ac[ci], raw, ac[16+ci]), 0.f);
    acc = fmaf(h, w[ci*4 + ki*2 + kj], acc);
  }
  out[idx] = 1.f/(1.f + __expf(-acc));
}

// ======================================================================
extern "C" void kernel_launch(void* const* d_in, const int* in_sizes, int n_in,
                              void* d_out, int out_size, void* d_ws, size_t ws_size,
                              hipStream_t stream){
  (void)in_sizes; (void)n_in; (void)out_size; (void)ws_size;
  const float* x     = (const float*)d_in[0];
  const float* c1w   = (const float*)d_in[1];
  const float* c1b   = (const float*)d_in[2];
  const float* bn1g  = (const float*)d_in[3];
  const float* bn1b  = (const float*)d_in[4];
  const float* c2w   = (const float*)d_in[5];
  const float* c2b   = (const float*)d_in[6];
  const float* bn2g  = (const float*)d_in[7];
  const float* bn2b  = (const float*)d_in[8];
  const float* c3w   = (const float*)d_in[9];
  const float* c3b   = (const float*)d_in[10];
  const float* bn3g  = (const float*)d_in[11];
  const float* bn3b  = (const float*)d_in[12];
  const float* c4w   = (const float*)d_in[13];
  const float* c4b   = (const float*)d_in[14];
  const float* bn4g  = (const float*)d_in[15];
  const float* bn4b  = (const float*)d_in[16];
  const float* mem   = (const float*)d_in[17];
  const float* d0w   = (const float*)d_in[18];
  const float* d0b   = (const float*)d_in[19];
  const float* dbn0g = (const float*)d_in[20];
  const float* dbn0b = (const float*)d_in[21];
  const float* d1w   = (const float*)d_in[22];
  const float* d1b   = (const float*)d_in[23];
  const float* dbn1g = (const float*)d_in[24];
  const float* dbn1b = (const float*)d_in[25];
  const float* d2w   = (const float*)d_in[26];
  const float* d2b   = (const float*)d_in[27];
  const float* dbn2g = (const float*)d_in[28];
  const float* dbn2b = (const float*)d_in[29];
  const float* d3w   = (const float*)d_in[30];
  const float* d3b   = (const float*)d_in[31];

  float* hdr  = (float*)d_ws;
  float* H2   = hdr + HDR_FLOATS;        // 512*32*625 (reused as G1)
  float* H3   = H2 + 10240000;           // 512*64*169 (reused as G0)
  float* ZRAW = H3 + 5537792;            // 512*2304
  float* WSLOT= ZRAW + 1179648;          // 73728 floats (holds WPK bf16)
  float* G2   = WSLOT + 73728;           // 19.67M floats scratch region
  ushort_t* MEMBF = (ushort_t*)(G2 + 19668992); // 2000*2304
  ushort_t* MEMT  = MEMBF + 4608000;            // 2304*2016
  ushort_t* ZBF   = MEMT + 4644864;             // 512*2304
  ushort_t* WBF   = ZBF + 1179648;              // 512*2016
  ushort_t* WPK   = (ushort_t*)WSLOT;
  // split-K partials overlaid on G2 region (dead before deconv2m writes G2BF):
  float* SIMP = G2;                      // 4 * 512*2000
  float* ZHP  = G2 + 4*SIMSTRIDE;        // 4 * 512*2304
  ushort_t* G2BF = (ushort_t*)G2;        // 512*16*4*625 bf16 = 20.48M ushort (10.24M floats)
  float* G0 = H3;
  float* G1 = H2;
  float* OUT = (float*)d_out;

  hipMemsetAsync(hdr, 0, HDR_FLOATS*sizeof(float), stream);
  k_xstats   <<<1024, 256, 0, stream>>>(x, hdr);
  k_wprep2   <<<460, 256, 0, stream>>>(c2w, c3w, c4w, d0w, d1w, d2w, WPK);
  k_memrows  <<<2000, 256, 0, stream>>>(mem, hdr, MEMBF);
  k_memT     <<<72*63, 256, 0, stream>>>(mem, MEMT);
  k_conv2m   <<<1024, 256, 0, stream>>>(x, WPK, c2b, c1w, c1b, bn1g, bn1b, hdr, H2);
  k_conv3m   <<<512, 256, 0, stream>>>(H2, WPK, c3b, bn2g, bn2b, hdr, H3);
  k_conv4m   <<<512, 256, 0, stream>>>(H3, WPK, c4b, bn3g, bn3b, hdr, ZRAW);
  k_z        <<<512, 256, 0, stream>>>(ZRAW, hdr, ZBF, bn4g, bn4b);
  k_gemmB    <<<256, 256, 0, stream>>>(ZBF, MEMBF, SIMP, 16, 2000, 2304, 72, 64, 18, SIMSTRIDE);
  k_softmax  <<<512, 256, 0, stream>>>(SIMP, hdr, WBF);
  k_gemmB    <<<288, 256, 0, stream>>>(WBF, MEMT, ZHP, 18, 2304, 2016, 63, 72, 16, ZHSTRIDE);
  k_deconv0m <<<512, 256, 0, stream>>>(ZHP, WPK, d0b, hdr, G0);
  k_deconv1m <<<512, 256, 0, stream>>>(G0, WPK, d1b, dbn0g, dbn0b, hdr, G1);
  k_deconv2m <<<512, 256, 0, stream>>>(G1, WPK, d2b, dbn1g, dbn1b, hdr, G2BF);
  k_deconv3  <<<19208, 256, 0, stream>>>(G2BF, d3w, d3b, dbn2g, dbn2b, hdr, OUT);
}

// Round 8
// 410.212 us; speedup vs baseline: 3.2415x; 1.0906x over previous
//
#include <hip/hip_runtime.h>
#include <stdint.h>

// R8: R7 + k_deconv3 restructured input-location-per-thread: each thread
// reads 16 ci values once (sequential plane runs, no 4x re-read) and emits
// all 4 output pixels of its (ii,jj) location. FETCH 103MB -> ~41MB.

typedef unsigned short ushort_t;
typedef __bf16 bf16x8 __attribute__((ext_vector_type(8)));
typedef float f32x4 __attribute__((ext_vector_type(4)));

#define DEV static __device__ __forceinline__

DEV ushort_t f2bf(float f){
  union { float f; uint32_t u; } v; v.f = f;
  return (ushort_t)((v.u + 0x7FFFu + ((v.u >> 16) & 1u)) >> 16);
}
DEV float bf2f(ushort_t u){
  union { uint32_t u; float f; } v; v.u = ((uint32_t)u) << 16;
  return v.f;
}

// ---------------- header (stats/coeff) offsets in floats ----------------
#define H_XS   0
#define H_S2   64
#define H_Q2   96
#define H_S3   192
#define H_Q3   256
#define H_S4   448
#define H_Q4   512
#define H_DS0  704
#define H_DQ0  768
#define H_DS1  960
#define H_DQ1  992
#define H_DS2  1088
#define H_DQ2  1104
#define H_ZN   1152   // [512]
#define H_MN   1664   // [2000]
#define H_BUK  4096   // 16 bucket banks of 1280 floats each
#define NBUK   16
#define BSTRIDE 1280
#define HDR_FLOATS (H_BUK + NBUK*BSTRIDE)

// packed-weight (bf16) offsets in WPK
#define OW2 0        // [32][160]  k=tap*16+ci, taps 0..9 (tap9 = zero pad)
#define OW3 5120     // [64][288]  k=tap*32+ci
#define OW4 23552    // [64][576]  k=tap*64+ci
#define OD0 60416    // 4 classes [64][K], K={256,128,128,64}
#define OD1 97280    // 4 classes [32][K], K={64,128,128,256}
#define OD2 115712   // 4 classes [16][32]
#define NWPK 117760

#define SIMSTRIDE 1024000   // 512*2000
#define ZHSTRIDE  1179648   // 512*2304

DEV float* bkt(float* hdr, int blk){ return hdr + H_BUK + (size_t)(blk & (NBUK-1))*BSTRIDE; }

// compute per-channel affine (a,c) from buckets into LDS ac[2*nch]
DEV void coef_lds(const float* __restrict__ hdr, int offS, int offQ,
                  const float* __restrict__ g, const float* __restrict__ be,
                  float* ac, int nch, float invN, int tid){
  if (tid < nch){
    float s = 0.f, q = 0.f;
    #pragma unroll
    for (int k=0;k<NBUK;k++){
      s += hdr[H_BUK + k*BSTRIDE + offS + tid];
      q += hdr[H_BUK + k*BSTRIDE + offQ + tid];
    }
    float m = s*invN;
    float v = q*invN - m*m;
    float a = g[tid]*rsqrtf(v + 1e-5f);
    ac[tid] = a;
    ac[nch+tid] = be[tid] - m*a;
  }
}

// ---------------- stats of strided-sampled input (for bn1 fold) ----------------
__global__ __launch_bounds__(256) void k_xstats(const float* __restrict__ x, float* __restrict__ hdr){
  __shared__ float red[8];
  float s = 0.f, q = 0.f;
  const int total = 512*49*49;
  for (int idx = blockIdx.x*256 + threadIdx.x; idx < total; idx += gridDim.x*256){
    int b = idx / 2401;
    int r = idx - b*2401;
    int i = r / 49, j = r - i*49;
    float v = 0.f;
    if (i > 0 && j > 0) v = x[(size_t)b*9216 + (2*i-1)*96 + (2*j-1)];
    s += v; q += v*v;
  }
  for (int o=32;o;o>>=1){ s += __shfl_down(s,o,64); q += __shfl_down(q,o,64); }
  int w = threadIdx.x>>6;
  if ((threadIdx.x&63)==0){ red[w*2]=s; red[w*2+1]=q; }
  __syncthreads();
  if (threadIdx.x==0){
    float* bk = bkt(hdr, blockIdx.x);
    atomicAdd(&bk[H_XS+0], red[0]+red[2]+red[4]+red[6]);
    atomicAdd(&bk[H_XS+1], red[1]+red[3]+red[5]+red[7]);
  }
}

// ---------------- pack all conv/deconv weights to bf16 [co][k] ----------------
__global__ __launch_bounds__(256) void k_wprep2(
    const float* __restrict__ c2w, const float* __restrict__ c3w, const float* __restrict__ c4w,
    const float* __restrict__ d0w, const float* __restrict__ d1w, const float* __restrict__ d2w,
    ushort_t* __restrict__ WPK){
  int i = blockIdx.x*256 + threadIdx.x;
  if (i >= NWPK) return;
  float val = 0.f;
  if (i < OW3){                       // conv2 [32][160]
    int co = i/160, k = i - co*160, tap = k>>4, ci = k&15;
    if (tap < 9) val = c2w[(co*16+ci)*9+tap];
  } else if (i < OW4){                // conv3 [64][288]
    int r = i - OW3; int co = r/288, k = r - co*288, tap = k>>5, ci = k&31;
    val = c3w[(co*32+ci)*9+tap];
  } else if (i < OD0){                // conv4 [64][576]
    int r = i - OW4; int co = r/576, k = r - co*576, tap = k>>6, ci = k&63;
    val = c4w[(co*64+ci)*9+tap];
  } else if (i < OD1){                // deconv0 classes
    int r = i - OD0;
    const int base[4]={0,16384,24576,32768}, K[4]={256,128,128,64};
    const int T0[4][4] = {{0,2,6,8},{1,7,0,0},{3,5,0,0},{4,0,0,0}};
    int cl = (r<16384)?0:(r<24576)?1:(r<32768)?2:3;
    int rr = r - base[cl]; int co = rr/K[cl], k = rr - co*K[cl], t = k>>6, ci = k&63;
    val = d0w[(ci*64+co)*9 + T0[cl][t]];
  } else if (i < OD2){                // deconv1 classes
    int r = i - OD1;
    const int base[4]={0,2048,6144,10240}, K[4]={64,128,128,256};
    const int T1[4][4] = {{4,0,0,0},{3,5,0,0},{1,7,0,0},{0,2,6,8}};
    int cl = (r<2048)?0:(r<6144)?1:(r<10240)?2:3;
    int rr = r - base[cl]; int co = rr/K[cl], k = rr - co*K[cl], t = k>>6, ci = k&63;
    val = d1w[(ci*32+co)*9 + T1[cl][t]];
  } else {                            // deconv2 classes [4][16][32]
    int r = i - OD2;
    int cl = r>>9, s = r&511, co = s>>5, ci = s&31;
    const int pis[4]={0,0,1,1}, pjs[4]={0,1,0,1};
    val = d2w[((ci*16+co)*2 + (1-pis[cl]))*2 + (1-pjs[cl])];
  }
  WPK[i] = f2bf(val);
}

// ---------------- memory rows -> bf16 + row norms ----------------
__global__ __launch_bounds__(256) void k_memrows(const float* __restrict__ mem, float* __restrict__ hdr,
                                                 ushort_t* __restrict__ mbf){
  __shared__ float red[4];
  const int m = blockIdx.x, tid = threadIdx.x;
  float part = 0.f;
  for (int i=tid;i<2304;i+=256){
    float v = mem[(size_t)m*2304+i];
    mbf[(size_t)m*2304+i] = f2bf(v);
    part += v*v;
  }
  for (int o=32;o;o>>=1) part += __shfl_down(part,o,64);
  if ((tid&63)==0) red[tid>>6] = part;
  __syncthreads();
  if (tid==0) hdr[H_MN+m] = sqrtf(red[0]+red[1]+red[2]+red[3]);
}

__global__ __launch_bounds__(256) void k_memT(const float* __restrict__ mem, ushort_t* __restrict__ mt){
  __shared__ ushort_t tile[32][33];
  const int ft = blockIdx.x % 72, mtile = blockIdx.x / 72;
  const int tx = threadIdx.x & 31, ty = threadIdx.x >> 5;
  #pragma unroll
  for (int r0=0;r0<4;r0++){
    int m = mtile*32 + r0*8 + ty;
    int f = ft*32 + tx;
    float v = (m < 2000) ? mem[(size_t)m*2304 + f] : 0.f;
    tile[r0*8+ty][tx] = f2bf(v);
  }
  __syncthreads();
  #pragma unroll
  for (int r0=0;r0<4;r0++){
    int f = ft*32 + r0*8 + ty;
    mt[(size_t)f*2016 + mtile*32 + tx] = tile[tx][r0*8+ty];
  }
}

// ---------------- conv2 (MFMA): 16->32, 3x3 s2 p1 on folded conv1 output ----------------
__global__ __launch_bounds__(256) void k_conv2m(
    const float* __restrict__ x, const ushort_t* __restrict__ WPK, const float* __restrict__ b2g,
    const float* __restrict__ c1w, const float* __restrict__ c1b,
    const float* __restrict__ bn1g, const float* __restrict__ bn1b,
    float* __restrict__ hdr, float* __restrict__ out){
  __shared__ ushort_t inp[27*51*16];    // [row][col][ci16], halo'd 51-grid rows [2*ro..2*ro+26]
  __shared__ float ac[32];
  const int blk = blockIdx.x, b = blk>>1, h = blk&1, tid = threadIdx.x;
  const int ro = h*13, nr = h?12:13, npos = nr*25, ntiles = (npos+15)>>4;
  if (tid < 16){
    float sx=0.f, qx=0.f;
    #pragma unroll
    for (int k=0;k<NBUK;k++){ sx += hdr[H_BUK+k*BSTRIDE+H_XS]; qx += hdr[H_BUK+k*BSTRIDE+H_XS+1]; }
    const float N = 512.f*49.f*49.f;
    float mx = sx/N, vx = qx/N - mx*mx;
    float mean = c1w[tid]*mx + c1b[tid];
    float a = bn1g[tid]*rsqrtf(c1w[tid]*c1w[tid]*vx + 1e-5f);
    ac[tid] = a*c1w[tid];
    ac[16+tid] = a*(c1b[tid]-mean) + bn1b[tid];
  }
  __syncthreads();
  for (int e = tid; e < 27*51; e += 256){
    int lr = e/51, gc = e - lr*51;
    int grg = 2*ro + lr;
    bool inside = (grg>=1 && grg<=49 && gc>=1 && gc<=49);
    float v = 0.f;
    if (grg>=2 && grg<=49 && gc>=2 && gc<=49) v = x[(size_t)b*9216 + (2*grg-3)*96 + (2*gc-3)];
    ushort_t hv[16];
    if (inside){
      #pragma unroll
      for (int c=0;c<16;c++) hv[c] = f2bf(fmaxf(fmaf(ac[c], v, ac[16+c]), 0.f));
    } else {
      #pragma unroll
      for (int c=0;c<16;c++) hv[c] = 0;
    }
    uint32_t w0[8];
    #pragma unroll
    for (int c=0;c<8;c++) w0[c] = (uint32_t)hv[2*c] | ((uint32_t)hv[2*c+1]<<16);
    uint4* dst = (uint4*)&inp[e*16];
    dst[0] = make_uint4(w0[0],w0[1],w0[2],w0[3]);
    dst[1] = make_uint4(w0[4],w0[5],w0[6],w0[7]);
  }
  __syncthreads();
  const int wv = tid>>6, lane = tid&63, r = lane&15, q = lane>>4;
  const int cotile = wv&1;
  bf16x8 af[5];
  #pragma unroll
  for (int c=0;c<5;c++) af[c] = *(const bf16x8*)(WPK + OW2 + (cotile*16+r)*160 + c*32 + q*8);
  float biasr[4];
  #pragma unroll
  for (int v=0;v<4;v++) biasr[v] = b2g[cotile*16 + q*4 + v];
  const int TOFF[10] = {0,1,2,51,52,53,102,103,104,0};
  const int qhi = q>>1, ci0 = (q&1)*8;
  float sacc[4]={0,0,0,0}, qacc[4]={0,0,0,0};
  for (int t = wv>>1; t < ntiles; t += 2){
    int p = t*16 + r;
    bool ok = p < npos;
    int pc = ok ? p : 0;
    int a_ = pc/25, c_ = pc - a_*25;
    int pb = (2*a_)*51 + 2*c_;
    f32x4 acc = {0.f,0.f,0.f,0.f};
    #pragma unroll
    for (int c=0;c<5;c++){
      int toff = qhi ? TOFF[2*c+1] : TOFF[2*c];
      bf16x8 bv = *(const bf16x8*)&inp[(pb + toff)*16 + ci0];
      acc = __builtin_amdgcn_mfma_f32_16x16x32_bf16(af[c], bv, acc, 0, 0, 0);
    }
    if (ok){
      int pg = (ro + a_)*25 + c_;
      #pragma unroll
      for (int reg=0;reg<4;reg++){
        float y = acc[reg] + biasr[reg];
        out[((size_t)b*32 + cotile*16 + q*4 + reg)*625 + pg] = y;
        sacc[reg] += y; qacc[reg] += y*y;
      }
    }
  }
  float* bk = bkt(hdr, blk);
  #pragma unroll
  for (int reg=0;reg<4;reg++){
    float s = sacc[reg], qq = qacc[reg];
    for (int o=8;o;o>>=1){ s += __shfl_down(s,o,16); qq += __shfl_down(qq,o,16); }
    if (r==0){ atomicAdd(&bk[H_S2+cotile*16+q*4+reg], s); atomicAdd(&bk[H_Q2+cotile*16+q*4+reg], qq); }
  }
}

// ---------------- conv3 (MFMA): 32->64, 3x3 s2 p1, 25->13 ----------------
__global__ __launch_bounds__(256) void k_conv3m(
    const float* __restrict__ h2, const ushort_t* __restrict__ WPK, const float* __restrict__ b3g,
    const float* __restrict__ g, const float* __restrict__ be,
    float* __restrict__ hdr, float* __restrict__ out){
  __shared__ ushort_t inp[27*27*32];   // [cell][ci32], halo'd 27-grid
  __shared__ float ac[64];
  const int b = blockIdx.x, tid = threadIdx.x;
  coef_lds(hdr, H_S2, H_Q2, g, be, ac, 32, 1.f/(512.f*625.f), tid);
  __syncthreads();
  for (int e = tid; e < 27*27*32; e += 256){
    int ci = e & 31, cell = e >> 5;
    int gr = cell/27, gc = cell - gr*27;
    int i = gr-1, j = gc-1;
    float v = 0.f;
    if ((unsigned)i < 25u && (unsigned)j < 25u){
      float raw = h2[((size_t)b*32 + ci)*625 + i*25 + j];
      v = fmaxf(fmaf(ac[ci], raw, ac[32+ci]), 0.f);
    }
    inp[e] = f2bf(v);
  }
  __syncthreads();
  const int wv = tid>>6, lane = tid&63, r = lane&15, q = lane>>4;
  bf16x8 af[9];
  #pragma unroll
  for (int c=0;c<9;c++) af[c] = *(const bf16x8*)(WPK + OW3 + (wv*16+r)*288 + c*32 + q*8);
  float biasr[4];
  #pragma unroll
  for (int v=0;v<4;v++) biasr[v] = b3g[wv*16 + q*4 + v];
  const int TOFF[9] = {0,1,2,27,28,29,54,55,56};
  const int ci0 = q*8;
  float sacc[4]={0,0,0,0}, qacc[4]={0,0,0,0};
  for (int t = 0; t < 11; t++){
    int p = t*16 + r;
    bool ok = p < 169;
    int pc = ok ? p : 0;
    int a_ = pc/13, c_ = pc - a_*13;
    int pb = (2*a_)*27 + 2*c_;
    f32x4 acc = {0.f,0.f,0.f,0.f};
    #pragma unroll
    for (int c=0;c<9;c++){
      bf16x8 bv = *(const bf16x8*)&inp[(pb + TOFF[c])*32 + ci0];
      acc = __builtin_amdgcn_mfma_f32_16x16x32_bf16(af[c], bv, acc, 0, 0, 0);
    }
    if (ok){
      #pragma unroll
      for (int reg=0;reg<4;reg++){
        float y = acc[reg] + biasr[reg];
        out[((size_t)b*64 + wv*16 + q*4 + reg)*169 + p] = y;
        sacc[reg] += y; qacc[reg] += y*y;
      }
    }
  }
  float* bk = bkt(hdr, b);
  #pragma unroll
  for (int reg=0;reg<4;reg++){
    float s = sacc[reg], qq = qacc[reg];
    for (int o=8;o;o>>=1){ s += __shfl_down(s,o,16); qq += __shfl_down(qq,o,16); }
    if (r==0){ atomicAdd(&bk[H_S3+wv*16+q*4+reg], s); atomicAdd(&bk[H_Q3+wv*16+q*4+reg], qq); }
  }
}

// ---------------- conv4 (MFMA): 64->64, 3x3 s2 p0, 13->6 ----------------
__global__ __launch_bounds__(256) void k_conv4m(
    const float* __restrict__ h3, const ushort_t* __restrict__ WPK, const float* __restrict__ b4g,
    const float* __restrict__ g, const float* __restrict__ be,
    float* __restrict__ hdr, float* __restrict__ out){
  __shared__ ushort_t inp[169*64];     // [cell][ci64]
  __shared__ float ac[128];
  const int b = blockIdx.x, tid = threadIdx.x;
  coef_lds(hdr, H_S3, H_Q3, g, be, ac, 64, 1.f/(512.f*169.f), tid);
  __syncthreads();
  for (int e = tid; e < 169*64; e += 256){
    int ci = e & 63, cell = e >> 6;
    float raw = h3[((size_t)b*64 + ci)*169 + cell];
    inp[e] = f2bf(fmaxf(fmaf(ac[ci], raw, ac[64+ci]), 0.f));
  }
  __syncthreads();
  const int wv = tid>>6, lane = tid&63, r = lane&15, q = lane>>4;
  bf16x8 af[18];
  #pragma unroll
  for (int c=0;c<18;c++) af[c] = *(const bf16x8*)(WPK + OW4 + (wv*16+r)*576 + c*32 + q*8);
  float biasr[4];
  #pragma unroll
  for (int v=0;v<4;v++) biasr[v] = b4g[wv*16 + q*4 + v];
  const int TOFF[9] = {0,1,2,13,14,15,26,27,28};
  float sacc[4]={0,0,0,0}, qacc[4]={0,0,0,0};
  for (int t = 0; t < 3; t++){
    int p = t*16 + r;
    bool ok = p < 36;
    int pc = ok ? p : 0;
    int a_ = pc/6, c_ = pc - a_*6;
    int pb = (2*a_)*13 + 2*c_;
    f32x4 acc = {0.f,0.f,0.f,0.f};
    #pragma unroll
    for (int c=0;c<18;c++){
      int ci0 = (c&1)*32 + q*8;
      bf16x8 bv = *(const bf16x8*)&inp[(pb + TOFF[c>>1])*64 + ci0];
      acc = __builtin_amdgcn_mfma_f32_16x16x32_bf16(af[c], bv, acc, 0, 0, 0);
    }
    if (ok){
      #pragma unroll
      for (int reg=0;reg<4;reg++){
        float y = acc[reg] + biasr[reg];
        out[((size_t)b*64 + wv*16 + q*4 + reg)*36 + p] = y;
        sacc[reg] += y; qacc[reg] += y*y;
      }
    }
  }
  float* bk = bkt(hdr, b);
  #pragma unroll
  for (int reg=0;reg<4;reg++){
    float s = sacc[reg], qq = qacc[reg];
    for (int o=8;o;o>>=1){ s += __shfl_down(s,o,16); qq += __shfl_down(qq,o,16); }
    if (r==0){ atomicAdd(&bk[H_S4+wv*16+q*4+reg], s); atomicAdd(&bk[H_Q4+wv*16+q*4+reg], qq); }
  }
}

// z = relu(bn4(conv4 raw)) -> bf16, plus per-row norm (computes A4/C4 itself)
__global__ __launch_bounds__(256) void k_z(const float* __restrict__ zraw, float* __restrict__ hdr,
                                           ushort_t* __restrict__ zbf,
                                           const float* __restrict__ g, const float* __restrict__ be){
  __shared__ float ac[128];
  __shared__ float red[4];
  const int b = blockIdx.x, tid = threadIdx.x;
  coef_lds(hdr, H_S4, H_Q4, g, be, ac, 64, 1.f/(512.f*36.f), tid);
  __syncthreads();
  float part = 0.f;
  for (int i=tid;i<2304;i+=256){
    int c = i/36;
    float h = fmaxf(fmaf(ac[c], zraw[(size_t)b*2304+i], ac[64+c]), 0.f);
    zbf[(size_t)b*2304+i] = f2bf(h);
    part += h*h;
  }
  for (int o=32;o;o>>=1) part += __shfl_down(part,o,64);
  if ((tid&63)==0) red[tid>>6] = part;
  __syncthreads();
  if (tid==0) hdr[H_ZN+b] = sqrtf(red[0]+red[1]+red[2]+red[3]);
}

// ---------------- blocked GEMM, split-K: D_s[M][N] = A[M][ks] * B[N][ks]^T
__global__ __launch_bounds__(256) void k_gemmB(const ushort_t* __restrict__ A, const ushort_t* __restrict__ Bm,
                                               float* __restrict__ D, int Nb, int N, int Kp, int kch,
                                               int tiles, int ksp, size_t dstride){
  __shared__ __align__(16) ushort_t lB[128*40];
  const int blk = blockIdx.x;
  const int s = blk / tiles, t = blk - s*tiles;
  const int bi = t / Nb, bj = t - bi*Nb;
  const int m0 = bi*128, n0 = bj*128;
  const int k0 = s*ksp, k1 = min(kch, k0 + ksp);
  const int tid = threadIdx.x;
  const int lane = tid & 63, wv = tid >> 6;
  const int r = lane & 15, q = lane >> 4;
  const int wr = wv >> 1, wc = wv & 1;
  float* Ds = D + (size_t)s*dstride;
  const int srow = tid >> 1, skq = (tid & 1) * 16;
  const bool bok = (n0 + srow) < N;
  const ushort_t* pb = Bm + (size_t)(n0 + srow)*Kp + skq;
  uint4* wB = (uint4*)&lB[srow*40 + skq];
  const uint4 zz = make_uint4(0,0,0,0);
  uint4 rb0 = bok ? *(const uint4*)(pb + k0*32)     : zz;
  uint4 rb1 = bok ? *(const uint4*)(pb + k0*32 + 8) : zz;
  const ushort_t* pa = A + (size_t)(m0 + wr*64 + r)*Kp + q*8;
  bf16x8 aN[4];
  #pragma unroll
  for (int mt=0;mt<4;mt++) aN[mt] = *(const bf16x8*)(pa + k0*32 + (size_t)(mt*16)*Kp);
  f32x4 acc[4][4];
  #pragma unroll
  for (int i=0;i<4;i++)
    #pragma unroll
    for (int j=0;j<4;j++) acc[i][j] = (f32x4){0.f,0.f,0.f,0.f};
  for (int k=k0; k<k1; k++){
    if (k > k0) __syncthreads();
    wB[0] = rb0; wB[1] = rb1;
    bf16x8 aF[4];
    #pragma unroll
    for (int mt=0;mt<4;mt++) aF[mt] = aN[mt];
    if (k+1 < k1){
      const ushort_t* nb = pb + (k+1)*32;
      rb0 = bok ? *(const uint4*)(nb)     : zz;
      rb1 = bok ? *(const uint4*)(nb + 8) : zz;
      const ushort_t* na = pa + (k+1)*32;
      #pragma unroll
      for (int mt=0;mt<4;mt++) aN[mt] = *(const bf16x8*)(na + (size_t)(mt*16)*Kp);
    }
    __syncthreads();
    bf16x8 bF[4];
    #pragma unroll
    for (int nt=0;nt<4;nt++) bF[nt] = *(const bf16x8*)&lB[(wc*64+nt*16+r)*40 + q*8];
    #pragma unroll
    for (int mt=0;mt<4;mt++)
      #pragma unroll
      for (int nt=0;nt<4;nt++)
        acc[mt][nt] = __builtin_amdgcn_mfma_f32_16x16x32_bf16(aF[mt], bF[nt], acc[mt][nt], 0, 0, 0);
  }
  #pragma unroll
  for (int mt=0;mt<4;mt++){
    int row = m0 + wr*64 + mt*16 + q*4;
    #pragma unroll
    for (int nt=0;nt<4;nt++){
      int col = n0 + wc*64 + nt*16 + r;
      if (col < N){
        #pragma unroll
        for (int reg=0;reg<4;reg++)
          Ds[(size_t)(row+reg)*N + col] = acc[mt][nt][reg];
      }
    }
  }
}

// softmax over M=2000 (sums 4 split-K partials) + hard-shrink + L1 renorm -> bf16
__global__ __launch_bounds__(256) void k_softmax(const float* __restrict__ sim, float* __restrict__ hdr,
                                                 ushort_t* __restrict__ wbf){
  __shared__ float e[2000];
  __shared__ float red[8];
  const int b = blockIdx.x, tid = threadIdx.x;
  const float znb = hdr[H_ZN+b];
  float part = 0.f;
  for (int m=tid;m<2000;m+=256){
    size_t ix = (size_t)b*2000+m;
    float sv = sim[ix] + sim[ix+SIMSTRIDE] + sim[ix+2*SIMSTRIDE] + sim[ix+3*SIMSTRIDE];
    float s = sv / fmaxf(znb * hdr[H_MN+m], 1e-8f);
    float ev = __expf(s);
    e[m] = ev; part += ev;
  }
  for (int o=32;o;o>>=1) part += __shfl_down(part,o,64);
  if ((tid&63)==0) red[tid>>6] = part;
  __syncthreads();
  const float denom = red[0]+red[1]+red[2]+red[3];
  const float t = 1.0f/2000.0f;
  float part2 = 0.f;
  for (int m=tid;m<2000;m+=256){
    float w = e[m]/denom;
    float d = w - t;
    float sh = fmaxf(d,0.f)*w/(fabsf(d)+0.01f);
    e[m] = sh; part2 += sh;
  }
  for (int o=32;o;o>>=1) part2 += __shfl_down(part2,o,64);
  if ((tid&63)==0) red[4+(tid>>6)] = part2;
  __syncthreads();
  const float inv = 1.0f/(red[4]+red[5]+red[6]+red[7]);
  for (int m=tid;m<2016;m+=256){
    ushort_t o = 0;
    if (m < 2000) o = f2bf(e[m]*inv);
    wbf[(size_t)b*2016+m] = o;
  }
}

// ---------------- deconv0 (MFMA): 64->64, k3 s2 p0, 6->13 (sums 4 zh partials) ----------------
__global__ __launch_bounds__(256) void k_deconv0m(
    const float* __restrict__ zh, const ushort_t* __restrict__ WPK, const float* __restrict__ b0g,
    float* __restrict__ hdr, float* __restrict__ out){
  __shared__ ushort_t inp[64*64];      // [cell 8x8 halo][ci64]
  const int b = blockIdx.x, tid = threadIdx.x;
  for (int e = tid; e < 64*64; e += 256){
    int ci = e & 63, cell = e >> 6;
    int r8 = cell>>3, c8 = cell&7;
    float v = 0.f;
    if (r8>=1 && r8<=6 && c8>=1 && c8<=6){
      size_t ix = (size_t)b*2304 + ci*36 + (r8-1)*6 + (c8-1);
      v = zh[ix] + zh[ix+ZHSTRIDE] + zh[ix+2*ZHSTRIDE] + zh[ix+3*ZHSTRIDE];
    }
    inp[e] = f2bf(v);
  }
  __syncthreads();
  const int wv = tid>>6, lane = tid&63, r = lane&15, q = lane>>4;
  float biasr[4];
  #pragma unroll
  for (int v=0;v<4;v++) biasr[v] = b0g[wv*16 + q*4 + v];
  const int NCOL[4]={7,6,7,6}, NPOS[4]={49,42,42,36}, NT[4]={4,3,3,3},
            NCH[4]={8,4,4,2}, KB[4]={0,16384,24576,32768}, KK[4]={256,128,128,64},
            PI[4]={0,0,1,1}, PJ[4]={0,1,0,1};
  const int TOFF[4][4] = {{9,8,1,0},{9,1,0,0},{9,8,0,0},{9,0,0,0}};
  float sacc[4]={0,0,0,0}, qacc[4]={0,0,0,0};
  #pragma unroll
  for (int cl=0; cl<4; cl++){
    bf16x8 af[8];
    #pragma unroll
    for (int m=0;m<NCH[cl];m++)
      af[m] = *(const bf16x8*)(WPK + OD0 + KB[cl] + (wv*16+r)*KK[cl] + m*32 + q*8);
    for (int t = 0; t < NT[cl]; t++){
      int p = t*16 + r;
      bool ok = p < NPOS[cl];
      int pc = ok ? p : 0;
      int a_ = pc/NCOL[cl], c_ = pc - a_*NCOL[cl];
      int pb = a_*8 + c_;
      f32x4 acc = {0.f,0.f,0.f,0.f};
      #pragma unroll
      for (int m=0;m<NCH[cl];m++){
        int ci0 = (m&1)*32 + q*8;
        bf16x8 bv = *(const bf16x8*)&inp[(pb + TOFF[cl][m>>1])*64 + ci0];
        acc = __builtin_amdgcn_mfma_f32_16x16x32_bf16(af[m], bv, acc, 0, 0, 0);
      }
      if (ok){
        int pos = (2*a_+PI[cl])*13 + (2*c_+PJ[cl]);
        #pragma unroll
        for (int reg=0;reg<4;reg++){
          float y = acc[reg] + biasr[reg];
          out[((size_t)b*64 + wv*16 + q*4 + reg)*169 + pos] = y;
          sacc[reg] += y; qacc[reg] += y*y;
        }
      }
    }
  }
  float* bk = bkt(hdr, b);
  #pragma unroll
  for (int reg=0;reg<4;reg++){
    float s = sacc[reg], qq = qacc[reg];
    for (int o=8;o;o>>=1){ s += __shfl_down(s,o,16); qq += __shfl_down(qq,o,16); }
    if (r==0){ atomicAdd(&bk[H_DS0+wv*16+q*4+reg], s); atomicAdd(&bk[H_DQ0+wv*16+q*4+reg], qq); }
  }
}

// ---------------- deconv1 (MFMA): 64->32, k3 s2 p1, 13->25 ----------------
__global__ __launch_bounds__(256) void k_deconv1m(
    const float* __restrict__ g0, const ushort_t* __restrict__ WPK, const float* __restrict__ b1g,
    const float* __restrict__ g, const float* __restrict__ be,
    float* __restrict__ hdr, float* __restrict__ out){
  __shared__ ushort_t inp[169*64];     // [cell 13x13][ci64]
  __shared__ float ac[128];
  const int b = blockIdx.x, tid = threadIdx.x;
  coef_lds(hdr, H_DS0, H_DQ0, g, be, ac, 64, 1.f/(512.f*169.f), tid);
  __syncthreads();
  for (int e = tid; e < 169*64; e += 256){
    int ci = e & 63, cell = e >> 6;
    float raw = g0[((size_t)b*64 + ci)*169 + cell];
    inp[e] = f2bf(fmaxf(fmaf(ac[ci], raw, ac[64+ci]), 0.f));
  }
  __syncthreads();
  const int wv = tid>>6, lane = tid&63, r = lane&15, q = lane>>4;
  const int cotile = wv&1, ph = wv>>1;
  float biasr[4];
  #pragma unroll
  for (int v=0;v<4;v++) biasr[v] = b1g[cotile*16 + q*4 + v];
  const int NCOL[4]={13,12,13,12}, NPOS[4]={169,156,156,144}, NT[4]={11,10,10,9},
            NCH[4]={2,4,4,8}, KB[4]={0,2048,6144,10240}, KK[4]={64,128,128,256},
            PI[4]={0,0,1,1}, PJ[4]={0,1,0,1};
  const int TOFF[4][4] = {{0,0,0,0},{1,0,0,0},{13,0,0,0},{14,13,1,0}};
  float sacc[4]={0,0,0,0}, qacc[4]={0,0,0,0};
  #pragma unroll
  for (int cl=0; cl<4; cl++){
    bf16x8 af[8];
    #pragma unroll
    for (int m=0;m<NCH[cl];m++)
      af[m] = *(const bf16x8*)(WPK + OD1 + KB[cl] + (cotile*16+r)*KK[cl] + m*32 + q*8);
    for (int t = ph; t < NT[cl]; t += 2){
      int p = t*16 + r;
      bool ok = p < NPOS[cl];
      int pc = ok ? p : 0;
      int a_ = pc/NCOL[cl], c_ = pc - a_*NCOL[cl];
      int pb = a_*13 + c_;
      f32x4 acc = {0.f,0.f,0.f,0.f};
      #pragma unroll
      for (int m=0;m<NCH[cl];m++){
        int ci0 = (m&1)*32 + q*8;
        bf16x8 bv = *(const bf16x8*)&inp[(pb + TOFF[cl][m>>1])*64 + ci0];
        acc = __builtin_amdgcn_mfma_f32_16x16x32_bf16(af[m], bv, acc, 0, 0, 0);
      }
      if (ok){
        int pos = (2*a_+PI[cl])*25 + (2*c_+PJ[cl]);
        #pragma unroll
        for (int reg=0;reg<4;reg++){
          float y = acc[reg] + biasr[reg];
          out[((size_t)b*32 + cotile*16 + q*4 + reg)*625 + pos] = y;
          sacc[reg] += y; qacc[reg] += y*y;
        }
      }
    }
  }
  float* bk = bkt(hdr, b);
  #pragma unroll
  for (int reg=0;reg<4;reg++){
    float s = sacc[reg], qq = qacc[reg];
    for (int o=8;o;o>>=1){ s += __shfl_down(s,o,16); qq += __shfl_down(qq,o,16); }
    if (r==0){ atomicAdd(&bk[H_DS1+cotile*16+q*4+reg], s); atomicAdd(&bk[H_DQ1+cotile*16+q*4+reg], qq); }
  }
}

// ---------------- deconv2 (MFMA): 32->16, k2 s2 p1 op1, 25->49 ----------------
// Output: bf16 parity-plane layout G2BF[b][co][cl][625] (cl=(oi&1)*2+(oj&1))
__global__ __launch_bounds__(256) void k_deconv2m(
    const float* __restrict__ g1, const ushort_t* __restrict__ WPK, const float* __restrict__ bg,
    const float* __restrict__ g, const float* __restrict__ be,
    float* __restrict__ hdr, ushort_t* __restrict__ out){
  __shared__ ushort_t inp[625*32];     // [cell 25x25][ci32]
  __shared__ float ac[64];
  const int b = blockIdx.x, tid = threadIdx.x;
  coef_lds(hdr, H_DS1, H_DQ1, g, be, ac, 32, 1.f/(512.f*625.f), tid);
  __syncthreads();
  for (int e = tid; e < 625*32; e += 256){
    int ci = e & 31, cell = e >> 5;
    float raw = g1[((size_t)b*32 + ci)*625 + cell];
    inp[e] = f2bf(fmaxf(fmaf(ac[ci], raw, ac[32+ci]), 0.f));
  }
  __syncthreads();
  const int wv = tid>>6, lane = tid&63, r = lane&15, q = lane>>4;
  const int cl = wv;   // one parity class per wave
  float biasr[4];
  #pragma unroll
  for (int v=0;v<4;v++) biasr[v] = bg[q*4 + v];
  const int NCOL[4]={25,24,25,24}, NPOS[4]={625,600,600,576}, NT[4]={40,38,38,36},
            TOFF[4]={0,1,25,26};
  const int ci0 = q*8;
  const int nc = NCOL[cl], npos = NPOS[cl], nt = NT[cl], toff = TOFF[cl];
  bf16x8 af = *(const bf16x8*)(WPK + OD2 + cl*512 + r*32 + q*8);
  float sacc[4]={0,0,0,0}, qacc[4]={0,0,0,0};
  for (int t = 0; t < nt; t++){
    int p = t*16 + r;
    bool ok = p < npos;
    int pc = ok ? p : 0;
    int a_ = pc/nc, c_ = pc - a_*nc;
    int pb = a_*25 + c_;
    f32x4 acc = {0.f,0.f,0.f,0.f};
    bf16x8 bv = *(const bf16x8*)&inp[(pb + toff)*32 + ci0];
    acc = __builtin_amdgcn_mfma_f32_16x16x32_bf16(af, bv, acc, 0, 0, 0);
    if (ok){
      #pragma unroll
      for (int reg=0;reg<4;reg++){
        float y = acc[reg] + biasr[reg];
        out[((size_t)(b*16 + q*4 + reg)*4 + cl)*625 + p] = f2bf(y);
        sacc[reg] += y; qacc[reg] += y*y;
      }
    }
  }
  float* bk = bkt(hdr, b);
  #pragma unroll
  for (int reg=0;reg<4;reg++){
    float s = sacc[reg], qq = qacc[reg];
    for (int o=8;o;o>>=1){ s += __shfl_down(s,o,16); qq += __shfl_down(qq,o,16); }
    if (r==0){ atomicAdd(&bk[H_DS2+q*4+reg], s); atomicAdd(&bk[H_DQ2+q*4+reg], qq); }
  }
}

// ---------------- deconv3: input-location-per-thread; each thread emits 4 output px ----------------
__global__ __launch_bounds__(256) void k_deconv3(const ushort_t* __restrict__ g2, const float* __restrict__ w,
                                                 const float* __restrict__ bias,
                                                 const float* __restrict__ g, const float* __restrict__ be,
                                                 float* __restrict__ hdr, float* __restrict__ out){
  __shared__ float ac[32];
  __shared__ float wl[64];
  const int tid = threadIdx.x;
  coef_lds(hdr, H_DS2, H_DQ2, g, be, ac, 16, 1.f/(512.f*2401.f), tid);
  if (tid >= 64 && tid < 128) wl[tid-64] = w[tid-64];
  __syncthreads();
  int idx = blockIdx.x*256 + tid;
  if (idx >= 512*2401) return;
  int b = idx / 2401; int loc = idx - b*2401;
  int ii = loc / 49, jj = loc - ii*49;
  int pi = ii & 1, pj = jj & 1, cl = pi*2 + pj;
  int a = ii >> 1, c = jj >> 1;
  int nc = pj ? 24 : 25;
  const float b0 = bias[0];
  float acc00 = b0, acc01 = b0, acc10 = b0, acc11 = b0;
  const ushort_t* gp = g2 + ((size_t)(b*16)*4 + cl)*625 + a*nc + c;
  #pragma unroll
  for (int ci=0; ci<16; ci++){
    float raw = bf2f(gp[(size_t)ci*4*625]);
    float h = fmaxf(fmaf(ac[ci], raw, ac[16+ci]), 0.f);
    acc00 = fmaf(h, wl[ci*4+0], acc00);
    acc01 = fmaf(h, wl[ci*4+1], acc01);
    acc10 = fmaf(h, wl[ci*4+2], acc10);
    acc11 = fmaf(h, wl[ci*4+3], acc11);
  }
  float* op = out + (size_t)b*9604 + (2*ii)*98 + 2*jj;
  op[0]   = 1.f/(1.f + __expf(-acc00));
  op[1]   = 1.f/(1.f + __expf(-acc01));
  op[98]  = 1.f/(1.f + __expf(-acc10));
  op[99]  = 1.f/(1.f + __expf(-acc11));
}

// ======================================================================
extern "C" void kernel_launch(void* const* d_in, const int* in_sizes, int n_in,
                              void* d_out, int out_size, void* d_ws, size_t ws_size,
                              hipStream_t stream){
  (void)in_sizes; (void)n_in; (void)out_size; (void)ws_size;
  const float* x     = (const float*)d_in[0];
  const float* c1w   = (const float*)d_in[1];
  const float* c1b   = (const float*)d_in[2];
  const float* bn1g  = (const float*)d_in[3];
  const float* bn1b  = (const float*)d_in[4];
  const float* c2w   = (const float*)d_in[5];
  const float* c2b   = (const float*)d_in[6];
  const float* bn2g  = (const float*)d_in[7];
  const float* bn2b  = (const float*)d_in[8];
  const float* c3w   = (const float*)d_in[9];
  const float* c3b   = (const float*)d_in[10];
  const float* bn3g  = (const float*)d_in[11];
  const float* bn3b  = (const float*)d_in[12];
  const float* c4w   = (const float*)d_in[13];
  const float* c4b   = (const float*)d_in[14];
  const float* bn4g  = (const float*)d_in[15];
  const float* bn4b  = (const float*)d_in[16];
  const float* mem   = (const float*)d_in[17];
  const float* d0w   = (const float*)d_in[18];
  const float* d0b   = (const float*)d_in[19];
  const float* dbn0g = (const float*)d_in[20];
  const float* dbn0b = (const float*)d_in[21];
  const float* d1w   = (const float*)d_in[22];
  const float* d1b   = (const float*)d_in[23];
  const float* dbn1g = (const float*)d_in[24];
  const float* dbn1b = (const float*)d_in[25];
  const float* d2w   = (const float*)d_in[26];
  const float* d2b   = (const float*)d_in[27];
  const float* dbn2g = (const float*)d_in[28];
  const float* dbn2b = (const float*)d_in[29];
  const float* d3w   = (const float*)d_in[30];
  const float* d3b   = (const float*)d_in[31];

  float* hdr  = (float*)d_ws;
  float* H2   = hdr + HDR_FLOATS;        // 512*32*625 (reused as G1)
  float* H3   = H2 + 10240000;           // 512*64*169 (reused as G0)
  float* ZRAW = H3 + 5537792;            // 512*2304
  float* WSLOT= ZRAW + 1179648;          // 73728 floats (holds WPK bf16)
  float* G2   = WSLOT + 73728;           // 19.67M floats scratch region
  ushort_t* MEMBF = (ushort_t*)(G2 + 19668992); // 2000*2304
  ushort_t* MEMT  = MEMBF + 4608000;            // 2304*2016
  ushort_t* ZBF   = MEMT + 4644864;             // 512*2304
  ushort_t* WBF   = ZBF + 1179648;              // 512*2016
  ushort_t* WPK   = (ushort_t*)WSLOT;
  // split-K partials overlaid on G2 region (dead before deconv2m writes G2BF):
  float* SIMP = G2;                      // 4 * 512*2000
  float* ZHP  = G2 + 4*SIMSTRIDE;        // 4 * 512*2304
  ushort_t* G2BF = (ushort_t*)G2;        // 512*16*4*625 bf16
  float* G0 = H3;
  float* G1 = H2;
  float* OUT = (float*)d_out;

  hipMemsetAsync(hdr, 0, HDR_FLOATS*sizeof(float), stream);
  k_xstats   <<<1024, 256, 0, stream>>>(x, hdr);
  k_wprep2   <<<460, 256, 0, stream>>>(c2w, c3w, c4w, d0w, d1w, d2w, WPK);
  k_memrows  <<<2000, 256, 0, stream>>>(mem, hdr, MEMBF);
  k_memT     <<<72*63, 256, 0, stream>>>(mem, MEMT);
  k_conv2m   <<<1024, 256, 0, stream>>>(x, WPK, c2b, c1w, c1b, bn1g, bn1b, hdr, H2);
  k_conv3m   <<<512, 256, 0, stream>>>(H2, WPK, c3b, bn2g, bn2b, hdr, H3);
  k_conv4m   <<<512, 256, 0, stream>>>(H3, WPK, c4b, bn3g, bn3b, hdr, ZRAW);
  k_z        <<<512, 256, 0, stream>>>(ZRAW, hdr, ZBF, bn4g, bn4b);
  k_gemmB    <<<256, 256, 0, stream>>>(ZBF, MEMBF, SIMP, 16, 2000, 2304, 72, 64, 18, SIMSTRIDE);
  k_softmax  <<<512, 256, 0, stream>>>(SIMP, hdr, WBF);
  k_gemmB    <<<288, 256, 0, stream>>>(WBF, MEMT, ZHP, 18, 2304, 2016, 63, 72, 16, ZHSTRIDE);
  k_deconv0m <<<512, 256, 0, stream>>>(ZHP, WPK, d0b, hdr, G0);
  k_deconv1m <<<512, 256, 0, stream>>>(G0, WPK, d1b, dbn0g, dbn0b, hdr, G1);
  k_deconv2m <<<512, 256, 0, stream>>>(G1, WPK, d2b, dbn1g, dbn1b, hdr, G2BF);
  k_deconv3  <<<4802, 256, 0, stream>>>(G2BF, d3w, d3b, dbn2g, dbn2b, hdr, OUT);
}

// Round 9
// 353.323 us; speedup vs baseline: 3.7634x; 1.1610x over previous
//
#include <hip/hip_runtime.h>
#include <stdint.h>

// R9: channel-last bf16 inter-layer tensors (conv2->conv3->conv4, dec0->dec1->dec2)
// with coalesced uint4 staging + affine-on-unpack; XOR chunk swizzle in LDS to
// kill MFMA B-frag bank conflicts; conv3m split into 2 spatial halves (grid 1024).

typedef unsigned short ushort_t;
typedef __bf16 bf16x8 __attribute__((ext_vector_type(8)));
typedef float f32x4 __attribute__((ext_vector_type(4)));

#define DEV static __device__ __forceinline__

DEV ushort_t f2bf(float f){
  union { float f; uint32_t u; } v; v.f = f;
  return (ushort_t)((v.u + 0x7FFFu + ((v.u >> 16) & 1u)) >> 16);
}
DEV float bf2f(ushort_t u){
  union { uint32_t u; float f; } v; v.u = ((uint32_t)u) << 16;
  return v.f;
}

// affine+relu two packed bf16 (raw) -> packed bf16
DEV uint32_t affine2(uint32_t rw, const float* ac, int ci, int nch){
  float lo = bf2f((ushort_t)(rw & 0xffffu));
  float hi = bf2f((ushort_t)(rw >> 16));
  lo = fmaxf(fmaf(ac[ci],   lo, ac[nch+ci]),   0.f);
  hi = fmaxf(fmaf(ac[ci+1], hi, ac[nch+ci+1]), 0.f);
  return (uint32_t)f2bf(lo) | ((uint32_t)f2bf(hi) << 16);
}
DEV uint4 stage_chunk(uint4 raw, const float* ac, int ci0, int nch){
  uint4 o;
  o.x = affine2(raw.x, ac, ci0+0, nch);
  o.y = affine2(raw.y, ac, ci0+2, nch);
  o.z = affine2(raw.z, ac, ci0+4, nch);
  o.w = affine2(raw.w, ac, ci0+6, nch);
  return o;
}

// ---------------- header (stats/coeff) offsets in floats ----------------
#define H_XS   0
#define H_S2   64
#define H_Q2   96
#define H_S3   192
#define H_Q3   256
#define H_S4   448
#define H_Q4   512
#define H_DS0  704
#define H_DQ0  768
#define H_DS1  960
#define H_DQ1  992
#define H_DS2  1088
#define H_DQ2  1104
#define H_ZN   1152   // [512]
#define H_MN   1664   // [2000]
#define H_BUK  4096   // 16 bucket banks of 1280 floats each
#define NBUK   16
#define BSTRIDE 1280
#define HDR_FLOATS (H_BUK + NBUK*BSTRIDE)

// packed-weight (bf16) offsets in WPK
#define OW2 0        // [32][160]  k=tap*16+ci, taps 0..9 (tap9 = zero pad)
#define OW3 5120     // [64][288]  k=tap*32+ci
#define OW4 23552    // [64][576]  k=tap*64+ci
#define OD0 60416    // 4 classes [64][K], K={256,128,128,64}
#define OD1 97280    // 4 classes [32][K], K={64,128,128,256}
#define OD2 115712   // 4 classes [16][32]
#define NWPK 117760

#define SIMSTRIDE 1024000   // 512*2000
#define ZHSTRIDE  1179648   // 512*2304

DEV float* bkt(float* hdr, int blk){ return hdr + H_BUK + (size_t)(blk & (NBUK-1))*BSTRIDE; }

DEV void coef_lds(const float* __restrict__ hdr, int offS, int offQ,
                  const float* __restrict__ g, const float* __restrict__ be,
                  float* ac, int nch, float invN, int tid){
  if (tid < nch){
    float s = 0.f, q = 0.f;
    #pragma unroll
    for (int k=0;k<NBUK;k++){
      s += hdr[H_BUK + k*BSTRIDE + offS + tid];
      q += hdr[H_BUK + k*BSTRIDE + offQ + tid];
    }
    float m = s*invN;
    float v = q*invN - m*m;
    float a = g[tid]*rsqrtf(v + 1e-5f);
    ac[tid] = a;
    ac[nch+tid] = be[tid] - m*a;
  }
}

// ---------------- stats of strided-sampled input (for bn1 fold) ----------------
__global__ __launch_bounds__(256) void k_xstats(const float* __restrict__ x, float* __restrict__ hdr){
  __shared__ float red[8];
  float s = 0.f, q = 0.f;
  const int total = 512*49*49;
  for (int idx = blockIdx.x*256 + threadIdx.x; idx < total; idx += gridDim.x*256){
    int b = idx / 2401;
    int r = idx - b*2401;
    int i = r / 49, j = r - i*49;
    float v = 0.f;
    if (i > 0 && j > 0) v = x[(size_t)b*9216 + (2*i-1)*96 + (2*j-1)];
    s += v; q += v*v;
  }
  for (int o=32;o;o>>=1){ s += __shfl_down(s,o,64); q += __shfl_down(q,o,64); }
  int w = threadIdx.x>>6;
  if ((threadIdx.x&63)==0){ red[w*2]=s; red[w*2+1]=q; }
  __syncthreads();
  if (threadIdx.x==0){
    float* bk = bkt(hdr, blockIdx.x);
    atomicAdd(&bk[H_XS+0], red[0]+red[2]+red[4]+red[6]);
    atomicAdd(&bk[H_XS+1], red[1]+red[3]+red[5]+red[7]);
  }
}

// ---------------- pack all conv/deconv weights to bf16 [co][k] ----------------
__global__ __launch_bounds__(256) void k_wprep2(
    const float* __restrict__ c2w, const float* __restrict__ c3w, const float* __restrict__ c4w,
    const float* __restrict__ d0w, const float* __restrict__ d1w, const float* __restrict__ d2w,
    ushort_t* __restrict__ WPK){
  int i = blockIdx.x*256 + threadIdx.x;
  if (i >= NWPK) return;
  float val = 0.f;
  if (i < OW3){                       // conv2 [32][160]
    int co = i/160, k = i - co*160, tap = k>>4, ci = k&15;
    if (tap < 9) val = c2w[(co*16+ci)*9+tap];
  } else if (i < OW4){                // conv3 [64][288]
    int r = i - OW3; int co = r/288, k = r - co*288, tap = k>>5, ci = k&31;
    val = c3w[(co*32+ci)*9+tap];
  } else if (i < OD0){                // conv4 [64][576]
    int r = i - OW4; int co = r/576, k = r - co*576, tap = k>>6, ci = k&63;
    val = c4w[(co*64+ci)*9+tap];
  } else if (i < OD1){                // deconv0 classes
    int r = i - OD0;
    const int base[4]={0,16384,24576,32768}, K[4]={256,128,128,64};
    const int T0[4][4] = {{0,2,6,8},{1,7,0,0},{3,5,0,0},{4,0,0,0}};
    int cl = (r<16384)?0:(r<24576)?1:(r<32768)?2:3;
    int rr = r - base[cl]; int co = rr/K[cl], k = rr - co*K[cl], t = k>>6, ci = k&63;
    val = d0w[(ci*64+co)*9 + T0[cl][t]];
  } else if (i < OD2){                // deconv1 classes
    int r = i - OD1;
    const int base[4]={0,2048,6144,10240}, K[4]={64,128,128,256};
    const int T1[4][4] = {{4,0,0,0},{3,5,0,0},{1,7,0,0},{0,2,6,8}};
    int cl = (r<2048)?0:(r<6144)?1:(r<10240)?2:3;
    int rr = r - base[cl]; int co = rr/K[cl], k = rr - co*K[cl], t = k>>6, ci = k&63;
    val = d1w[(ci*32+co)*9 + T1[cl][t]];
  } else {                            // deconv2 classes [4][16][32]
    int r = i - OD2;
    int cl = r>>9, s = r&511, co = s>>5, ci = s&31;
    const int pis[4]={0,0,1,1}, pjs[4]={0,1,0,1};
    val = d2w[((ci*16+co)*2 + (1-pis[cl]))*2 + (1-pjs[cl])];
  }
  WPK[i] = f2bf(val);
}

// ---------------- memory rows -> bf16 + row norms ----------------
__global__ __launch_bounds__(256) void k_memrows(const float* __restrict__ mem, float* __restrict__ hdr,
                                                 ushort_t* __restrict__ mbf){
  __shared__ float red[4];
  const int m = blockIdx.x, tid = threadIdx.x;
  float part = 0.f;
  for (int i=tid;i<2304;i+=256){
    float v = mem[(size_t)m*2304+i];
    mbf[(size_t)m*2304+i] = f2bf(v);
    part += v*v;
  }
  for (int o=32;o;o>>=1) part += __shfl_down(part,o,64);
  if ((tid&63)==0) red[tid>>6] = part;
  __syncthreads();
  if (tid==0) hdr[H_MN+m] = sqrtf(red[0]+red[1]+red[2]+red[3]);
}

__global__ __launch_bounds__(256) void k_memT(const float* __restrict__ mem, ushort_t* __restrict__ mt){
  __shared__ ushort_t tile[32][33];
  const int ft = blockIdx.x % 72, mtile = blockIdx.x / 72;
  const int tx = threadIdx.x & 31, ty = threadIdx.x >> 5;
  #pragma unroll
  for (int r0=0;r0<4;r0++){
    int m = mtile*32 + r0*8 + ty;
    int f = ft*32 + tx;
    float v = (m < 2000) ? mem[(size_t)m*2304 + f] : 0.f;
    tile[r0*8+ty][tx] = f2bf(v);
  }
  __syncthreads();
  #pragma unroll
  for (int r0=0;r0<4;r0++){
    int f = ft*32 + r0*8 + ty;
    mt[(size_t)f*2016 + mtile*32 + tx] = tile[tx][r0*8+ty];
  }
}

// ---------------- conv2 (MFMA): 16->32, 3x3 s2 p1; writes H2CL [b][625][32] raw bf16 ----------------
__global__ __launch_bounds__(256) void k_conv2m(
    const float* __restrict__ x, const ushort_t* __restrict__ WPK, const float* __restrict__ b2g,
    const float* __restrict__ c1w, const float* __restrict__ c1b,
    const float* __restrict__ bn1g, const float* __restrict__ bn1b,
    float* __restrict__ hdr, ushort_t* __restrict__ out){
  __shared__ ushort_t inp[27*51*16];    // [row][col][ci16], halo'd 51-grid rows [2*ro..2*ro+26]
  __shared__ float ac[32];
  const int blk = blockIdx.x, b = blk>>1, h = blk&1, tid = threadIdx.x;
  const int ro = h*13, nr = h?12:13, npos = nr*25, ntiles = (npos+15)>>4;
  if (tid < 16){
    float sx=0.f, qx=0.f;
    #pragma unroll
    for (int k=0;k<NBUK;k++){ sx += hdr[H_BUK+k*BSTRIDE+H_XS]; qx += hdr[H_BUK+k*BSTRIDE+H_XS+1]; }
    const float N = 512.f*49.f*49.f;
    float mx = sx/N, vx = qx/N - mx*mx;
    float mean = c1w[tid]*mx + c1b[tid];
    float a = bn1g[tid]*rsqrtf(c1w[tid]*c1w[tid]*vx + 1e-5f);
    ac[tid] = a*c1w[tid];
    ac[16+tid] = a*(c1b[tid]-mean) + bn1b[tid];
  }
  __syncthreads();
  for (int e = tid; e < 27*51; e += 256){
    int lr = e/51, gc = e - lr*51;
    int grg = 2*ro + lr;
    bool inside = (grg>=1 && grg<=49 && gc>=1 && gc<=49);
    float v = 0.f;
    if (grg>=2 && grg<=49 && gc>=2 && gc<=49) v = x[(size_t)b*9216 + (2*grg-3)*96 + (2*gc-3)];
    ushort_t hv[16];
    if (inside){
      #pragma unroll
      for (int c=0;c<16;c++) hv[c] = f2bf(fmaxf(fmaf(ac[c], v, ac[16+c]), 0.f));
    } else {
      #pragma unroll
      for (int c=0;c<16;c++) hv[c] = 0;
    }
    uint32_t w0[8];
    #pragma unroll
    for (int c=0;c<8;c++) w0[c] = (uint32_t)hv[2*c] | ((uint32_t)hv[2*c+1]<<16);
    uint4* dst = (uint4*)&inp[e*16];
    dst[0] = make_uint4(w0[0],w0[1],w0[2],w0[3]);
    dst[1] = make_uint4(w0[4],w0[5],w0[6],w0[7]);
  }
  __syncthreads();
  const int wv = tid>>6, lane = tid&63, r = lane&15, q = lane>>4;
  const int cotile = wv&1;
  bf16x8 af[5];
  #pragma unroll
  for (int c=0;c<5;c++) af[c] = *(const bf16x8*)(WPK + OW2 + (cotile*16+r)*160 + c*32 + q*8);
  float biasr[4];
  #pragma unroll
  for (int v=0;v<4;v++) biasr[v] = b2g[cotile*16 + q*4 + v];
  const int TOFF[10] = {0,1,2,51,52,53,102,103,104,0};
  const int qhi = q>>1, ci0 = (q&1)*8;
  float sacc[4]={0,0,0,0}, qacc[4]={0,0,0,0};
  for (int t = wv>>1; t < ntiles; t += 2){
    int p = t*16 + r;
    bool ok = p < npos;
    int pc = ok ? p : 0;
    int a_ = pc/25, c_ = pc - a_*25;
    int pb = (2*a_)*51 + 2*c_;
    f32x4 acc = {0.f,0.f,0.f,0.f};
    #pragma unroll
    for (int c=0;c<5;c++){
      int toff = qhi ? TOFF[2*c+1] : TOFF[2*c];
      bf16x8 bv = *(const bf16x8*)&inp[(pb + toff)*16 + ci0];
      acc = __builtin_amdgcn_mfma_f32_16x16x32_bf16(af[c], bv, acc, 0, 0, 0);
    }
    if (ok){
      int pg = (ro + a_)*25 + c_;
      ushort_t pk[4];
      #pragma unroll
      for (int reg=0;reg<4;reg++){
        float y = acc[reg] + biasr[reg];
        pk[reg] = f2bf(y);
        sacc[reg] += y; qacc[reg] += y*y;
      }
      *(uint2*)&out[((size_t)b*625 + pg)*32 + cotile*16 + q*4] =
        make_uint2((uint32_t)pk[0] | ((uint32_t)pk[1]<<16), (uint32_t)pk[2] | ((uint32_t)pk[3]<<16));
    }
  }
  float* bk = bkt(hdr, blk);
  #pragma unroll
  for (int reg=0;reg<4;reg++){
    float s = sacc[reg], qq = qacc[reg];
    for (int o=8;o;o>>=1){ s += __shfl_down(s,o,16); qq += __shfl_down(qq,o,16); }
    if (r==0){ atomicAdd(&bk[H_S2+cotile*16+q*4+reg], s); atomicAdd(&bk[H_Q2+cotile*16+q*4+reg], qq); }
  }
}

// ---------------- conv3 (MFMA): 32->64, 3x3 s2 p1, 25->13; 2 spatial halves per image ----------------
// in: H2CL [b][625][32] raw bf16; out: H3CL [b][169][64] raw bf16
__global__ __launch_bounds__(256) void k_conv3m(
    const ushort_t* __restrict__ h2, const ushort_t* __restrict__ WPK, const float* __restrict__ b3g,
    const float* __restrict__ g, const float* __restrict__ be,
    float* __restrict__ hdr, ushort_t* __restrict__ out){
  __shared__ ushort_t inp[15*27*32];   // [lr][lc][ci32], chunk-swizzled
  __shared__ float ac[64];
  const int blk = blockIdx.x, b = blk>>1, h = blk&1, tid = threadIdx.x;
  const int a0 = h*7, na = h?6:7, npos = na*13, ntiles = (npos+15)>>4, nrows = 2*na+1;
  coef_lds(hdr, H_S2, H_Q2, g, be, ac, 32, 1.f/(512.f*625.f), tid);
  __syncthreads();
  for (int e = tid; e < nrows*27*4; e += 256){
    int cell = e>>2, ch = e&3;
    int lr = cell/27, lc = cell - lr*27;
    int ii = 2*a0 - 1 + lr, j = lc - 1;
    uint4 val = make_uint4(0,0,0,0);
    if ((unsigned)ii < 25u && (unsigned)j < 25u){
      uint4 raw = *(const uint4*)&h2[((size_t)b*625 + ii*25 + j)*32 + ch*8];
      val = stage_chunk(raw, ac, ch*8, 32);
    }
    int slot = ch ^ ((cell>>1)&3);
    *(uint4*)&inp[cell*32 + slot*8] = val;
  }
  __syncthreads();
  const int wv = tid>>6, lane = tid&63, r = lane&15, q = lane>>4;
  bf16x8 af[9];
  #pragma unroll
  for (int c=0;c<9;c++) af[c] = *(const bf16x8*)(WPK + OW3 + (wv*16+r)*288 + c*32 + q*8);
  float biasr[4];
  #pragma unroll
  for (int v=0;v<4;v++) biasr[v] = b3g[wv*16 + q*4 + v];
  const int TOFF[9] = {0,1,2,27,28,29,54,55,56};
  float sacc[4]={0,0,0,0}, qacc[4]={0,0,0,0};
  for (int t = 0; t < ntiles; t++){
    int p = t*16 + r;
    bool ok = p < npos;
    int pc = ok ? p : 0;
    int a_ = pc/13, c_ = pc - a_*13;
    int pb = (2*a_)*27 + 2*c_;
    f32x4 acc = {0.f,0.f,0.f,0.f};
    #pragma unroll
    for (int c=0;c<9;c++){
      int cell = pb + TOFF[c];
      int slot = q ^ ((cell>>1)&3);
      bf16x8 bv = *(const bf16x8*)&inp[cell*32 + slot*8];
      acc = __builtin_amdgcn_mfma_f32_16x16x32_bf16(af[c], bv, acc, 0, 0, 0);
    }
    if (ok){
      int pos = (a0 + a_)*13 + c_;
      ushort_t pk[4];
      #pragma unroll
      for (int reg=0;reg<4;reg++){
        float y = acc[reg] + biasr[reg];
        pk[reg] = f2bf(y);
        sacc[reg] += y; qacc[reg] += y*y;
      }
      *(uint2*)&out[((size_t)b*169 + pos)*64 + wv*16 + q*4] =
        make_uint2((uint32_t)pk[0] | ((uint32_t)pk[1]<<16), (uint32_t)pk[2] | ((uint32_t)pk[3]<<16));
    }
  }
  float* bk = bkt(hdr, blk);
  #pragma unroll
  for (int reg=0;reg<4;reg++){
    float s = sacc[reg], qq = qacc[reg];
    for (int o=8;o;o>>=1){ s += __shfl_down(s,o,16); qq += __shfl_down(qq,o,16); }
    if (r==0){ atomicAdd(&bk[H_S3+wv*16+q*4+reg], s); atomicAdd(&bk[H_Q3+wv*16+q*4+reg], qq); }
  }
}

// ---------------- conv4 (MFMA): 64->64, 3x3 s2 p0, 13->6; in: H3CL raw bf16 ----------------
__global__ __launch_bounds__(256) void k_conv4m(
    const ushort_t* __restrict__ h3, const ushort_t* __restrict__ WPK, const float* __restrict__ b4g,
    const float* __restrict__ g, const float* __restrict__ be,
    float* __restrict__ hdr, float* __restrict__ out){
  __shared__ ushort_t inp[169*64];     // [cell][ci64], chunk-swizzled
  __shared__ float ac[128];
  const int b = blockIdx.x, tid = threadIdx.x;
  coef_lds(hdr, H_S3, H_Q3, g, be, ac, 64, 1.f/(512.f*169.f), tid);
  __syncthreads();
  for (int e = tid; e < 169*8; e += 256){
    int cell = e>>3, ch = e&7;
    uint4 raw = *(const uint4*)&h3[((size_t)b*169 + cell)*64 + ch*8];
    uint4 val = stage_chunk(raw, ac, ch*8, 64);
    int slot = ch ^ ((cell>>1)&7);
    *(uint4*)&inp[cell*64 + slot*8] = val;
  }
  __syncthreads();
  const int wv = tid>>6, lane = tid&63, r = lane&15, q = lane>>4;
  bf16x8 af[18];
  #pragma unroll
  for (int c=0;c<18;c++) af[c] = *(const bf16x8*)(WPK + OW4 + (wv*16+r)*576 + c*32 + q*8);
  float biasr[4];
  #pragma unroll
  for (int v=0;v<4;v++) biasr[v] = b4g[wv*16 + q*4 + v];
  const int TOFF[9] = {0,1,2,13,14,15,26,27,28};
  float sacc[4]={0,0,0,0}, qacc[4]={0,0,0,0};
  for (int t = 0; t < 3; t++){
    int p = t*16 + r;
    bool ok = p < 36;
    int pc = ok ? p : 0;
    int a_ = pc/6, c_ = pc - a_*6;
    int pb = (2*a_)*13 + 2*c_;
    f32x4 acc = {0.f,0.f,0.f,0.f};
    #pragma unroll
    for (int c=0;c<18;c++){
      int cell = pb + TOFF[c>>1];
      int chunk = (c&1)*4 + q;
      int slot = chunk ^ ((cell>>1)&7);
      bf16x8 bv = *(const bf16x8*)&inp[cell*64 + slot*8];
      acc = __builtin_amdgcn_mfma_f32_16x16x32_bf16(af[c], bv, acc, 0, 0, 0);
    }
    if (ok){
      #pragma unroll
      for (int reg=0;reg<4;reg++){
        float y = acc[reg] + biasr[reg];
        out[((size_t)b*64 + wv*16 + q*4 + reg)*36 + p] = y;
        sacc[reg] += y; qacc[reg] += y*y;
      }
    }
  }
  float* bk = bkt(hdr, b);
  #pragma unroll
  for (int reg=0;reg<4;reg++){
    float s = sacc[reg], qq = qacc[reg];
    for (int o=8;o;o>>=1){ s += __shfl_down(s,o,16); qq += __shfl_down(qq,o,16); }
    if (r==0){ atomicAdd(&bk[H_S4+wv*16+q*4+reg], s); atomicAdd(&bk[H_Q4+wv*16+q*4+reg], qq); }
  }
}

// z = relu(bn4(conv4 raw)) -> bf16, plus per-row norm
__global__ __launch_bounds__(256) void k_z(const float* __restrict__ zraw, float* __restrict__ hdr,
                                           ushort_t* __restrict__ zbf,
                                           const float* __restrict__ g, const float* __restrict__ be){
  __shared__ float ac[128];
  __shared__ float red[4];
  const int b = blockIdx.x, tid = threadIdx.x;
  coef_lds(hdr, H_S4, H_Q4, g, be, ac, 64, 1.f/(512.f*36.f), tid);
  __syncthreads();
  float part = 0.f;
  for (int i=tid;i<2304;i+=256){
    int c = i/36;
    float h = fmaxf(fmaf(ac[c], zraw[(size_t)b*2304+i], ac[64+c]), 0.f);
    zbf[(size_t)b*2304+i] = f2bf(h);
    part += h*h;
  }
  for (int o=32;o;o>>=1) part += __shfl_down(part,o,64);
  if ((tid&63)==0) red[tid>>6] = part;
  __syncthreads();
  if (tid==0) hdr[H_ZN+b] = sqrtf(red[0]+red[1]+red[2]+red[3]);
}

// ---------------- blocked GEMM, split-K ----------------
__global__ __launch_bounds__(256) void k_gemmB(const ushort_t* __restrict__ A, const ushort_t* __restrict__ Bm,
                                               float* __restrict__ D, int Nb, int N, int Kp, int kch,
                                               int tiles, int ksp, size_t dstride){
  __shared__ __align__(16) ushort_t lB[128*40];
  const int blk = blockIdx.x;
  const int s = blk / tiles, t = blk - s*tiles;
  const int bi = t / Nb, bj = t - bi*Nb;
  const int m0 = bi*128, n0 = bj*128;
  const int k0 = s*ksp, k1 = min(kch, k0 + ksp);
  const int tid = threadIdx.x;
  const int lane = tid & 63, wv = tid >> 6;
  const int r = lane & 15, q = lane >> 4;
  const int wr = wv >> 1, wc = wv & 1;
  float* Ds = D + (size_t)s*dstride;
  const int srow = tid >> 1, skq = (tid & 1) * 16;
  const bool bok = (n0 + srow) < N;
  const ushort_t* pb = Bm + (size_t)(n0 + srow)*Kp + skq;
  uint4* wB = (uint4*)&lB[srow*40 + skq];
  const uint4 zz = make_uint4(0,0,0,0);
  uint4 rb0 = bok ? *(const uint4*)(pb + k0*32)     : zz;
  uint4 rb1 = bok ? *(const uint4*)(pb + k0*32 + 8) : zz;
  const ushort_t* pa = A + (size_t)(m0 + wr*64 + r)*Kp + q*8;
  bf16x8 aN[4];
  #pragma unroll
  for (int mt=0;mt<4;mt++) aN[mt] = *(const bf16x8*)(pa + k0*32 + (size_t)(mt*16)*Kp);
  f32x4 acc[4][4];
  #pragma unroll
  for (int i=0;i<4;i++)
    #pragma unroll
    for (int j=0;j<4;j++) acc[i][j] = (f32x4){0.f,0.f,0.f,0.f};
  for (int k=k0; k<k1; k++){
    if (k > k0) __syncthreads();
    wB[0] = rb0; wB[1] = rb1;
    bf16x8 aF[4];
    #pragma unroll
    for (int mt=0;mt<4;mt++) aF[mt] = aN[mt];
    if (k+1 < k1){
      const ushort_t* nb = pb + (k+1)*32;
      rb0 = bok ? *(const uint4*)(nb)     : zz;
      rb1 = bok ? *(const uint4*)(nb + 8) : zz;
      const ushort_t* na = pa + (k+1)*32;
      #pragma unroll
      for (int mt=0;mt<4;mt++) aN[mt] = *(const bf16x8*)(na + (size_t)(mt*16)*Kp);
    }
    __syncthreads();
    bf16x8 bF[4];
    #pragma unroll
    for (int nt=0;nt<4;nt++) bF[nt] = *(const bf16x8*)&lB[(wc*64+nt*16+r)*40 + q*8];
    #pragma unroll
    for (int mt=0;mt<4;mt++)
      #pragma unroll
      for (int nt=0;nt<4;nt++)
        acc[mt][nt] = __builtin_amdgcn_mfma_f32_16x16x32_bf16(aF[mt], bF[nt], acc[mt][nt], 0, 0, 0);
  }
  #pragma unroll
  for (int mt=0;mt<4;mt++){
    int row = m0 + wr*64 + mt*16 + q*4;
    #pragma unroll
    for (int nt=0;nt<4;nt++){
      int col = n0 + wc*64 + nt*16 + r;
      if (col < N){
        #pragma unroll
        for (int reg=0;reg<4;reg++)
          Ds[(size_t)(row+reg)*N + col] = acc[mt][nt][reg];
      }
    }
  }
}

// softmax over M=2000 (sums 4 split-K partials) + hard-shrink + L1 renorm -> bf16
__global__ __launch_bounds__(256) void k_softmax(const float* __restrict__ sim, float* __restrict__ hdr,
                                                 ushort_t* __restrict__ wbf){
  __shared__ float e[2000];
  __shared__ float red[8];
  const int b = blockIdx.x, tid = threadIdx.x;
  const float znb = hdr[H_ZN+b];
  float part = 0.f;
  for (int m=tid;m<2000;m+=256){
    size_t ix = (size_t)b*2000+m;
    float sv = sim[ix] + sim[ix+SIMSTRIDE] + sim[ix+2*SIMSTRIDE] + sim[ix+3*SIMSTRIDE];
    float s = sv / fmaxf(znb * hdr[H_MN+m], 1e-8f);
    float ev = __expf(s);
    e[m] = ev; part += ev;
  }
  for (int o=32;o;o>>=1) part += __shfl_down(part,o,64);
  if ((tid&63)==0) red[tid>>6] = part;
  __syncthreads();
  const float denom = red[0]+red[1]+red[2]+red[3];
  const float t = 1.0f/2000.0f;
  float part2 = 0.f;
  for (int m=tid;m<2000;m+=256){
    float w = e[m]/denom;
    float d = w - t;
    float sh = fmaxf(d,0.f)*w/(fabsf(d)+0.01f);
    e[m] = sh; part2 += sh;
  }
  for (int o=32;o;o>>=1) part2 += __shfl_down(part2,o,64);
  if ((tid&63)==0) red[4+(tid>>6)] = part2;
  __syncthreads();
  const float inv = 1.0f/(red[4]+red[5]+red[6]+red[7]);
  for (int m=tid;m<2016;m+=256){
    ushort_t o = 0;
    if (m < 2000) o = f2bf(e[m]*inv);
    wbf[(size_t)b*2016+m] = o;
  }
}

// ---------------- deconv0 (MFMA): 64->64, k3 s2 p0, 6->13; out: G0CL [b][169][64] raw bf16 ----------------
__global__ __launch_bounds__(256) void k_deconv0m(
    const float* __restrict__ zh, const ushort_t* __restrict__ WPK, const float* __restrict__ b0g,
    float* __restrict__ hdr, ushort_t* __restrict__ out){
  __shared__ ushort_t inp[64*64];      // [cell 8x8 halo][ci64]
  const int b = blockIdx.x, tid = threadIdx.x;
  for (int e = tid; e < 64*64; e += 256){
    int ci = e & 63, cell = e >> 6;
    int r8 = cell>>3, c8 = cell&7;
    float v = 0.f;
    if (r8>=1 && r8<=6 && c8>=1 && c8<=6){
      size_t ix = (size_t)b*2304 + ci*36 + (r8-1)*6 + (c8-1);
      v = zh[ix] + zh[ix+ZHSTRIDE] + zh[ix+2*ZHSTRIDE] + zh[ix+3*ZHSTRIDE];
    }
    inp[e] = f2bf(v);
  }
  __syncthreads();
  const int wv = tid>>6, lane = tid&63, r = lane&15, q = lane>>4;
  float biasr[4];
  #pragma unroll
  for (int v=0;v<4;v++) biasr[v] = b0g[wv*16 + q*4 + v];
  const int NCOL[4]={7,6,7,6}, NPOS[4]={49,42,42,36}, NT[4]={4,3,3,3},
            NCH[4]={8,4,4,2}, KB[4]={0,16384,24576,32768}, KK[4]={256,128,128,64},
            PI[4]={0,0,1,1}, PJ[4]={0,1,0,1};
  const int TOFF[4][4] = {{9,8,1,0},{9,1,0,0},{9,8,0,0},{9,0,0,0}};
  float sacc[4]={0,0,0,0}, qacc[4]={0,0,0,0};
  #pragma unroll
  for (int cl=0; cl<4; cl++){
    bf16x8 af[8];
    #pragma unroll
    for (int m=0;m<NCH[cl];m++)
      af[m] = *(const bf16x8*)(WPK + OD0 + KB[cl] + (wv*16+r)*KK[cl] + m*32 + q*8);
    for (int t = 0; t < NT[cl]; t++){
      int p = t*16 + r;
      bool ok = p < NPOS[cl];
      int pc = ok ? p : 0;
      int a_ = pc/NCOL[cl], c_ = pc - a_*NCOL[cl];
      int pb = a_*8 + c_;
      f32x4 acc = {0.f,0.f,0.f,0.f};
      #pragma unroll
      for (int m=0;m<NCH[cl];m++){
        int ci0 = (m&1)*32 + q*8;
        bf16x8 bv = *(const bf16x8*)&inp[(pb + TOFF[cl][m>>1])*64 + ci0];
        acc = __builtin_amdgcn_mfma_f32_16x16x32_bf16(af[m], bv, acc, 0, 0, 0);
      }
      if (ok){
        int pos = (2*a_+PI[cl])*13 + (2*c_+PJ[cl]);
        ushort_t pk[4];
        #pragma unroll
        for (int reg=0;reg<4;reg++){
          float y = acc[reg] + biasr[reg];
          pk[reg] = f2bf(y);
          sacc[reg] += y; qacc[reg] += y*y;
        }
        *(uint2*)&out[((size_t)b*169 + pos)*64 + wv*16 + q*4] =
          make_uint2((uint32_t)pk[0] | ((uint32_t)pk[1]<<16), (uint32_t)pk[2] | ((uint32_t)pk[3]<<16));
      }
    }
  }
  float* bk = bkt(hdr, b);
  #pragma unroll
  for (int reg=0;reg<4;reg++){
    float s = sacc[reg], qq = qacc[reg];
    for (int o=8;o;o>>=1){ s += __shfl_down(s,o,16); qq += __shfl_down(qq,o,16); }
    if (r==0){ atomicAdd(&bk[H_DS0+wv*16+q*4+reg], s); atomicAdd(&bk[H_DQ0+wv*16+q*4+reg], qq); }
  }
}

// ---------------- deconv1 (MFMA): 64->32, k3 s2 p1, 13->25; in: G0CL, out: G1CL [b][625][32] ----------------
__global__ __launch_bounds__(256) void k_deconv1m(
    const ushort_t* __restrict__ g0, const ushort_t* __restrict__ WPK, const float* __restrict__ b1g,
    const float* __restrict__ g, const float* __restrict__ be,
    float* __restrict__ hdr, ushort_t* __restrict__ out){
  __shared__ ushort_t inp[169*64];     // [cell 13x13][ci64], chunk-swizzled
  __shared__ float ac[128];
  const int b = blockIdx.x, tid = threadIdx.x;
  coef_lds(hdr, H_DS0, H_DQ0, g, be, ac, 64, 1.f/(512.f*169.f), tid);
  __syncthreads();
  for (int e = tid; e < 169*8; e += 256){
    int cell = e>>3, ch = e&7;
    uint4 raw = *(const uint4*)&g0[((size_t)b*169 + cell)*64 + ch*8];
    uint4 val = stage_chunk(raw, ac, ch*8, 64);
    int slot = ch ^ ((cell>>1)&7);
    *(uint4*)&inp[cell*64 + slot*8] = val;
  }
  __syncthreads();
  const int wv = tid>>6, lane = tid&63, r = lane&15, q = lane>>4;
  const int cotile = wv&1, ph = wv>>1;
  float biasr[4];
  #pragma unroll
  for (int v=0;v<4;v++) biasr[v] = b1g[cotile*16 + q*4 + v];
  const int NCOL[4]={13,12,13,12}, NPOS[4]={169,156,156,144}, NT[4]={11,10,10,9},
            NCH[4]={2,4,4,8}, KB[4]={0,2048,6144,10240}, KK[4]={64,128,128,256},
            PI[4]={0,0,1,1}, PJ[4]={0,1,0,1};
  const int TOFF[4][4] = {{0,0,0,0},{1,0,0,0},{13,0,0,0},{14,13,1,0}};
  float sacc[4]={0,0,0,0}, qacc[4]={0,0,0,0};
  #pragma unroll
  for (int cl=0; cl<4; cl++){
    bf16x8 af[8];
    #pragma unroll
    for (int m=0;m<NCH[cl];m++)
      af[m] = *(const bf16x8*)(WPK + OD1 + KB[cl] + (cotile*16+r)*KK[cl] + m*32 + q*8);
    for (int t = ph; t < NT[cl]; t += 2){
      int p = t*16 + r;
      bool ok = p < NPOS[cl];
      int pc = ok ? p : 0;
      int a_ = pc/NCOL[cl], c_ = pc - a_*NCOL[cl];
      int pb = a_*13 + c_;
      f32x4 acc = {0.f,0.f,0.f,0.f};
      #pragma unroll
      for (int m=0;m<NCH[cl];m++){
        int cell = pb + TOFF[cl][m>>1];
        int chunk = (m&1)*4 + q;
        int slot = chunk ^ ((cell>>1)&7);
        bf16x8 bv = *(const bf16x8*)&inp[cell*64 + slot*8];
        acc = __builtin_amdgcn_mfma_f32_16x16x32_bf16(af[m], bv, acc, 0, 0, 0);
      }
      if (ok){
        int pos = (2*a_+PI[cl])*25 + (2*c_+PJ[cl]);
        ushort_t pk[4];
        #pragma unroll
        for (int reg=0;reg<4;reg++){
          float y = acc[reg] + biasr[reg];
          pk[reg] = f2bf(y);
          sacc[reg] += y; qacc[reg] += y*y;
        }
        *(uint2*)&out[((size_t)b*625 + pos)*32 + cotile*16 + q*4] =
          make_uint2((uint32_t)pk[0] | ((uint32_t)pk[1]<<16), (uint32_t)pk[2] | ((uint32_t)pk[3]<<16));
      }
    }
  }
  float* bk = bkt(hdr, b);
  #pragma unroll
  for (int reg=0;reg<4;reg++){
    float s = sacc[reg], qq = qacc[reg];
    for (int o=8;o;o>>=1){ s += __shfl_down(s,o,16); qq += __shfl_down(qq,o,16); }
    if (r==0){ atomicAdd(&bk[H_DS1+cotile*16+q*4+reg], s); atomicAdd(&bk[H_DQ1+cotile*16+q*4+reg], qq); }
  }
}

// ---------------- deconv2 (MFMA): 32->16, k2 s2 p1 op1, 25->49; in: G1CL; out: G2BF planes ----------------
__global__ __launch_bounds__(256) void k_deconv2m(
    const ushort_t* __restrict__ g1, const ushort_t* __restrict__ WPK, const float* __restrict__ bg,
    const float* __restrict__ g, const float* __restrict__ be,
    float* __restrict__ hdr, ushort_t* __restrict__ out){
  __shared__ ushort_t inp[625*32];     // [cell 25x25][ci32], chunk-swizzled
  __shared__ float ac[64];
  const int b = blockIdx.x, tid = threadIdx.x;
  coef_lds(hdr, H_DS1, H_DQ1, g, be, ac, 32, 1.f/(512.f*625.f), tid);
  __syncthreads();
  for (int e = tid; e < 625*4; e += 256){
    int cell = e>>2, ch = e&3;
    uint4 raw = *(const uint4*)&g1[((size_t)b*625 + cell)*32 + ch*8];
    uint4 val = stage_chunk(raw, ac, ch*8, 32);
    int slot = ch ^ ((cell>>1)&3);
    *(uint4*)&inp[cell*32 + slot*8] = val;
  }
  __syncthreads();
  const int wv = tid>>6, lane = tid&63, r = lane&15, q = lane>>4;
  const int cl = wv;   // one parity class per wave
  float biasr[4];
  #pragma unroll
  for (int v=0;v<4;v++) biasr[v] = bg[q*4 + v];
  const int NCOL[4]={25,24,25,24}, NPOS[4]={625,600,600,576}, NT[4]={40,38,38,36},
            TOFF[4]={0,1,25,26};
  const int nc = NCOL[cl], npos = NPOS[cl], nt = NT[cl], toff = TOFF[cl];
  bf16x8 af = *(const bf16x8*)(WPK + OD2 + cl*512 + r*32 + q*8);
  float sacc[4]={0,0,0,0}, qacc[4]={0,0,0,0};
  for (int t = 0; t < nt; t++){
    int p = t*16 + r;
    bool ok = p < npos;
    int pc = ok ? p : 0;
    int a_ = pc/nc, c_ = pc - a_*nc;
    int cell = a_*25 + c_ + toff;
    int slot = q ^ ((cell>>1)&3);
    f32x4 acc = {0.f,0.f,0.f,0.f};
    bf16x8 bv = *(const bf16x8*)&inp[cell*32 + slot*8];
    acc = __builtin_amdgcn_mfma_f32_16x16x32_bf16(af, bv, acc, 0, 0, 0);
    if (ok){
      #pragma unroll
      for (int reg=0;reg<4;reg++){
        float y = acc[reg] + biasr[reg];
        out[((size_t)(b*16 + q*4 + reg)*4 + cl)*625 + p] = f2bf(y);
        sacc[reg] += y; qacc[reg] += y*y;
      }
    }
  }
  float* bk = bkt(hdr, b);
  #pragma unroll
  for (int reg=0;reg<4;reg++){
    float s = sacc[reg], qq = qacc[reg];
    for (int o=8;o;o>>=1){ s += __shfl_down(s,o,16); qq += __shfl_down(qq,o,16); }
    if (r==0){ atomicAdd(&bk[H_DS2+q*4+reg], s); atomicAdd(&bk[H_DQ2+q*4+reg], qq); }
  }
}

// ---------------- deconv3: input-location-per-thread; each thread emits 4 output px ----------------
__global__ __launch_bounds__(256) void k_deconv3(const ushort_t* __restrict__ g2, const float* __restrict__ w,
                                                 const float* __restrict__ bias,
                                                 const float* __restrict__ g, const float* __restrict__ be,
                                                 float* __restrict__ hdr, float* __restrict__ out){
  __shared__ float ac[32];
  __shared__ float wl[64];
  const int tid = threadIdx.x;
  coef_lds(hdr, H_DS2, H_DQ2, g, be, ac, 16, 1.f/(512.f*2401.f), tid);
  if (tid >= 64 && tid < 128) wl[tid-64] = w[tid-64];
  __syncthreads();
  int idx = blockIdx.x*256 + tid;
  if (idx >= 512*2401) return;
  int b = idx / 2401; int loc = idx - b*2401;
  int ii = loc / 49, jj = loc - ii*49;
  int pi = ii & 1, pj = jj & 1, cl = pi*2 + pj;
  int a = ii >> 1, c = jj >> 1;
  int nc = pj ? 24 : 25;
  const float b0 = bias[0];
  float acc00 = b0, acc01 = b0, acc10 = b0, acc11 = b0;
  const ushort_t* gp = g2 + ((size_t)(b*16)*4 + cl)*625 + a*nc + c;
  #pragma unroll
  for (int ci=0; ci<16; ci++){
    float raw = bf2f(gp[(size_t)ci*4*625]);
    float h = fmaxf(fmaf(ac[ci], raw, ac[16+ci]), 0.f);
    acc00 = fmaf(h, wl[ci*4+0], acc00);
    acc01 = fmaf(h, wl[ci*4+1], acc01);
    acc10 = fmaf(h, wl[ci*4+2], acc10);
    acc11 = fmaf(h, wl[ci*4+3], acc11);
  }
  float* op = out + (size_t)b*9604 + (2*ii)*98 + 2*jj;
  op[0]   = 1.f/(1.f + __expf(-acc00));
  op[1]   = 1.f/(1.f + __expf(-acc01));
  op[98]  = 1.f/(1.f + __expf(-acc10));
  op[99]  = 1.f/(1.f + __expf(-acc11));
}

// ======================================================================
extern "C" void kernel_launch(void* const* d_in, const int* in_sizes, int n_in,
                              void* d_out, int out_size, void* d_ws, size_t ws_size,
                              hipStream_t stream){
  (void)in_sizes; (void)n_in; (void)out_size; (void)ws_size;
  const float* x     = (const float*)d_in[0];
  const float* c1w   = (const float*)d_in[1];
  const float* c1b   = (const float*)d_in[2];
  const float* bn1g  = (const float*)d_in[3];
  const float* bn1b  = (const float*)d_in[4];
  const float* c2w   = (const float*)d_in[5];
  const float* c2b   = (const float*)d_in[6];
  const float* bn2g  = (const float*)d_in[7];
  const float* bn2b  = (const float*)d_in[8];
  const float* c3w   = (const float*)d_in[9];
  const float* c3b   = (const float*)d_in[10];
  const float* bn3g  = (const float*)d_in[11];
  const float* bn3b  = (const float*)d_in[12];
  const float* c4w   = (const float*)d_in[13];
  const float* c4b   = (const float*)d_in[14];
  const float* bn4g  = (const float*)d_in[15];
  const float* bn4b  = (const float*)d_in[16];
  const float* mem   = (const float*)d_in[17];
  const float* d0w   = (const float*)d_in[18];
  const float* d0b   = (const float*)d_in[19];
  const float* dbn0g = (const float*)d_in[20];
  const float* dbn0b = (const float*)d_in[21];
  const float* d1w   = (const float*)d_in[22];
  const float* d1b   = (const float*)d_in[23];
  const float* dbn1g = (const float*)d_in[24];
  const float* dbn1b = (const float*)d_in[25];
  const float* d2w   = (const float*)d_in[26];
  const float* d2b   = (const float*)d_in[27];
  const float* dbn2g = (const float*)d_in[28];
  const float* dbn2b = (const float*)d_in[29];
  const float* d3w   = (const float*)d_in[30];
  const float* d3b   = (const float*)d_in[31];

  float* hdr  = (float*)d_ws;
  float* H2f  = hdr + HDR_FLOATS;        // slot: H2CL bf16 (10.24M ushort) / later G1CL
  float* H3f  = H2f + 10240000;          // slot: H3CL bf16 (5.54M ushort) / later G0CL
  float* ZRAW = H3f + 5537792;           // 512*2304 fp32
  float* WSLOT= ZRAW + 1179648;          // 73728 floats (holds WPK bf16)
  float* G2   = WSLOT + 73728;           // 19.67M floats scratch region
  ushort_t* MEMBF = (ushort_t*)(G2 + 19668992); // 2000*2304
  ushort_t* MEMT  = MEMBF + 4608000;            // 2304*2016
  ushort_t* ZBF   = MEMT + 4644864;             // 512*2304
  ushort_t* WBF   = ZBF + 1179648;              // 512*2016
  ushort_t* WPK   = (ushort_t*)WSLOT;
  float* SIMP = G2;                      // 4 * 512*2000
  float* ZHP  = G2 + 4*SIMSTRIDE;        // 4 * 512*2304
  ushort_t* G2BF = (ushort_t*)G2;        // 512*16*4*625 bf16
  ushort_t* H2CL = (ushort_t*)H2f;
  ushort_t* H3CL = (ushort_t*)H3f;
  ushort_t* G0CL = (ushort_t*)H3f;       // reuse (H3CL dead after conv4m)
  ushort_t* G1CL = (ushort_t*)H2f;       // reuse (H2CL dead after conv3m)
  float* OUT = (float*)d_out;

  hipMemsetAsync(hdr, 0, HDR_FLOATS*sizeof(float), stream);
  k_xstats   <<<1024, 256, 0, stream>>>(x, hdr);
  k_wprep2   <<<460, 256, 0, stream>>>(c2w, c3w, c4w, d0w, d1w, d2w, WPK);
  k_memrows  <<<2000, 256, 0, stream>>>(mem, hdr, MEMBF);
  k_memT     <<<72*63, 256, 0, stream>>>(mem, MEMT);
  k_conv2m   <<<1024, 256, 0, stream>>>(x, WPK, c2b, c1w, c1b, bn1g, bn1b, hdr, H2CL);
  k_conv3m   <<<1024, 256, 0, stream>>>(H2CL, WPK, c3b, bn2g, bn2b, hdr, H3CL);
  k_conv4m   <<<512, 256, 0, stream>>>(H3CL, WPK, c4b, bn3g, bn3b, hdr, ZRAW);
  k_z        <<<512, 256, 0, stream>>>(ZRAW, hdr, ZBF, bn4g, bn4b);
  k_gemmB    <<<256, 256, 0, stream>>>(ZBF, MEMBF, SIMP, 16, 2000, 2304, 72, 64, 18, SIMSTRIDE);
  k_softmax  <<<512, 256, 0, stream>>>(SIMP, hdr, WBF);
  k_gemmB    <<<288, 256, 0, stream>>>(WBF, MEMT, ZHP, 18, 2304, 2016, 63, 72, 16, ZHSTRIDE);
  k_deconv0m <<<512, 256, 0, stream>>>(ZHP, WPK, d0b, hdr, G0CL);
  k_deconv1m <<<512, 256, 0, stream>>>(G0CL, WPK, d1b, dbn0g, dbn0b, hdr, G1CL);
  k_deconv2m <<<512, 256, 0, stream>>>(G1CL, WPK, d2b, dbn1g, dbn1b, hdr, G2BF);
  k_deconv3  <<<4802, 256, 0, stream>>>(G2BF, d3w, d3b, dbn2g, dbn2b, hdr, OUT);
}